// Round 7
// baseline (3551.302 us; speedup 1.0000x reference)
//
#include <hip/hip_runtime.h>
#include <hip/hip_cooperative_groups.h>
#include <hip/hip_bf16.h>
#include <math.h>

namespace cg = cooperative_groups;

#define B_     64
#define NSM_   400
#define NLG_   196
#define SM_    512
#define LG_    1024
#define H_     16
#define DH_    64
#define INNER_ 1024
#define SSTR   424

typedef __attribute__((ext_vector_type(8))) short bf16x8;
typedef __attribute__((ext_vector_type(4))) float f32x4;

__device__ __forceinline__ unsigned short f2b(float f) {
  unsigned u = __float_as_uint(f);
  u = u + 0x7FFFu + ((u >> 16) & 1u);   // RNE
  return (unsigned short)(u >> 16);
}

// ============================ setup kernels ================================

struct CC2 { const float* tok; float* out; unsigned short* abf; float* cls;
             unsigned short* clsb; int Np1, nf4, shift, tot4; };
__global__ __launch_bounds__(256) void copy_cvt2(CC2 a, CC2 b) {
  const int total = a.tot4 + b.tot4;
  for (int i = blockIdx.x * 256 + threadIdx.x; i < total; i += gridDim.x * 256) {
    CC2 g; int idx;
    if (i < a.tot4) { g = a; idx = i; } else { g = b; idx = i - a.tot4; }
    int rowg = idx >> g.shift, t = idx & ((1 << g.shift) - 1);
    int bb = rowg / g.Np1, row = rowg - bb * g.Np1;
    const float4 v = ((const float4*)g.tok)[idx];
    ((float4*)g.out)[idx] = v;
    ushort4 w2; w2.x = f2b(v.x); w2.y = f2b(v.y); w2.z = f2b(v.z); w2.w = f2b(v.w);
    if (row > 0) {
      ((ushort4*)g.abf)[(size_t)(bb * (g.Np1 - 1) + row - 1) * g.nf4 + t] = w2;
    } else {
      ((float4*)g.cls)[(size_t)bb * g.nf4 + t] = v;
      ((ushort4*)g.clsb)[(size_t)bb * g.nf4 + t] = w2;
    }
  }
}

struct TXArgs { const unsigned short* xbf; unsigned short* xT; int Nctx, dout, xstride, nx, ny, nblk; };
__global__ void transpose_x2(TXArgs ga, TXArgs gb) {
  __shared__ unsigned short tile[64][65];
  TXArgs g; int bx;
  if ((int)blockIdx.x < ga.nblk) { g = ga; bx = blockIdx.x; }
  else { g = gb; bx = blockIdx.x - ga.nblk; }
  int cx = bx % g.nx; int rem = bx / g.nx;
  int jy = rem % g.ny; int b = rem / g.ny;
  int jt = jy * 64, ct = cx * 64;
  int tx = threadIdx.x, ty = threadIdx.y;  // (64,4)
  for (int r = ty; r < 64; r += 4) {
    int j = jt + r;
    tile[r][tx] = (j < g.Nctx) ? g.xbf[((size_t)b * g.Nctx + j) * g.dout + ct + tx]
                               : (unsigned short)0;
  }
  __syncthreads();
  for (int r = ty; r < 64; r += 4) {
    int col = jt + tx;
    if (col < g.xstride)
      g.xT[((size_t)b * g.dout + ct + r) * g.xstride + col] = tile[tx][r];
  }
}

struct WTDesc { const float* src; unsigned short* dst; int K, N; };
struct WTArgs { WTDesc d[10]; int cum[11]; };
__global__ __launch_bounds__(256) void wtrans_all(WTArgs W) {
  __shared__ unsigned short tile[64][65];
  int bx = blockIdx.x, di = 0;
  while (bx >= W.cum[di + 1]) di++;
  int local = bx - W.cum[di];
  WTDesc g = W.d[di];
  int tn = g.N >> 6;
  int tpl = tn * (g.K >> 6);
  int layer = local / tpl, rem = local % tpl;
  int kt = (rem / tn) * 64, nt = (rem % tn) * 64;
  const float* wp = g.src + (size_t)layer * g.K * g.N;
  unsigned short* op = g.dst + (size_t)layer * g.K * g.N;
  int tx = threadIdx.x & 63, ty = threadIdx.x >> 6;
  for (int r = ty; r < 64; r += 4)
    tile[r][tx] = f2b(wp[(size_t)(kt + r) * g.N + nt + tx]);
  __syncthreads();
  for (int r = ty; r < 64; r += 4)
    op[(size_t)(nt + r) * g.K + kt + tx] = tile[tx][r];
}

// ============================== MFMA helpers ===============================
__device__ __forceinline__ void zero4(f32x4 a[4]) {
#pragma unroll
  for (int m = 0; m < 4; m++) { a[m][0] = 0.f; a[m][1] = 0.f; a[m][2] = 0.f; a[m][3] = 0.f; }
}

__device__ __forceinline__ void mm64x16(const unsigned short* __restrict__ aB, int lda,
                                        const unsigned short* __restrict__ wB, int K,
                                        f32x4 acc[4]) {
#pragma unroll 2
  for (int k0 = 0; k0 < K; k0 += 32) {
    bf16x8 bfr = *(const bf16x8*)&wB[k0];
#pragma unroll
    for (int mt = 0; mt < 4; mt++) {
      bf16x8 af = *(const bf16x8*)&aB[(size_t)(mt * 16) * lda + k0];
      acc[mt] = __builtin_amdgcn_mfma_f32_16x16x32_bf16(af, bfr, acc[mt], 0, 0, 0);
    }
  }
}

__device__ __forceinline__ f32x4 mm16x16(const unsigned short* __restrict__ ap,
                                         const unsigned short* __restrict__ bp, int K) {
  f32x4 acc; acc[0] = 0.f; acc[1] = 0.f; acc[2] = 0.f; acc[3] = 0.f;
#pragma unroll 4
  for (int k0 = 0; k0 < K; k0 += 32)
    acc = __builtin_amdgcn_mfma_f32_16x16x32_bf16(*(const bf16x8*)&ap[k0],
                                                  *(const bf16x8*)&bp[k0], acc, 0, 0, 0);
  return acc;
}

// ============================ shared phase code ============================
struct MegaArgs {
  const unsigned short *Abf_lg, *Abf_sm, *xT_lg, *xT_sm;
  const unsigned short *WTpin_a, *WTpin_b, *WTwq_a, *WTwq_b, *WTkv_a, *WTkv_b;
  const unsigned short *WTwo_a, *WTwo_b, *WTpout_a, *WTpout_b;
  const float *wkv_a, *wkv_b;
  const float *pinb_a, *ng_a, *nb_a, *wob_a, *poutb_a;
  const float *pinb_b, *ng_b, *nb_b, *wob_b, *poutb_b;
  float *cls_sm, *cls_lg; unsigned short *clsb_sm, *clsb_lg;
  float *xbuf_a, *xbuf_b; unsigned short *xnb_a, *xnb_b;
  float *qbuf_a, *qbuf_b;
  float *kvc_a, *kvc_b; unsigned short *qt_a, *qt_b;
  float *S_a, *S_b; unsigned short *p_a, *p_b; float *pcls_a, *pcls_b;
  unsigned short *u_a, *u_b, *ob_a, *ob_b, *t1_a, *t1_b;
  float *out;
};

__device__ void run_phase(const MegaArgs& M, int l, int ph,
                          int wid, int NW, int bId, int nB, int tid) {
  const int lane = tid & 63;
  const int r16 = lane & 15, kv8 = (lane >> 4) * 8, rbase = (lane >> 4) * 4;
  const unsigned short* WTpin_al = M.WTpin_a + (size_t)l * SM_ * LG_;
  const unsigned short* WTpin_bl = M.WTpin_b + (size_t)l * LG_ * SM_;
  const unsigned short* WTwq_al  = M.WTwq_a  + (size_t)l * LG_ * INNER_;
  const unsigned short* WTwq_bl  = M.WTwq_b  + (size_t)l * SM_ * INNER_;
  const unsigned short* WTkv_al  = M.WTkv_a  + (size_t)l * 2048 * LG_;
  const unsigned short* WTkv_bl  = M.WTkv_b  + (size_t)l * 2048 * SM_;
  const unsigned short* WTwo_al  = M.WTwo_a  + (size_t)l * INNER_ * LG_;
  const unsigned short* WTwo_bl  = M.WTwo_b  + (size_t)l * INNER_ * SM_;
  const unsigned short* WTpout_al = M.WTpout_a + (size_t)l * LG_ * SM_;
  const unsigned short* WTpout_bl = M.WTpout_b + (size_t)l * SM_ * LG_;
  const float* wkv_al = M.wkv_a + (size_t)l * LG_ * 2048;
  const float* wkv_bl = M.wkv_b + (size_t)l * SM_ * 2048;

  if (ph == 1) {          // pin (96 items)
    for (int it = wid; it < 96; it += NW) {
      f32x4 acc[4]; zero4(acc);
      if (it < 64) {
        int n0 = it * 16;
        mm64x16(M.clsb_sm + (size_t)r16 * SM_ + kv8, SM_,
                WTpin_al + (size_t)(n0 + r16) * SM_ + kv8, SM_, acc);
#pragma unroll
        for (int mt = 0; mt < 4; mt++)
#pragma unroll
          for (int rr = 0; rr < 4; rr++) {
            int r = mt * 16 + rbase + rr, c = n0 + r16;
            M.xbuf_a[(size_t)r * LG_ + c] = acc[mt][rr] + M.pinb_a[l * LG_ + c];
          }
      } else {
        int n0 = (it - 64) * 16;
        mm64x16(M.clsb_lg + (size_t)r16 * LG_ + kv8, LG_,
                WTpin_bl + (size_t)(n0 + r16) * LG_ + kv8, LG_, acc);
#pragma unroll
        for (int mt = 0; mt < 4; mt++)
#pragma unroll
          for (int rr = 0; rr < 4; rr++) {
            int r = mt * 16 + rbase + rr, c = n0 + r16;
            M.xbuf_b[(size_t)r * SM_ + c] = acc[mt][rr] + M.pinb_b[l * SM_ + c];
          }
      }
    }
  } else if (ph == 2) {   // LN (128 items)
    for (int it = wid; it < 128; it += NW) {
      const float* xp; unsigned short* op; const float* ng; const float* nb; int dim;
      if (it < 64) { xp = M.xbuf_a + (size_t)it * LG_; op = M.xnb_a + (size_t)it * LG_;
                     ng = M.ng_a + l * LG_; nb = M.nb_a + l * LG_; dim = LG_; }
      else { int r = it - 64; xp = M.xbuf_b + (size_t)r * SM_; op = M.xnb_b + (size_t)r * SM_;
             ng = M.ng_b + l * SM_; nb = M.nb_b + l * SM_; dim = SM_; }
      float s = 0.f, sq = 0.f;
      for (int c = lane; c < dim; c += 64) { float v = xp[c]; s += v; sq += v * v; }
#pragma unroll
      for (int o = 32; o >= 1; o >>= 1) { s += __shfl_down(s, o); sq += __shfl_down(sq, o); }
      s = __shfl(s, 0); sq = __shfl(sq, 0);
      float mu = s / dim;
      float rv = rsqrtf(sq / dim - mu * mu + 1e-5f);
      for (int c = lane; c < dim; c += 64)
        op[c] = f2b((xp[c] - mu) * rv * ng[c] + nb[c]);
    }
  } else if (ph == 3) {   // q + kv_cls (384 items)
    for (int it = wid; it < 384; it += NW) {
      f32x4 acc[4]; zero4(acc);
      if (it < 64) {
        int n0 = it * 16;
        mm64x16(M.xnb_a + (size_t)r16 * LG_ + kv8, LG_,
                WTwq_al + (size_t)(n0 + r16) * LG_ + kv8, LG_, acc);
#pragma unroll
        for (int mt = 0; mt < 4; mt++)
#pragma unroll
          for (int rr = 0; rr < 4; rr++)
            M.qbuf_a[(size_t)(mt * 16 + rbase + rr) * INNER_ + n0 + r16] = acc[mt][rr];
      } else if (it < 192) {
        int n0 = (it - 64) * 16;
        mm64x16(M.xnb_a + (size_t)r16 * LG_ + kv8, LG_,
                WTkv_al + (size_t)(n0 + r16) * LG_ + kv8, LG_, acc);
#pragma unroll
        for (int mt = 0; mt < 4; mt++)
#pragma unroll
          for (int rr = 0; rr < 4; rr++)
            M.kvc_a[(size_t)(mt * 16 + rbase + rr) * 2048 + n0 + r16] = acc[mt][rr];
      } else if (it < 256) {
        int n0 = (it - 192) * 16;
        mm64x16(M.xnb_b + (size_t)r16 * SM_ + kv8, SM_,
                WTwq_bl + (size_t)(n0 + r16) * SM_ + kv8, SM_, acc);
#pragma unroll
        for (int mt = 0; mt < 4; mt++)
#pragma unroll
          for (int rr = 0; rr < 4; rr++)
            M.qbuf_b[(size_t)(mt * 16 + rbase + rr) * INNER_ + n0 + r16] = acc[mt][rr];
      } else {
        int n0 = (it - 256) * 16;
        mm64x16(M.xnb_b + (size_t)r16 * SM_ + kv8, SM_,
                WTkv_bl + (size_t)(n0 + r16) * SM_ + kv8, SM_, acc);
#pragma unroll
        for (int mt = 0; mt < 4; mt++)
#pragma unroll
          for (int rr = 0; rr < 4; rr++)
            M.kvc_b[(size_t)(mt * 16 + rbase + rr) * 2048 + n0 + r16] = acc[mt][rr];
      }
    }
  } else if (ph == 4) {   // q~ (f32 VALU, LDS-staged; 384 block-items)
    __shared__ float qs[64][65];
    __shared__ float wsm[64][65];
    for (int itb = bId; itb < 384; itb += nB) {
      const float* qbuf; const float* wkv; unsigned short* qt; int dout, ct, h;
      if (itb < 256) { qbuf = M.qbuf_a; wkv = wkv_al; qt = M.qt_a; dout = LG_;
                       h = itb >> 4; ct = itb & 15; }
      else { int i2 = itb - 256; qbuf = M.qbuf_b; wkv = wkv_bl; qt = M.qt_b; dout = SM_;
             h = i2 >> 3; ct = i2 & 7; }
      for (int i = tid; i < 64 * 64; i += 256) {
        int b = i >> 6, d = i & 63;
        qs[b][d] = qbuf[(size_t)b * INNER_ + h * 64 + d];
      }
      for (int i = tid; i < 64 * 64; i += 256) {
        int c = i >> 6, d = i & 63;
        wsm[c][d] = wkv[(size_t)(ct * 64 + c) * 2048 + h * 64 + d];
      }
      __syncthreads();
      int b = tid & 63, w = tid >> 6;
      for (int c = w; c < 64; c += 4) {
        float s = 0.f;
#pragma unroll
        for (int d = 0; d < 64; d++) s += qs[b][d] * wsm[c][d];
        qt[((size_t)b * 16 + h) * dout + ct * 64 + c] = f2b(s);
      }
      __syncthreads();
    }
  } else if (ph == 5) {   // S (2560 items)
    for (int it = wid; it < 2560; it += NW) {
      if (it < 896) {
        int bb = it / 14, jt = it - bb * 14;
        f32x4 acc = mm16x16(M.qt_a + ((size_t)bb * 16 + r16) * LG_ + kv8,
                            M.Abf_lg + ((size_t)bb * NLG_ + jt * 16 + r16) * LG_ + kv8, LG_);
#pragma unroll
        for (int rr = 0; rr < 4; rr++)
          M.S_a[((size_t)bb * 16 + rbase + rr) * SSTR + jt * 16 + r16] = acc[rr];
      } else {
        int it2 = it - 896;
        int bb = it2 / 26, jt = it2 - bb * 26;
        f32x4 acc = mm16x16(M.qt_b + ((size_t)bb * 16 + r16) * SM_ + kv8,
                            M.Abf_sm + ((size_t)bb * NSM_ + jt * 16 + r16) * SM_ + kv8, SM_);
#pragma unroll
        for (int rr = 0; rr < 4; rr++)
          M.S_b[((size_t)bb * 16 + rbase + rr) * SSTR + jt * 16 + r16] = acc[rr];
      }
    }
  } else if (ph == 6) {   // softmax (2048 items)
    for (int it = wid; it < 2048; it += NW) {
      const float* Sp; unsigned short* pp; float* pcls; const float* qb; const float* kvc;
      int bb, h, Nctx, Npad;
      if (it < 1024) {
        bb = it >> 4; h = it & 15; Nctx = NLG_; Npad = 224;
        Sp = M.S_a + ((size_t)bb * 16 + h) * SSTR; pp = M.p_a + ((size_t)bb * 16 + h) * 224;
        pcls = M.pcls_a; qb = M.qbuf_a; kvc = M.kvc_a;
      } else {
        int i2 = it - 1024; bb = i2 >> 4; h = i2 & 15; Nctx = NSM_; Npad = 416;
        Sp = M.S_b + ((size_t)bb * 16 + h) * SSTR; pp = M.p_b + ((size_t)bb * 16 + h) * 416;
        pcls = M.pcls_b; qb = M.qbuf_b; kvc = M.kvc_b;
      }
      float sc = qb[(size_t)bb * INNER_ + h * 64 + lane] * kvc[(size_t)bb * 2048 + h * 64 + lane];
#pragma unroll
      for (int o = 32; o >= 1; o >>= 1) sc += __shfl_down(sc, o);
      sc = __shfl(sc, 0) * 0.125f;
      float sv[7]; float mr = -1e30f;
#pragma unroll
      for (int ji = 0; ji < 7; ji++) {
        int j = ji * 64 + lane;
        sv[ji] = (j < Nctx) ? Sp[j] * 0.125f : -1e30f;
        mr = fmaxf(mr, sv[ji]);
      }
#pragma unroll
      for (int o = 32; o >= 1; o >>= 1) mr = fmaxf(mr, __shfl_down(mr, o));
      mr = __shfl(mr, 0);
      const float m = fmaxf(mr, sc);
      float es = 0.f;
#pragma unroll
      for (int ji = 0; ji < 7; ji++) {
        int j = ji * 64 + lane;
        float e = (j < Nctx) ? expf(sv[ji] - m) : 0.f;
        sv[ji] = e; es += e;
      }
#pragma unroll
      for (int o = 32; o >= 1; o >>= 1) es += __shfl_down(es, o);
      es = __shfl(es, 0);
      const float ecls = expf(sc - m);
      const float inv = 1.f / (es + ecls);
#pragma unroll
      for (int ji = 0; ji < 7; ji++) {
        int j = ji * 64 + lane;
        if (j < Npad) pp[j] = (j < Nctx) ? f2b(sv[ji] * inv) : (unsigned short)0;
      }
      if (lane == 0) pcls[bb * 16 + h] = ecls * inv;
    }
  } else if (ph == 7) {   // u (6144 items)
    for (int it = wid; it < 6144; it += NW) {
      if (it < 4096) {
        int bb = it >> 6, ct = it & 63;
        f32x4 acc = mm16x16(M.p_a + ((size_t)bb * 16 + r16) * 224 + kv8,
                            M.xT_lg + ((size_t)bb * LG_ + ct * 16 + r16) * 224 + kv8, 224);
#pragma unroll
        for (int rr = 0; rr < 4; rr++)
          M.u_a[((size_t)bb * 16 + rbase + rr) * LG_ + ct * 16 + r16] = f2b(acc[rr]);
      } else {
        int it2 = it - 4096;
        int bb = it2 >> 5, ct = it2 & 31;
        f32x4 acc = mm16x16(M.p_b + ((size_t)bb * 16 + r16) * 416 + kv8,
                            M.xT_sm + ((size_t)bb * SM_ + ct * 16 + r16) * 416 + kv8, 416);
#pragma unroll
        for (int rr = 0; rr < 4; rr++)
          M.u_b[((size_t)bb * 16 + rbase + rr) * SM_ + ct * 16 + r16] = f2b(acc[rr]);
      }
    }
  } else if (ph == 8) {   // o (128 items)
    for (int it = wid; it < 128; it += NW) {
      f32x4 acc[4]; zero4(acc);
      if (it < 64) {
        int h = it >> 2, dt = it & 3;
        mm64x16(M.u_a + ((size_t)r16 * 16 + h) * LG_ + kv8, 16 * LG_,
                WTkv_al + (size_t)(1024 + h * 64 + dt * 16 + r16) * LG_ + kv8, LG_, acc);
#pragma unroll
        for (int mt = 0; mt < 4; mt++)
#pragma unroll
          for (int rr = 0; rr < 4; rr++) {
            int bi = mt * 16 + rbase + rr, d = h * 64 + dt * 16 + r16;
            float v = acc[mt][rr] + M.pcls_a[bi * 16 + h] * M.kvc_a[(size_t)bi * 2048 + 1024 + d];
            M.ob_a[(size_t)bi * INNER_ + d] = f2b(v);
          }
      } else {
        int i2 = it - 64;
        int h = i2 >> 2, dt = i2 & 3;
        mm64x16(M.u_b + ((size_t)r16 * 16 + h) * SM_ + kv8, 16 * SM_,
                WTkv_bl + (size_t)(1024 + h * 64 + dt * 16 + r16) * SM_ + kv8, SM_, acc);
#pragma unroll
        for (int mt = 0; mt < 4; mt++)
#pragma unroll
          for (int rr = 0; rr < 4; rr++) {
            int bi = mt * 16 + rbase + rr, d = h * 64 + dt * 16 + r16;
            float v = acc[mt][rr] + M.pcls_b[bi * 16 + h] * M.kvc_b[(size_t)bi * 2048 + 1024 + d];
            M.ob_b[(size_t)bi * INNER_ + d] = f2b(v);
          }
      }
    }
  } else if (ph == 9) {   // wo (96 items)
    for (int it = wid; it < 96; it += NW) {
      f32x4 acc[4]; zero4(acc);
      if (it < 64) {
        int n0 = it * 16;
        mm64x16(M.ob_a + (size_t)r16 * INNER_ + kv8, INNER_,
                WTwo_al + (size_t)(n0 + r16) * INNER_ + kv8, INNER_, acc);
#pragma unroll
        for (int mt = 0; mt < 4; mt++)
#pragma unroll
          for (int rr = 0; rr < 4; rr++) {
            int r = mt * 16 + rbase + rr, c = n0 + r16;
            M.t1_a[(size_t)r * LG_ + c] = f2b(acc[mt][rr] + M.wob_a[l * LG_ + c]);
          }
      } else {
        int n0 = (it - 64) * 16;
        mm64x16(M.ob_b + (size_t)r16 * INNER_ + kv8, INNER_,
                WTwo_bl + (size_t)(n0 + r16) * INNER_ + kv8, INNER_, acc);
#pragma unroll
        for (int mt = 0; mt < 4; mt++)
#pragma unroll
          for (int rr = 0; rr < 4; rr++) {
            int r = mt * 16 + rbase + rr, c = n0 + r16;
            M.t1_b[(size_t)r * SM_ + c] = f2b(acc[mt][rr] + M.wob_b[l * SM_ + c]);
          }
      }
    }
  } else if (ph == 10) {  // pout + residual (96 items)
    for (int it = wid; it < 96; it += NW) {
      f32x4 acc[4]; zero4(acc);
      if (it < 32) {
        int n0 = it * 16;
        mm64x16(M.t1_a + (size_t)r16 * LG_ + kv8, LG_,
                WTpout_al + (size_t)(n0 + r16) * LG_ + kv8, LG_, acc);
#pragma unroll
        for (int mt = 0; mt < 4; mt++)
#pragma unroll
          for (int rr = 0; rr < 4; rr++) {
            int r = mt * 16 + rbase + rr, c = n0 + r16;
            float v = acc[mt][rr] + M.poutb_a[l * SM_ + c] + M.cls_sm[(size_t)r * SM_ + c];
            M.cls_sm[(size_t)r * SM_ + c] = v;
            M.clsb_sm[(size_t)r * SM_ + c] = f2b(v);
          }
      } else {
        int n0 = (it - 32) * 16;
        mm64x16(M.t1_b + (size_t)r16 * SM_ + kv8, SM_,
                WTpout_bl + (size_t)(n0 + r16) * SM_ + kv8, SM_, acc);
#pragma unroll
        for (int mt = 0; mt < 4; mt++)
#pragma unroll
          for (int rr = 0; rr < 4; rr++) {
            int r = mt * 16 + rbase + rr, c = n0 + r16;
            float v = acc[mt][rr] + M.poutb_b[l * LG_ + c] + M.cls_lg[(size_t)r * LG_ + c];
            M.cls_lg[(size_t)r * LG_ + c] = v;
            M.clsb_lg[(size_t)r * LG_ + c] = f2b(v);
          }
      }
    }
  } else {                // ph == 11: final cls rows -> out
    float* out_lg = M.out + (size_t)B_ * (NSM_ + 1) * SM_;
    for (int it = wid; it < 128; it += NW) {
      if (it < 64) {
        for (int c = lane; c < SM_; c += 64)
          M.out[(size_t)it * (NSM_ + 1) * SM_ + c] = M.cls_sm[(size_t)it * SM_ + c];
      } else {
        int bb = it - 64;
        for (int c = lane; c < LG_; c += 64)
          out_lg[(size_t)bb * (NLG_ + 1) * LG_ + c] = M.cls_lg[(size_t)bb * LG_ + c];
      }
    }
  }
}

// ------------------------------ kernels ------------------------------------
__global__ __launch_bounds__(256, 4) void mega(MegaArgs M) {
  cg::grid_group grid = cg::this_grid();
  const int NW = gridDim.x * 4;
  const int wid = blockIdx.x * 4 + (threadIdx.x >> 6);
  for (int l = 0; l < 4; l++) {
    for (int ph = 1; ph <= 10; ph++) {
      run_phase(M, l, ph, wid, NW, blockIdx.x, gridDim.x, threadIdx.x);
      grid.sync();
    }
  }
  run_phase(M, 0, 11, wid, NW, blockIdx.x, gridDim.x, threadIdx.x);
}

__global__ __launch_bounds__(256, 4) void phase_k(MegaArgs M, int l, int ph) {
  const int NW = gridDim.x * 4;
  const int wid = blockIdx.x * 4 + (threadIdx.x >> 6);
  run_phase(M, l, ph, wid, NW, blockIdx.x, gridDim.x, threadIdx.x);
}

// ================================ host =====================================
extern "C" void kernel_launch(void* const* d_in, const int* in_sizes, int n_in,
                              void* d_out, int out_size, void* d_ws, size_t ws_size,
                              hipStream_t stream) {
  const float* sm_tokens = (const float*)d_in[0];
  const float* lg_tokens = (const float*)d_in[1];
  const float* a_pin_w  = (const float*)d_in[2];  const float* a_pin_b  = (const float*)d_in[3];
  const float* a_ng     = (const float*)d_in[4];  const float* a_nb     = (const float*)d_in[5];
  const float* a_wq     = (const float*)d_in[6];  const float* a_wkv    = (const float*)d_in[7];
  const float* a_wo     = (const float*)d_in[8];  const float* a_wob    = (const float*)d_in[9];
  const float* a_pout_w = (const float*)d_in[10]; const float* a_pout_b = (const float*)d_in[11];
  const float* b_pin_w  = (const float*)d_in[12]; const float* b_pin_b  = (const float*)d_in[13];
  const float* b_ng     = (const float*)d_in[14]; const float* b_nb     = (const float*)d_in[15];
  const float* b_wq     = (const float*)d_in[16]; const float* b_wkv    = (const float*)d_in[17];
  const float* b_wo     = (const float*)d_in[18]; const float* b_wob    = (const float*)d_in[19];
  const float* b_pout_w = (const float*)d_in[20]; const float* b_pout_b = (const float*)d_in[21];

  float* out = (float*)d_out;
  char* ws = (char*)d_ws;
  size_t off = 0;
  auto alloc = [&](size_t bytes) -> void* {
    void* pt = ws + off;
    off += (bytes + 255) & ~(size_t)255;
    return pt;
  };
  unsigned short* Abf_lg = (unsigned short*)alloc(((size_t)B_ * NLG_ + 32) * LG_ * 2);
  unsigned short* Abf_sm = (unsigned short*)alloc(((size_t)B_ * NSM_ + 32) * SM_ * 2);
  unsigned short* xT_lg  = (unsigned short*)alloc((size_t)B_ * LG_ * 224 * 2);
  unsigned short* xT_sm  = (unsigned short*)alloc((size_t)B_ * SM_ * 416 * 2);
  unsigned short* WTkv_a = (unsigned short*)alloc((size_t)4 * 2048 * LG_ * 2);
  unsigned short* WTkv_b = (unsigned short*)alloc((size_t)4 * 2048 * SM_ * 2);
  unsigned short* WTpin_a = (unsigned short*)alloc((size_t)4 * SM_ * LG_ * 2);
  unsigned short* WTpin_b = (unsigned short*)alloc((size_t)4 * LG_ * SM_ * 2);
  unsigned short* WTwq_a  = (unsigned short*)alloc((size_t)4 * LG_ * INNER_ * 2);
  unsigned short* WTwq_b  = (unsigned short*)alloc((size_t)4 * SM_ * INNER_ * 2);
  unsigned short* WTwo_a  = (unsigned short*)alloc((size_t)4 * INNER_ * LG_ * 2);
  unsigned short* WTwo_b  = (unsigned short*)alloc((size_t)4 * INNER_ * SM_ * 2);
  unsigned short* WTpout_a = (unsigned short*)alloc((size_t)4 * LG_ * SM_ * 2);
  unsigned short* WTpout_b = (unsigned short*)alloc((size_t)4 * SM_ * LG_ * 2);
  unsigned short* qt_a = (unsigned short*)alloc((size_t)B_ * 16 * LG_ * 2);
  unsigned short* qt_b = (unsigned short*)alloc((size_t)B_ * 16 * SM_ * 2);
  float* S_a = (float*)alloc((size_t)B_ * 16 * SSTR * 4);
  float* S_b = (float*)alloc((size_t)B_ * 16 * SSTR * 4);
  unsigned short* p_a = (unsigned short*)alloc((size_t)B_ * 16 * 224 * 2);
  unsigned short* p_b = (unsigned short*)alloc((size_t)B_ * 16 * 416 * 2);
  unsigned short* u_a  = (unsigned short*)alloc((size_t)B_ * 16 * LG_ * 2);
  unsigned short* u_b  = (unsigned short*)alloc((size_t)B_ * 16 * SM_ * 2);
  float* pcls_a = (float*)alloc((size_t)B_ * 16 * 4);
  float* pcls_b = (float*)alloc((size_t)B_ * 16 * 4);
  float* cls_sm = (float*)alloc((size_t)B_ * SM_ * 4);
  float* cls_lg = (float*)alloc((size_t)B_ * LG_ * 4);
  unsigned short* clsb_sm = (unsigned short*)alloc((size_t)B_ * SM_ * 2);
  unsigned short* clsb_lg = (unsigned short*)alloc((size_t)B_ * LG_ * 2);
  float* xbuf_a = (float*)alloc((size_t)B_ * LG_ * 4);
  float* xbuf_b = (float*)alloc((size_t)B_ * SM_ * 4);
  unsigned short* xnb_a = (unsigned short*)alloc((size_t)B_ * LG_ * 2);
  unsigned short* xnb_b = (unsigned short*)alloc((size_t)B_ * SM_ * 2);
  float* qbuf_a = (float*)alloc((size_t)B_ * INNER_ * 4);
  float* qbuf_b = (float*)alloc((size_t)B_ * INNER_ * 4);
  float* kvc_a  = (float*)alloc((size_t)B_ * 2048 * 4);
  float* kvc_b  = (float*)alloc((size_t)B_ * 2048 * 4);
  unsigned short* ob_a = (unsigned short*)alloc((size_t)B_ * INNER_ * 2);
  unsigned short* ob_b = (unsigned short*)alloc((size_t)B_ * INNER_ * 2);
  unsigned short* t1_a = (unsigned short*)alloc((size_t)B_ * LG_ * 2);
  unsigned short* t1_b = (unsigned short*)alloc((size_t)B_ * SM_ * 2);
  (void)ws_size; (void)in_sizes; (void)n_in; (void)out_size;

  const size_t sm_elems = (size_t)B_ * (NSM_ + 1) * SM_;

  // ---- setup
  CC2 ca{sm_tokens, out, Abf_sm, cls_sm, clsb_sm, NSM_ + 1, SM_ / 4, 7,
         (int)((size_t)B_ * (NSM_ + 1) * SM_ / 4)};
  CC2 cb{lg_tokens, out + sm_elems, Abf_lg, cls_lg, clsb_lg, NLG_ + 1, LG_ / 4, 8,
         (int)((size_t)B_ * (NLG_ + 1) * LG_ / 4)};
  copy_cvt2<<<2048, 256, 0, stream>>>(ca, cb);
  TXArgs txa{Abf_lg, xT_lg, NLG_, LG_, 224, LG_ / 64, 4, B_ * (LG_ / 64) * 4};
  TXArgs txb{Abf_sm, xT_sm, NSM_, SM_, 416, SM_ / 64, 7, B_ * (SM_ / 64) * 7};
  transpose_x2<<<txa.nblk + txb.nblk, dim3(64, 4), 0, stream>>>(txa, txb);
  WTArgs W;
  W.d[0] = {a_wkv,    WTkv_a,   LG_, 2048};
  W.d[1] = {b_wkv,    WTkv_b,   SM_, 2048};
  W.d[2] = {a_pin_w,  WTpin_a,  SM_, LG_};
  W.d[3] = {b_pin_w,  WTpin_b,  LG_, SM_};
  W.d[4] = {a_wq,     WTwq_a,   LG_, INNER_};
  W.d[5] = {b_wq,     WTwq_b,   SM_, INNER_};
  W.d[6] = {a_wo,     WTwo_a,   INNER_, LG_};
  W.d[7] = {b_wo,     WTwo_b,   INNER_, SM_};
  W.d[8] = {a_pout_w, WTpout_a, LG_, SM_};
  W.d[9] = {b_pout_w, WTpout_b, SM_, LG_};
  W.cum[0] = 0;
  for (int i = 0; i < 10; i++)
    W.cum[i + 1] = W.cum[i] + (W.d[i].K / 64) * (W.d[i].N / 64) * 4;
  wtrans_all<<<W.cum[10], 256, 0, stream>>>(W);

  // ---- main chain
  MegaArgs MA;
  MA.Abf_lg = Abf_lg; MA.Abf_sm = Abf_sm; MA.xT_lg = xT_lg; MA.xT_sm = xT_sm;
  MA.WTpin_a = WTpin_a; MA.WTpin_b = WTpin_b; MA.WTwq_a = WTwq_a; MA.WTwq_b = WTwq_b;
  MA.WTkv_a = WTkv_a; MA.WTkv_b = WTkv_b; MA.WTwo_a = WTwo_a; MA.WTwo_b = WTwo_b;
  MA.WTpout_a = WTpout_a; MA.WTpout_b = WTpout_b;
  MA.wkv_a = a_wkv; MA.wkv_b = b_wkv;
  MA.pinb_a = a_pin_b; MA.ng_a = a_ng; MA.nb_a = a_nb; MA.wob_a = a_wob; MA.poutb_a = a_pout_b;
  MA.pinb_b = b_pin_b; MA.ng_b = b_ng; MA.nb_b = b_nb; MA.wob_b = b_wob; MA.poutb_b = b_pout_b;
  MA.cls_sm = cls_sm; MA.cls_lg = cls_lg; MA.clsb_sm = clsb_sm; MA.clsb_lg = clsb_lg;
  MA.xbuf_a = xbuf_a; MA.xbuf_b = xbuf_b; MA.xnb_a = xnb_a; MA.xnb_b = xnb_b;
  MA.qbuf_a = qbuf_a; MA.qbuf_b = qbuf_b;
  MA.kvc_a = kvc_a; MA.kvc_b = kvc_b; MA.qt_a = qt_a; MA.qt_b = qt_b;
  MA.S_a = S_a; MA.S_b = S_b; MA.p_a = p_a; MA.p_b = p_b;
  MA.pcls_a = pcls_a; MA.pcls_b = pcls_b;
  MA.u_a = u_a; MA.u_b = u_b; MA.ob_a = ob_a; MA.ob_b = ob_b; MA.t1_a = t1_a; MA.t1_b = t1_b;
  MA.out = out;

  // cooperative grid sized by the runtime's own occupancy calc (deterministic)
  int nbPerCU = 0;
  hipError_t qe = hipOccupancyMaxActiveBlocksPerMultiprocessor(&nbPerCU, (const void*)mega, 256, 0);
  int grid = (qe == hipSuccess && nbPerCU > 0) ? nbPerCU * 256 : 0;
  if (grid > 960) grid = 960;
  hipError_t err = hipErrorUnknown;
  if (grid >= 8) {
    void* kparams[] = {(void*)&MA};
    err = hipLaunchCooperativeKernel((const void*)mega, dim3(grid), dim3(256), kparams, 0, stream);
  }
  if (err != hipSuccess) {
    // fallback: identical phase code, plain dispatches (guaranteed-correct path)
    for (int l = 0; l < 4; l++)
      for (int ph = 1; ph <= 10; ph++)
        phase_k<<<512, 256, 0, stream>>>(MA, l, ph);
    phase_k<<<512, 256, 0, stream>>>(MA, 0, 11);
  }
}

// Round 8
// 2636.516 us; speedup vs baseline: 1.3470x; 1.3470x over previous
//
#include <hip/hip_runtime.h>
#include <hip/hip_bf16.h>
#include <math.h>

#define B_     64
#define NSM_   400
#define NLG_   196
#define SM_    512
#define LG_    1024
#define INNER_ 1024
#define QTSTR  1032   // q~ / u LDS row stride (bf16): 2064B -> 4-bank row skew
#define PSTR   424    // p LDS row stride (bf16)
#define SST    424    // S LDS row stride (f32)

typedef __attribute__((ext_vector_type(8))) short bf16x8;
typedef __attribute__((ext_vector_type(4))) float f32x4;

__device__ __forceinline__ unsigned short f2b(float f) {
  unsigned u = __float_as_uint(f);
  u = u + 0x7FFFu + ((u >> 16) & 1u);   // RNE
  return (unsigned short)(u >> 16);
}
__device__ __forceinline__ float b2f(unsigned short b) {
  return __uint_as_float(((unsigned)b) << 16);
}

// ============================ setup kernels ================================

// tokens: full f32 copy to out + patch rows -> contiguous bf16
struct CC2 { const float* tok; float* out; unsigned short* abf; int Np1, nf4, shift, tot4; };
__global__ __launch_bounds__(256) void copy_cvt2(CC2 a, CC2 b) {
  const int total = a.tot4 + b.tot4;
  for (int i = blockIdx.x * 256 + threadIdx.x; i < total; i += gridDim.x * 256) {
    CC2 g; int idx;
    if (i < a.tot4) { g = a; idx = i; } else { g = b; idx = i - a.tot4; }
    int rowg = idx >> g.shift, t = idx & ((1 << g.shift) - 1);
    int bb = rowg / g.Np1, row = rowg - bb * g.Np1;
    const float4 v = ((const float4*)g.tok)[idx];
    ((float4*)g.out)[idx] = v;
    if (row > 0) {
      ushort4 w2; w2.x = f2b(v.x); w2.y = f2b(v.y); w2.z = f2b(v.z); w2.w = f2b(v.w);
      ((ushort4*)g.abf)[(size_t)(bb * (g.Np1 - 1) + row - 1) * g.nf4 + t] = w2;
    }
  }
}

// xbf [B*Nctx][dout] bf16 -> xT [B][dout][xstride] bf16, zero pad j>=Nctx
struct TXArgs { const unsigned short* xbf; unsigned short* xT; int Nctx, dout, xstride, nx, ny, nblk; };
__global__ void transpose_x2(TXArgs ga, TXArgs gb) {
  __shared__ unsigned short tile[64][65];
  TXArgs g; int bx;
  if ((int)blockIdx.x < ga.nblk) { g = ga; bx = blockIdx.x; }
  else { g = gb; bx = blockIdx.x - ga.nblk; }
  int cx = bx % g.nx; int rem = bx / g.nx;
  int jy = rem % g.ny; int b = rem / g.ny;
  int jt = jy * 64, ct = cx * 64;
  int tx = threadIdx.x, ty = threadIdx.y;  // (64,4)
  for (int r = ty; r < 64; r += 4) {
    int j = jt + r;
    tile[r][tx] = (j < g.Nctx) ? g.xbf[((size_t)b * g.Nctx + j) * g.dout + ct + tx]
                               : (unsigned short)0;
  }
  __syncthreads();
  for (int r = ty; r < 64; r += 4) {
    int col = jt + tx;
    if (col < g.xstride)
      g.xT[((size_t)b * g.dout + ct + r) * g.xstride + col] = tile[tx][r];
  }
}

// flat f32 -> bf16 convert for all weights (straight (K,N) layout, no transpose)
struct CVD { const float* src; unsigned short* dst; };
struct CVArgs { CVD d[10]; int cum[11]; };
__global__ __launch_bounds__(256) void wcvt(CVArgs C) {
  const int total = C.cum[10];
  for (int i = blockIdx.x * 256 + threadIdx.x; i < total; i += gridDim.x * 256) {
    int di = 0;
    while (i >= C.cum[di + 1]) di++;
    int idx = i - C.cum[di];
    const float4 v = ((const float4*)C.d[di].src)[idx];
    ushort4 w2; w2.x = f2b(v.x); w2.y = f2b(v.y); w2.z = f2b(v.z); w2.w = f2b(v.w);
    ((ushort4*)C.d[di].dst)[idx] = w2;
  }
}

// ============================== mega2 ======================================
// 128 fully independent chains: block = (branch, b). No grid-level sync at all.
struct M2Args {
  const float *sm_tok, *lg_tok;
  const unsigned short *Abf_lg, *Abf_sm, *xT_lg, *xT_sm;
  const unsigned short *wpin_a, *wq_a, *wkv_a, *wo_a, *wpout_a;   // bf16 (K,N), 4 layers contiguous
  const unsigned short *wpin_b, *wq_b, *wkv_b, *wo_b, *wpout_b;
  const float *pinb_a, *ng_a, *nb_a, *wob_a, *poutb_a;
  const float *pinb_b, *ng_b, *nb_b, *wob_b, *poutb_b;
  float *out;
};

__global__ __launch_bounds__(1024, 1) void mega2(M2Args A) {
  __shared__ float cls_s[1024];
  __shared__ float xb_s[1024];
  __shared__ unsigned short xn_s[1024];
  __shared__ float q_s[1024];
  __shared__ float kv_s[2048];
  __shared__ unsigned short qt_s[16 * QTSTR];
  __shared__ float S_s[16 * SST];
  __shared__ unsigned short p_s[16 * PSTR];
  __shared__ unsigned short u_s[16 * QTSTR];
  __shared__ unsigned short o_s[1024];
  __shared__ unsigned short t1_s[1024];
  __shared__ float pcls_s[16];
  __shared__ float red1_s[16], red2_s[16], mv_s[2];

  const int bid = blockIdx.x;
  const int br = bid >> 6;      // 0: branch a (sm cls, lg ctx), 1: branch b
  const int b  = bid & 63;
  const int tid = threadIdx.x;
  const int lane = tid & 63, w = tid >> 6;
  const int r16 = lane & 15, kv8 = (lane >> 4) * 8, rbase = (lane >> 4) * 4;

  const int din  = br ? LG_ : SM_;
  const int dout = br ? SM_ : LG_;
  const int Nctx = br ? NSM_ : NLG_;
  const int Npad = br ? 416 : 224;
  const int NTJ  = Npad >> 4;
  const int NTC  = dout >> 4;
  const int dsh  = br ? 9 : 10;          // log2(dout)
  const float* tok = br ? A.lg_tok : A.sm_tok;
  const int Np1 = br ? (NLG_ + 1) : (NSM_ + 1);
  const unsigned short* Abf = br ? A.Abf_sm : A.Abf_lg;
  const unsigned short* xT  = br ? A.xT_sm : A.xT_lg;
  const unsigned short* wpin0  = br ? A.wpin_b  : A.wpin_a;
  const unsigned short* wq0    = br ? A.wq_b    : A.wq_a;
  const unsigned short* wkv0   = br ? A.wkv_b   : A.wkv_a;
  const unsigned short* wo0    = br ? A.wo_b    : A.wo_a;
  const unsigned short* wpout0 = br ? A.wpout_b : A.wpout_a;
  const float* pinb0  = br ? A.pinb_b  : A.pinb_a;
  const float* ng0    = br ? A.ng_b    : A.ng_a;
  const float* nb0    = br ? A.nb_b    : A.nb_a;
  const float* wob0   = br ? A.wob_b   : A.wob_a;
  const float* poutb0 = br ? A.poutb_b : A.poutb_a;

  // ---- load this chain's cls row (f32, directly from input tokens)
  for (int c = tid; c < din; c += 1024)
    cls_s[c] = tok[(size_t)b * Np1 * din + c];
  __syncthreads();

  for (int l = 0; l < 4; l++) {
    const unsigned short* wpin  = wpin0  + (size_t)l * din * dout;
    const unsigned short* wq    = wq0    + (size_t)l * dout * INNER_;
    const unsigned short* wkv   = wkv0   + (size_t)l * dout * 2048;
    const unsigned short* wo    = wo0    + (size_t)l * INNER_ * dout;
    const unsigned short* wpout = wpout0 + (size_t)l * dout * din;
    const float* pinb  = pinb0  + (size_t)l * dout;
    const float* ng    = ng0    + (size_t)l * dout;
    const float* nb    = nb0    + (size_t)l * dout;
    const float* wob   = wob0   + (size_t)l * dout;
    const float* poutb = poutb0 + (size_t)l * din;

    // ---- P1: x = cls @ Wpin + b   (gemv, coalesced over c)
    for (int c = tid; c < dout; c += 1024) {
      float f = pinb[c];
#pragma unroll 4
      for (int k = 0; k < din; k++) f += cls_s[k] * b2f(wpin[(size_t)k * dout + c]);
      xb_s[c] = f;
    }
    __syncthreads();

    // ---- P2: LayerNorm -> xn (bf16)
    {
      float s = 0.f, sq = 0.f;
      for (int c = tid; c < dout; c += 1024) { float v = xb_s[c]; s += v; sq += v * v; }
#pragma unroll
      for (int o = 32; o >= 1; o >>= 1) { s += __shfl_down(s, o); sq += __shfl_down(sq, o); }
      if (lane == 0) { red1_s[w] = s; red2_s[w] = sq; }
      __syncthreads();
      if (tid == 0) {
        float ts = 0.f, tq = 0.f;
#pragma unroll
        for (int i = 0; i < 16; i++) { ts += red1_s[i]; tq += red2_s[i]; }
        float mu = ts / dout;
        mv_s[0] = mu; mv_s[1] = rsqrtf(tq / dout - mu * mu + 1e-5f);
      }
      __syncthreads();
      float mu = mv_s[0], rv = mv_s[1];
      for (int c = tid; c < dout; c += 1024)
        xn_s[c] = f2b((xb_s[c] - mu) * rv * ng[c] + nb[c]);
    }
    __syncthreads();

    // ---- P3: q = xn @ Wq ; kv_cls = xn @ Wkv   (gemv, coalesced)
    for (int c = tid; c < INNER_; c += 1024) {
      float f = 0.f;
#pragma unroll 4
      for (int k = 0; k < dout; k++) f += b2f(xn_s[k]) * b2f(wq[(size_t)k * INNER_ + c]);
      q_s[c] = f;
    }
    for (int c = tid; c < 2048; c += 1024) {
      float f = 0.f;
#pragma unroll 4
      for (int k = 0; k < dout; k++) f += b2f(xn_s[k]) * b2f(wkv[(size_t)k * 2048 + c]);
      kv_s[c] = f;
    }
    __syncthreads();

    // ---- P4: q~[h][c] = sum_d q[h*64+d] * Wk[c][h*64+d]  (per-lane row streams)
    for (int idx = tid; idx < 16 * dout; idx += 1024) {
      int h = idx >> dsh, c = idx & (dout - 1);
      float f = 0.f;
      const unsigned short* wr = wkv + (size_t)c * 2048 + h * 64;
#pragma unroll 8
      for (int d = 0; d < 64; d++) f += q_s[h * 64 + d] * b2f(wr[d]);
      qt_s[h * QTSTR + c] = f2b(f);
    }
    __syncthreads();

    // ---- P5: S[h][j] = q~[h,:] . x[j,:]   (MFMA, M=16 heads, wave per j-tile)
    for (int jt = w; jt < NTJ; jt += 16) {
      f32x4 acc; acc[0] = 0.f; acc[1] = 0.f; acc[2] = 0.f; acc[3] = 0.f;
      const unsigned short* bp = Abf + ((size_t)b * Nctx + jt * 16 + r16) * dout + kv8;
      const unsigned short* ap = &qt_s[r16 * QTSTR + kv8];
#pragma unroll 4
      for (int k0 = 0; k0 < dout; k0 += 32)
        acc = __builtin_amdgcn_mfma_f32_16x16x32_bf16(*(const bf16x8*)&ap[k0],
                                                      *(const bf16x8*)&bp[k0], acc, 0, 0, 0);
#pragma unroll
      for (int rr = 0; rr < 4; rr++)
        S_s[(rbase + rr) * SST + jt * 16 + r16] = acc[rr];
    }
    __syncthreads();

    // ---- P6: softmax (wave w = head h)
    {
      const int h = w;
      float sc = q_s[h * 64 + lane] * kv_s[h * 64 + lane];
#pragma unroll
      for (int o = 32; o >= 1; o >>= 1) sc += __shfl_down(sc, o);
      sc = __shfl(sc, 0) * 0.125f;
      float mr = -1e30f;
      for (int j = lane; j < Nctx; j += 64) mr = fmaxf(mr, S_s[h * SST + j] * 0.125f);
#pragma unroll
      for (int o = 32; o >= 1; o >>= 1) mr = fmaxf(mr, __shfl_down(mr, o));
      mr = __shfl(mr, 0);
      const float m = fmaxf(mr, sc);
      float es = 0.f;
      for (int j = lane; j < Nctx; j += 64) es += expf(S_s[h * SST + j] * 0.125f - m);
#pragma unroll
      for (int o = 32; o >= 1; o >>= 1) es += __shfl_down(es, o);
      es = __shfl(es, 0);
      const float ecls = expf(sc - m);
      const float inv = 1.f / (es + ecls);
      for (int j = lane; j < Npad; j += 64)
        p_s[h * PSTR + j] = (j < Nctx) ? f2b(expf(S_s[h * SST + j] * 0.125f - m) * inv)
                                       : (unsigned short)0;
      if (lane == 0) pcls_s[h] = ecls * inv;
    }
    __syncthreads();

    // ---- P7: u[h][c] = p[h,:] . xT[c,:]   (MFMA, M=16 heads, wave per c-tile)
    for (int ct = w; ct < NTC; ct += 16) {
      f32x4 acc; acc[0] = 0.f; acc[1] = 0.f; acc[2] = 0.f; acc[3] = 0.f;
      const unsigned short* bp = xT + ((size_t)b * dout + ct * 16 + r16) * Npad + kv8;
      const unsigned short* ap = &p_s[r16 * PSTR + kv8];
#pragma unroll 4
      for (int k0 = 0; k0 < Npad; k0 += 32)
        acc = __builtin_amdgcn_mfma_f32_16x16x32_bf16(*(const bf16x8*)&ap[k0],
                                                      *(const bf16x8*)&bp[k0], acc, 0, 0, 0);
#pragma unroll
      for (int rr = 0; rr < 4; rr++)
        u_s[(rbase + rr) * QTSTR + ct * 16 + r16] = f2b(acc[rr]);
    }
    __syncthreads();

    // ---- P8: o[h*64+d] = u[h,:] . Wv[:, h*64+d] + pcls[h]*v_cls  (coalesced)
    {
      int h = tid >> 6, d = tid & 63;   // 1024 threads = exactly 16x64
      float f = pcls_s[h] * kv_s[1024 + tid];
      const unsigned short* wc = wkv + 1024 + tid;
#pragma unroll 4
      for (int c = 0; c < dout; c++) f += b2f(u_s[h * QTSTR + c]) * b2f(wc[(size_t)c * 2048]);
      o_s[tid] = f2b(f);
      (void)d;
    }
    __syncthreads();

    // ---- P9: t1 = o @ Wo + wob   (gemv, coalesced)
    for (int c = tid; c < dout; c += 1024) {
      float f = wob[c];
#pragma unroll 4
      for (int k = 0; k < INNER_; k++) f += b2f(o_s[k]) * b2f(wo[(size_t)k * dout + c]);
      t1_s[c] = f2b(f);
    }
    __syncthreads();

    // ---- P10: cls += t1 @ Wpout + poutb   (gemv, coalesced)
    for (int c = tid; c < din; c += 1024) {
      float f = poutb[c];
#pragma unroll 4
      for (int k = 0; k < dout; k++) f += b2f(t1_s[k]) * b2f(wpout[(size_t)k * din + c]);
      cls_s[c] += f;
    }
    __syncthreads();
  }

  // ---- write final cls row to out
  float* orow = br ? (A.out + (size_t)B_ * (NSM_ + 1) * SM_ + (size_t)b * (NLG_ + 1) * LG_)
                   : (A.out + (size_t)b * (NSM_ + 1) * SM_);
  for (int c = tid; c < din; c += 1024) orow[c] = cls_s[c];
}

// ================================ host =====================================
extern "C" void kernel_launch(void* const* d_in, const int* in_sizes, int n_in,
                              void* d_out, int out_size, void* d_ws, size_t ws_size,
                              hipStream_t stream) {
  const float* sm_tokens = (const float*)d_in[0];
  const float* lg_tokens = (const float*)d_in[1];
  const float* a_pin_w  = (const float*)d_in[2];  const float* a_pin_b  = (const float*)d_in[3];
  const float* a_ng     = (const float*)d_in[4];  const float* a_nb     = (const float*)d_in[5];
  const float* a_wq     = (const float*)d_in[6];  const float* a_wkv    = (const float*)d_in[7];
  const float* a_wo     = (const float*)d_in[8];  const float* a_wob    = (const float*)d_in[9];
  const float* a_pout_w = (const float*)d_in[10]; const float* a_pout_b = (const float*)d_in[11];
  const float* b_pin_w  = (const float*)d_in[12]; const float* b_pin_b  = (const float*)d_in[13];
  const float* b_ng     = (const float*)d_in[14]; const float* b_nb     = (const float*)d_in[15];
  const float* b_wq     = (const float*)d_in[16]; const float* b_wkv    = (const float*)d_in[17];
  const float* b_wo     = (const float*)d_in[18]; const float* b_wob    = (const float*)d_in[19];
  const float* b_pout_w = (const float*)d_in[20]; const float* b_pout_b = (const float*)d_in[21];

  float* out = (float*)d_out;
  char* ws = (char*)d_ws;
  size_t off = 0;
  auto alloc = [&](size_t bytes) -> void* {
    void* pt = ws + off;
    off += (bytes + 255) & ~(size_t)255;
    return pt;
  };
  unsigned short* Abf_lg = (unsigned short*)alloc(((size_t)B_ * NLG_ + 32) * LG_ * 2);
  unsigned short* Abf_sm = (unsigned short*)alloc(((size_t)B_ * NSM_ + 32) * SM_ * 2);
  unsigned short* xT_lg  = (unsigned short*)alloc((size_t)B_ * LG_ * 224 * 2);
  unsigned short* xT_sm  = (unsigned short*)alloc((size_t)B_ * SM_ * 416 * 2);
  unsigned short* wpin_a  = (unsigned short*)alloc((size_t)4 * SM_ * LG_ * 2);
  unsigned short* wq_a    = (unsigned short*)alloc((size_t)4 * LG_ * INNER_ * 2);
  unsigned short* wkv_a   = (unsigned short*)alloc((size_t)4 * LG_ * 2048 * 2);
  unsigned short* wo_a    = (unsigned short*)alloc((size_t)4 * INNER_ * LG_ * 2);
  unsigned short* wpout_a = (unsigned short*)alloc((size_t)4 * LG_ * SM_ * 2);
  unsigned short* wpin_b  = (unsigned short*)alloc((size_t)4 * LG_ * SM_ * 2);
  unsigned short* wq_b    = (unsigned short*)alloc((size_t)4 * SM_ * INNER_ * 2);
  unsigned short* wkv_b   = (unsigned short*)alloc((size_t)4 * SM_ * 2048 * 2);
  unsigned short* wo_b    = (unsigned short*)alloc((size_t)4 * INNER_ * SM_ * 2);
  unsigned short* wpout_b = (unsigned short*)alloc((size_t)4 * SM_ * LG_ * 2);
  (void)ws_size; (void)in_sizes; (void)n_in; (void)out_size;

  const size_t sm_elems = (size_t)B_ * (NSM_ + 1) * SM_;

  // ---- setup 1: token copy + patch bf16
  CC2 ca{sm_tokens, out, Abf_sm, NSM_ + 1, SM_ / 4, 7, (int)(sm_elems / 4)};
  CC2 cb{lg_tokens, out + sm_elems, Abf_lg, NLG_ + 1, LG_ / 4, 8,
         (int)((size_t)B_ * (NLG_ + 1) * LG_ / 4)};
  copy_cvt2<<<2048, 256, 0, stream>>>(ca, cb);
  // ---- setup 2: x^T (zero padded)
  TXArgs txa{Abf_lg, xT_lg, NLG_, LG_, 224, LG_ / 64, 4, B_ * (LG_ / 64) * 4};
  TXArgs txb{Abf_sm, xT_sm, NSM_, SM_, 416, SM_ / 64, 7, B_ * (SM_ / 64) * 7};
  transpose_x2<<<txa.nblk + txb.nblk, dim3(64, 4), 0, stream>>>(txa, txb);
  // ---- setup 3: all weights -> straight bf16
  CVArgs C;
  C.d[0] = {a_pin_w,  wpin_a};  C.d[1] = {a_wq, wq_a};   C.d[2] = {a_wkv, wkv_a};
  C.d[3] = {a_wo, wo_a};        C.d[4] = {a_pout_w, wpout_a};
  C.d[5] = {b_pin_w,  wpin_b};  C.d[6] = {b_wq, wq_b};   C.d[7] = {b_wkv, wkv_b};
  C.d[8] = {b_wo, wo_b};        C.d[9] = {b_pout_w, wpout_b};
  const int n4[10] = {4 * SM_ * LG_ / 4, 4 * LG_ * INNER_ / 4, 4 * LG_ * 2048 / 4,
                      4 * INNER_ * LG_ / 4, 4 * LG_ * SM_ / 4,
                      4 * LG_ * SM_ / 4, 4 * SM_ * INNER_ / 4, 4 * SM_ * 2048 / 4,
                      4 * INNER_ * SM_ / 4, 4 * SM_ * LG_ / 4};
  C.cum[0] = 0;
  for (int i = 0; i < 10; i++) C.cum[i + 1] = C.cum[i] + n4[i];
  wcvt<<<2048, 256, 0, stream>>>(C);

  // ---- the whole 4-layer chain: 128 independent blocks, no global sync
  M2Args MA;
  MA.sm_tok = sm_tokens; MA.lg_tok = lg_tokens;
  MA.Abf_lg = Abf_lg; MA.Abf_sm = Abf_sm; MA.xT_lg = xT_lg; MA.xT_sm = xT_sm;
  MA.wpin_a = wpin_a; MA.wq_a = wq_a; MA.wkv_a = wkv_a; MA.wo_a = wo_a; MA.wpout_a = wpout_a;
  MA.wpin_b = wpin_b; MA.wq_b = wq_b; MA.wkv_b = wkv_b; MA.wo_b = wo_b; MA.wpout_b = wpout_b;
  MA.pinb_a = a_pin_b; MA.ng_a = a_ng; MA.nb_a = a_nb; MA.wob_a = a_wob; MA.poutb_a = a_pout_b;
  MA.pinb_b = b_pin_b; MA.ng_b = b_ng; MA.nb_b = b_nb; MA.wob_b = b_wob; MA.poutb_b = b_pout_b;
  MA.out = out;
  mega2<<<128, 1024, 0, stream>>>(MA);
}

// Round 9
// 668.768 us; speedup vs baseline: 5.3102x; 3.9423x over previous
//
#include <hip/hip_runtime.h>
#include <hip/hip_bf16.h>
#include <math.h>

#define B_     64
#define NSM_   400
#define NLG_   196
#define SM_    512
#define LG_    1024
#define H_     16
#define DH_    64
#define INNER_ 1024
#define SSTR   424    // S row stride (f32)
#define PSTR   424    // p row stride (bf16)

typedef __attribute__((ext_vector_type(8))) short bf16x8;
typedef __attribute__((ext_vector_type(4))) float f32x4;

__device__ __forceinline__ unsigned short f2b(float f) {
  unsigned u = __float_as_uint(f);
  u = u + 0x7FFFu + ((u >> 16) & 1u);   // RNE
  return (unsigned short)(u >> 16);
}

// ============================ setup kernels ================================

// one pass over tokens: full f32 copy to out, patches->bf16, cls row -> f32+bf16
struct CCArgs {
  const float* tok; float* out; unsigned short* abf; float* cls; unsigned short* clsb;
  int Np1, dim, nblk;
};
__global__ __launch_bounds__(256) void copy_cvt(CCArgs Aa, CCArgs Bb) {
  CCArgs g; int bx;
  if ((int)blockIdx.x < Aa.nblk) { g = Aa; bx = blockIdx.x; }
  else { g = Bb; bx = blockIdx.x - Aa.nblk; }
  int b = bx / g.Np1, row = bx % g.Np1;
  int t = threadIdx.x;
  int nf4 = g.dim >> 2;
  if (t >= nf4) return;
  const float4 v = ((const float4*)g.tok)[(size_t)bx * nf4 + t];
  ((float4*)g.out)[(size_t)bx * nf4 + t] = v;
  ushort4 w2;
  w2.x = f2b(v.x); w2.y = f2b(v.y); w2.z = f2b(v.z); w2.w = f2b(v.w);
  if (row > 0) {
    *(ushort4*)&g.abf[((size_t)b * (g.Np1 - 1) + row - 1) * g.dim + t * 4] = w2;
  } else {
    ((float4*)g.cls)[(size_t)b * nf4 + t] = v;
    *(ushort4*)&g.clsb[(size_t)b * g.dim + t * 4] = w2;
  }
}

// xbf [B*Nctx][dout] bf16 -> xT [B][dout][xstride] bf16, zero pad j>=Nctx
struct TXArgs { const unsigned short* xbf; unsigned short* xT; int Nctx, dout, xstride, nx, ny, nblk; };
__global__ void transpose_x2(TXArgs ga, TXArgs gb) {
  __shared__ unsigned short tile[64][65];
  TXArgs g; int bx;
  if ((int)blockIdx.x < ga.nblk) { g = ga; bx = blockIdx.x; }
  else { g = gb; bx = blockIdx.x - ga.nblk; }
  int cx = bx % g.nx; int rem = bx / g.nx;
  int jy = rem % g.ny; int b = rem / g.ny;
  int jt = jy * 64, ct = cx * 64;
  int tx = threadIdx.x, ty = threadIdx.y;  // (64,4)
  for (int r = ty; r < 64; r += 4) {
    int j = jt + r;
    tile[r][tx] = (j < g.Nctx) ? g.xbf[((size_t)b * g.Nctx + j) * g.dout + ct + tx]
                               : (unsigned short)0;
  }
  __syncthreads();
  for (int r = ty; r < 64; r += 4) {
    int col = jt + tx;
    if (col < g.xstride)
      g.xT[((size_t)b * g.dout + ct + r) * g.xstride + col] = tile[tx][r];
  }
}

// all 10 weight transposes (f32 (L,K,N) -> bf16 (L,N,K)) in one dispatch
struct WTDesc { const float* src; unsigned short* dst; int K, N; };
struct WTArgs { WTDesc d[10]; int cum[11]; };
__global__ __launch_bounds__(256) void wtrans_all(WTArgs W) {
  __shared__ unsigned short tile[64][65];
  int bx = blockIdx.x, di = 0;
  while (bx >= W.cum[di + 1]) di++;
  int local = bx - W.cum[di];
  WTDesc g = W.d[di];
  int tn = g.N >> 6;
  int tpl = tn * (g.K >> 6);
  int layer = local / tpl, rem = local % tpl;
  int kt = (rem / tn) * 64, nt = (rem % tn) * 64;
  const float* wp = g.src + (size_t)layer * g.K * g.N;
  unsigned short* op = g.dst + (size_t)layer * g.K * g.N;
  int tx = threadIdx.x & 63, ty = threadIdx.x >> 6;
  for (int r = ty; r < 64; r += 4)
    tile[r][tx] = f2b(wp[(size_t)(kt + r) * g.N + nt + tx]);
  __syncthreads();
  for (int r = ty; r < 64; r += 4)
    op[(size_t)(nt + r) * g.K + kt + tx] = tile[tx][r];
}

// ========== wide small GEMM: M=64, one 16-col tile per 256-thr block =======
// wave w handles M-rows [w*16, w*16+16): 4 waves/block -> latency hidden
struct SGDesc {
  const unsigned short* A;    // [64][K] bf16
  const unsigned short* WT;   // [N][K] bf16
  const float* bias;          // [N] or null
  float* Cf;                  // f32 out [64][N] or null
  unsigned short* Cbf;        // bf16 out [64][N] or null
  const float* Rf;            // residual f32 in [64][N] or null
  int K, N;
};
struct SGArgs { SGDesc d[4]; int cum[5]; int nd; };
__global__ __launch_bounds__(256) void sg_wide(SGArgs W) {
  int bx = blockIdx.x, di = 0;
  while (di < W.nd - 1 && bx >= W.cum[di + 1]) di++;
  SGDesc g = W.d[di];
  const int n0 = (bx - W.cum[di]) * 16;
  const int tid = threadIdx.x;
  const int lane = tid & 63, mt = tid >> 6;
  const int r16 = lane & 15, kv8 = (lane >> 4) * 8;
  f32x4 acc; acc[0] = 0.f; acc[1] = 0.f; acc[2] = 0.f; acc[3] = 0.f;
  const unsigned short* wp = &g.WT[(size_t)(n0 + r16) * g.K + kv8];
  const unsigned short* ap = &g.A[(size_t)(mt * 16 + r16) * g.K + kv8];
  const int K = g.K;
#pragma unroll 4
  for (int k0 = 0; k0 < K; k0 += 32)
    acc = __builtin_amdgcn_mfma_f32_16x16x32_bf16(*(const bf16x8*)&ap[k0],
                                                  *(const bf16x8*)&wp[k0], acc, 0, 0, 0);
  const int rbase = (lane >> 4) * 4;
#pragma unroll
  for (int rr = 0; rr < 4; rr++) {
    int r = mt * 16 + rbase + rr, c = n0 + r16;
    float v = acc[rr];
    if (g.bias) v += g.bias[c];
    if (g.Rf) v += g.Rf[(size_t)r * g.N + c];
    if (g.Cf)  g.Cf[(size_t)r * g.N + c] = v;
    if (g.Cbf) g.Cbf[(size_t)r * g.N + c] = f2b(v);
  }
}

// =============================== layernorm =================================
struct LNArgs { const float* x; unsigned short* xnb; const float* ng; const float* nb; int dim; };
__global__ __launch_bounds__(256) void ln2(LNArgs la, LNArgs lb) {
  LNArgs g = ((int)blockIdx.x < 64) ? la : lb;
  int b = blockIdx.x & 63, t = threadIdx.x;
  __shared__ float rs[4], rq[4], bc[2];
  const float* xp = g.x + (size_t)b * g.dim;
  float s = 0.f, sq = 0.f;
  for (int c = t; c < g.dim; c += 256) {
    float v = xp[c];
    s += v; sq += v * v;
  }
#pragma unroll
  for (int off = 32; off >= 1; off >>= 1) {
    s += __shfl_down(s, off);
    sq += __shfl_down(sq, off);
  }
  int w = t >> 6;
  if ((t & 63) == 0) { rs[w] = s; rq[w] = sq; }
  __syncthreads();
  if (t == 0) {
    float ts = rs[0] + rs[1] + rs[2] + rs[3];
    float tq = rq[0] + rq[1] + rq[2] + rq[3];
    float mu = ts / g.dim;
    float var = tq / g.dim - mu * mu;
    bc[0] = mu; bc[1] = rsqrtf(var + 1e-5f);
  }
  __syncthreads();
  float mu = bc[0], r = bc[1];
  for (int c = t; c < g.dim; c += 256)
    g.xnb[(size_t)b * g.dim + c] = f2b((xp[c] - mu) * r * g.ng[c] + g.nb[c]);
}

// ============================ q~ (merged) ==================================
__global__ __launch_bounds__(256) void qtilde2(const float* qa, const float* wkva,
                                               unsigned short* qta, int nxa,
                                               const float* qb, const float* wkvb,
                                               unsigned short* qtb) {
  const float* qbuf; const float* wkv; unsigned short* qt; int dout, ct;
  if ((int)blockIdx.x < nxa) { qbuf = qa; wkv = wkva; qt = qta; dout = 1024; ct = blockIdx.x; }
  else { qbuf = qb; wkv = wkvb; qt = qtb; dout = 512; ct = blockIdx.x - nxa; }
  const int h = blockIdx.y;
  __shared__ float qs[64][64];
  __shared__ float wsm[64][65];
  int t = threadIdx.x;
  for (int i = t; i < 64 * 64; i += 256) {
    int b = i >> 6, d = i & 63;
    qs[b][d] = qbuf[(size_t)b * INNER_ + h * 64 + d];
  }
  for (int i = t; i < 64 * 64; i += 256) {
    int c = i >> 6, d = i & 63;
    wsm[c][d] = wkv[(size_t)(ct * 64 + c) * 2048 + h * 64 + d];
  }
  __syncthreads();
  int b = t & 63, w = t >> 6;
  for (int c = w; c < 64; c += 4) {
    float s = 0.f;
#pragma unroll
    for (int d = 0; d < 64; d++) s += qs[b][d] * wsm[c][d];
    qt[((size_t)b * 16 + h) * dout + ct * 64 + c] = f2b(s);
  }
}

// ======================== S = q~ . x^T (1 wave / 16x16 tile) ===============
struct SArgs { const unsigned short* qt; const unsigned short* xbf; float* S;
               int dout, Nctx, ntj, nblk; };
__global__ __launch_bounds__(64) void s_gemm(SArgs ga, SArgs gb) {
  SArgs g; int bx;
  if ((int)blockIdx.x < ga.nblk) { g = ga; bx = blockIdx.x; }
  else { g = gb; bx = blockIdx.x - ga.nblk; }
  const int b = bx / g.ntj, jt = bx - b * g.ntj;
  const int lane = threadIdx.x;
  const int r16 = lane & 15, kv8 = (lane >> 4) * 8;
  const unsigned short* ap = g.qt + ((size_t)b * 16 + r16) * g.dout + kv8;
  const unsigned short* bp = g.xbf + ((size_t)b * g.Nctx + jt * 16 + r16) * g.dout + kv8;
  f32x4 acc; acc[0]=0.f; acc[1]=0.f; acc[2]=0.f; acc[3]=0.f;
  const int K = g.dout;
#pragma unroll 4
  for (int k0 = 0; k0 < K; k0 += 32)
    acc = __builtin_amdgcn_mfma_f32_16x16x32_bf16(*(const bf16x8*)&ap[k0],
                                                  *(const bf16x8*)&bp[k0], acc, 0, 0, 0);
  const int rbase = (lane >> 4) * 4;
#pragma unroll
  for (int rr = 0; rr < 4; rr++)
    g.S[((size_t)b * 16 + rbase + rr) * SSTR + jt * 16 + r16] = acc[rr];
}

// ============================ softmax -> p (once) ==========================
struct SMArgs { const float* S; const float* qb; const float* kvc;
                unsigned short* p; float* pcls; int Nctx, Npad; };
__global__ __launch_bounds__(256) void softmax_p2(SMArgs ga, SMArgs gb) {
  SMArgs g = blockIdx.z ? gb : ga;
  const int h = blockIdx.x, b = blockIdx.y;
  const int t = threadIdx.x;
  __shared__ float red[4], bc;
  float sc = 0.f;
  if (t < 64) sc = g.qb[(size_t)b * INNER_ + h * 64 + t] * g.kvc[(size_t)b * 2048 + h * 64 + t];
#pragma unroll
  for (int o = 32; o >= 1; o >>= 1) sc += __shfl_down(sc, o);
  if (t == 0) bc = sc * 0.125f;
  __syncthreads();
  const float scls = bc;
  const float* Sp = g.S + ((size_t)b * 16 + h) * SSTR;

  float sraw[2] = {-1e30f, -1e30f};
#pragma unroll
  for (int u2 = 0; u2 < 2; u2++) {
    int j = t + u2 * 256;
    if (j < g.Nctx) sraw[u2] = Sp[j] * 0.125f;
  }
  float mx = fmaxf(fmaxf(sraw[0], sraw[1]), scls);
#pragma unroll
  for (int o = 32; o >= 1; o >>= 1) mx = fmaxf(mx, __shfl_down(mx, o));
  if ((t & 63) == 0) red[t >> 6] = mx;
  __syncthreads();
  mx = fmaxf(fmaxf(red[0], red[1]), fmaxf(red[2], red[3]));
  __syncthreads();

  float e0 = (t < g.Nctx) ? expf(sraw[0] - mx) : 0.f;
  float e1 = (t + 256 < g.Nctx) ? expf(sraw[1] - mx) : 0.f;
  float ecls = expf(scls - mx);
  float ls = e0 + e1;
#pragma unroll
  for (int o = 32; o >= 1; o >>= 1) ls += __shfl_down(ls, o);
  if ((t & 63) == 0) red[t >> 6] = ls;
  __syncthreads();
  const float denom = red[0] + red[1] + red[2] + red[3] + ecls;
  const float inv = 1.f / denom;

  unsigned short* pp = g.p + ((size_t)b * 16 + h) * PSTR;
  if (t < g.Nctx) pp[t] = f2b(e0 * inv);
  if (t + 256 < g.Nctx) pp[t + 256] = f2b(e1 * inv);
  for (int j = g.Nctx + t; j < g.Npad; j += 256) pp[j] = 0;
  if (t == 0) g.pcls[b * 16 + h] = ecls * inv;
}

// ============================ u = p . x ====================================
struct UG { const unsigned short* p; const unsigned short* xT; unsigned short* u;
            int dout, Npad, xstride, ntx; };
__global__ __launch_bounds__(256) void ugemm2(UG ga, UG gb) {
  UG g; int bx = blockIdx.x;
  if (bx < ga.ntx) g = ga; else { g = gb; bx -= ga.ntx; }
  const int b = blockIdx.y;
  const int tid = threadIdx.x, lane = tid & 63, w = tid >> 6;
  const int c0 = bx * 64 + w * 16;
  const int r16 = lane & 15, kv8 = (lane >> 4) * 8, rbase = (lane >> 4) * 4;
  const unsigned short* ap = g.p + ((size_t)b * 16 + r16) * PSTR + kv8;
  const unsigned short* bp = g.xT + ((size_t)b * g.dout + c0 + r16) * g.xstride + kv8;
  f32x4 acc; acc[0]=0.f; acc[1]=0.f; acc[2]=0.f; acc[3]=0.f;
#pragma unroll 2
  for (int k0 = 0; k0 < g.Npad; k0 += 32)
    acc = __builtin_amdgcn_mfma_f32_16x16x32_bf16(*(const bf16x8*)&ap[k0],
                                                  *(const bf16x8*)&bp[k0], acc, 0, 0, 0);
#pragma unroll
  for (int rr = 0; rr < 4; rr++)
    g.u[((size_t)b * 16 + rbase + rr) * g.dout + c0 + r16] = f2b(acc[rr]);
}

// ==================== o = u.Wv (+ cls term), 4 waves/block =================
struct OArgs {
  const unsigned short* u; const unsigned short* WTkv; const float* kvc; const float* pcls;
  unsigned short* ob; int dout;
};
__global__ __launch_bounds__(256) void ogemm_w(OArgs ga, OArgs gb) {
  OArgs g; int bx = blockIdx.x;
  if (bx < 64) { g = ga; } else { g = gb; bx -= 64; }
  const int h = bx >> 2, dt = bx & 3;
  const int tid = threadIdx.x, lane = tid & 63, mt = tid >> 6;
  const int r16 = lane & 15, kv8 = (lane >> 4) * 8;
  const int dout = g.dout;
  f32x4 acc; acc[0]=0.f; acc[1]=0.f; acc[2]=0.f; acc[3]=0.f;
  const unsigned short* wp = &g.WTkv[(size_t)(1024 + h * 64 + dt * 16 + r16) * dout + kv8];
  const unsigned short* up = &g.u[((size_t)(mt * 16 + r16) * 16 + h) * dout + kv8];
#pragma unroll 4
  for (int k0 = 0; k0 < dout; k0 += 32)
    acc = __builtin_amdgcn_mfma_f32_16x16x32_bf16(*(const bf16x8*)&up[k0],
                                                  *(const bf16x8*)&wp[k0], acc, 0, 0, 0);
  const int rbase = (lane >> 4) * 4;
#pragma unroll
  for (int rr = 0; rr < 4; rr++) {
    int bi = mt * 16 + rbase + rr;
    int d = h * 64 + dt * 16 + r16;
    float v = acc[rr] + g.pcls[bi * 16 + h] * g.kvc[(size_t)bi * 2048 + 1024 + d];
    g.ob[(size_t)bi * INNER_ + d] = f2b(v);
  }
}

// ============================ final cls copy ===============================
__global__ __launch_bounds__(256) void final_copy(const float* clsa, float* outa, int Np1a, int dima,
                                                  const float* clsb2, float* outb, int Np1b, int dimb) {
  int x = blockIdx.x, t = threadIdx.x;
  if (x < 64) {
    for (int c = t; c < dima; c += 256)
      outa[(size_t)x * Np1a * dima + c] = clsa[(size_t)x * dima + c];
  } else {
    int b = x - 64;
    for (int c = t; c < dimb; c += 256)
      outb[(size_t)b * Np1b * dimb + c] = clsb2[(size_t)b * dimb + c];
  }
}

// ================================ host =====================================
extern "C" void kernel_launch(void* const* d_in, const int* in_sizes, int n_in,
                              void* d_out, int out_size, void* d_ws, size_t ws_size,
                              hipStream_t stream) {
  const float* sm_tokens = (const float*)d_in[0];
  const float* lg_tokens = (const float*)d_in[1];
  const float* a_pin_w  = (const float*)d_in[2];  const float* a_pin_b  = (const float*)d_in[3];
  const float* a_ng     = (const float*)d_in[4];  const float* a_nb     = (const float*)d_in[5];
  const float* a_wq     = (const float*)d_in[6];  const float* a_wkv    = (const float*)d_in[7];
  const float* a_wo     = (const float*)d_in[8];  const float* a_wob    = (const float*)d_in[9];
  const float* a_pout_w = (const float*)d_in[10]; const float* a_pout_b = (const float*)d_in[11];
  const float* b_pin_w  = (const float*)d_in[12]; const float* b_pin_b  = (const float*)d_in[13];
  const float* b_ng     = (const float*)d_in[14]; const float* b_nb     = (const float*)d_in[15];
  const float* b_wq     = (const float*)d_in[16]; const float* b_wkv    = (const float*)d_in[17];
  const float* b_wo     = (const float*)d_in[18]; const float* b_wob    = (const float*)d_in[19];
  const float* b_pout_w = (const float*)d_in[20]; const float* b_pout_b = (const float*)d_in[21];

  float* out = (float*)d_out;
  char* ws = (char*)d_ws;
  size_t off = 0;
  auto alloc = [&](size_t bytes) -> void* {
    void* pt = ws + off;
    off += (bytes + 255) & ~(size_t)255;
    return pt;
  };
  unsigned short* Abf_lg = (unsigned short*)alloc(((size_t)B_ * NLG_ + 32) * LG_ * 2);
  unsigned short* Abf_sm = (unsigned short*)alloc(((size_t)B_ * NSM_ + 32) * SM_ * 2);
  unsigned short* xT_lg  = (unsigned short*)alloc((size_t)B_ * LG_ * 224 * 2);
  unsigned short* xT_sm  = (unsigned short*)alloc((size_t)B_ * SM_ * 416 * 2);
  unsigned short* WTkv_a = (unsigned short*)alloc((size_t)4 * 2048 * LG_ * 2);
  unsigned short* WTkv_b = (unsigned short*)alloc((size_t)4 * 2048 * SM_ * 2);
  unsigned short* WTpin_a = (unsigned short*)alloc((size_t)4 * SM_ * LG_ * 2);
  unsigned short* WTpin_b = (unsigned short*)alloc((size_t)4 * LG_ * SM_ * 2);
  unsigned short* WTwq_a  = (unsigned short*)alloc((size_t)4 * LG_ * INNER_ * 2);
  unsigned short* WTwq_b  = (unsigned short*)alloc((size_t)4 * SM_ * INNER_ * 2);
  unsigned short* WTwo_a  = (unsigned short*)alloc((size_t)4 * INNER_ * LG_ * 2);
  unsigned short* WTwo_b  = (unsigned short*)alloc((size_t)4 * INNER_ * SM_ * 2);
  unsigned short* WTpout_a = (unsigned short*)alloc((size_t)4 * LG_ * SM_ * 2);
  unsigned short* WTpout_b = (unsigned short*)alloc((size_t)4 * SM_ * LG_ * 2);
  unsigned short* qt_a = (unsigned short*)alloc((size_t)B_ * 16 * LG_ * 2);
  unsigned short* qt_b = (unsigned short*)alloc((size_t)B_ * 16 * SM_ * 2);
  float* S_a = (float*)alloc((size_t)B_ * 16 * SSTR * 4);
  float* S_b = (float*)alloc((size_t)B_ * 16 * SSTR * 4);
  unsigned short* p_a = (unsigned short*)alloc((size_t)B_ * 16 * PSTR * 2);
  unsigned short* p_b = (unsigned short*)alloc((size_t)B_ * 16 * PSTR * 2);
  unsigned short* u_a  = (unsigned short*)alloc((size_t)B_ * 16 * LG_ * 2);
  unsigned short* u_b  = (unsigned short*)alloc((size_t)B_ * 16 * SM_ * 2);
  float* pcls_a = (float*)alloc((size_t)B_ * 16 * 4);
  float* pcls_b = (float*)alloc((size_t)B_ * 16 * 4);
  float* cls_sm = (float*)alloc((size_t)B_ * SM_ * 4);
  float* cls_lg = (float*)alloc((size_t)B_ * LG_ * 4);
  unsigned short* clsb_sm = (unsigned short*)alloc((size_t)B_ * SM_ * 2);
  unsigned short* clsb_lg = (unsigned short*)alloc((size_t)B_ * LG_ * 2);
  float* xbuf_a = (float*)alloc((size_t)B_ * LG_ * 4);
  float* xbuf_b = (float*)alloc((size_t)B_ * SM_ * 4);
  unsigned short* xnb_a = (unsigned short*)alloc((size_t)B_ * LG_ * 2);
  unsigned short* xnb_b = (unsigned short*)alloc((size_t)B_ * SM_ * 2);
  float* qbuf_a = (float*)alloc((size_t)B_ * INNER_ * 4);
  float* qbuf_b = (float*)alloc((size_t)B_ * INNER_ * 4);
  float* kvc_a  = (float*)alloc((size_t)B_ * 2048 * 4);
  float* kvc_b  = (float*)alloc((size_t)B_ * 2048 * 4);
  unsigned short* obufb_a = (unsigned short*)alloc((size_t)B_ * INNER_ * 2);
  unsigned short* obufb_b = (unsigned short*)alloc((size_t)B_ * INNER_ * 2);
  unsigned short* t1b_a = (unsigned short*)alloc((size_t)B_ * LG_ * 2);
  unsigned short* t1b_b = (unsigned short*)alloc((size_t)B_ * SM_ * 2);
  (void)ws_size; (void)in_sizes; (void)n_in; (void)out_size;

  const size_t sm_elems = (size_t)B_ * (NSM_ + 1) * SM_;

  // ---- setup: tokens pass
  CCArgs ca{sm_tokens, out, Abf_sm, cls_sm, clsb_sm, NSM_ + 1, SM_, B_ * (NSM_ + 1)};
  CCArgs cb{lg_tokens, out + sm_elems, Abf_lg, cls_lg, clsb_lg, NLG_ + 1, LG_, B_ * (NLG_ + 1)};
  copy_cvt<<<ca.nblk + cb.nblk, 256, 0, stream>>>(ca, cb);
  // ---- x^T (both branches, one dispatch)
  TXArgs txa{Abf_lg, xT_lg, NLG_, LG_, 224, LG_ / 64, 4, B_ * (LG_ / 64) * 4};
  TXArgs txb{Abf_sm, xT_sm, NSM_, SM_, 416, SM_ / 64, 7, B_ * (SM_ / 64) * 7};
  transpose_x2<<<txa.nblk + txb.nblk, dim3(64, 4), 0, stream>>>(txa, txb);
  // ---- all weight transposes
  WTArgs W;
  W.d[0] = {a_wkv,    WTkv_a,   LG_, 2048};
  W.d[1] = {b_wkv,    WTkv_b,   SM_, 2048};
  W.d[2] = {a_pin_w,  WTpin_a,  SM_, LG_};
  W.d[3] = {b_pin_w,  WTpin_b,  LG_, SM_};
  W.d[4] = {a_wq,     WTwq_a,   LG_, INNER_};
  W.d[5] = {b_wq,     WTwq_b,   SM_, INNER_};
  W.d[6] = {a_wo,     WTwo_a,   INNER_, LG_};
  W.d[7] = {b_wo,     WTwo_b,   INNER_, SM_};
  W.d[8] = {a_pout_w, WTpout_a, LG_, SM_};
  W.d[9] = {b_pout_w, WTpout_b, SM_, LG_};
  W.cum[0] = 0;
  for (int i = 0; i < 10; i++)
    W.cum[i + 1] = W.cum[i] + (W.d[i].K / 64) * (W.d[i].N / 64) * 4;
  wtrans_all<<<W.cum[10], 256, 0, stream>>>(W);

  for (int l = 0; l < 4; l++) {
    const unsigned short* WTpin_al = WTpin_a + (size_t)l * SM_ * LG_;
    const unsigned short* WTpin_bl = WTpin_b + (size_t)l * LG_ * SM_;
    const unsigned short* WTwq_al  = WTwq_a  + (size_t)l * LG_ * INNER_;
    const unsigned short* WTwq_bl  = WTwq_b  + (size_t)l * SM_ * INNER_;
    const unsigned short* WTkv_al  = WTkv_a  + (size_t)l * 2048 * LG_;
    const unsigned short* WTkv_bl  = WTkv_b  + (size_t)l * 2048 * SM_;
    const unsigned short* WTwo_al  = WTwo_a  + (size_t)l * INNER_ * LG_;
    const unsigned short* WTwo_bl  = WTwo_b  + (size_t)l * INNER_ * SM_;
    const unsigned short* WTpout_al = WTpout_a + (size_t)l * LG_ * SM_;
    const unsigned short* WTpout_bl = WTpout_b + (size_t)l * SM_ * LG_;

    // pin
    SGArgs Gp; Gp.nd = 2;
    Gp.d[0] = {clsb_sm, WTpin_al, a_pin_b + (size_t)l * LG_, xbuf_a, nullptr, nullptr, SM_, LG_};
    Gp.d[1] = {clsb_lg, WTpin_bl, b_pin_b + (size_t)l * SM_, xbuf_b, nullptr, nullptr, LG_, SM_};
    Gp.cum[0] = 0; Gp.cum[1] = LG_ / 16; Gp.cum[2] = LG_ / 16 + SM_ / 16;
    sg_wide<<<Gp.cum[2], 256, 0, stream>>>(Gp);
    // ln
    LNArgs la{xbuf_a, xnb_a, a_ng + (size_t)l * LG_, a_nb + (size_t)l * LG_, LG_};
    LNArgs lb{xbuf_b, xnb_b, b_ng + (size_t)l * SM_, b_nb + (size_t)l * SM_, SM_};
    ln2<<<128, 256, 0, stream>>>(la, lb);
    // q + kv (cls)
    SGArgs Gq; Gq.nd = 4;
    Gq.d[0] = {xnb_a, WTwq_al, nullptr, qbuf_a, nullptr, nullptr, LG_, INNER_};
    Gq.d[1] = {xnb_a, WTkv_al, nullptr, kvc_a,  nullptr, nullptr, LG_, 2048};
    Gq.d[2] = {xnb_b, WTwq_bl, nullptr, qbuf_b, nullptr, nullptr, SM_, INNER_};
    Gq.d[3] = {xnb_b, WTkv_bl, nullptr, kvc_b,  nullptr, nullptr, SM_, 2048};
    Gq.cum[0] = 0; Gq.cum[1] = 64; Gq.cum[2] = 192; Gq.cum[3] = 256; Gq.cum[4] = 384;
    sg_wide<<<384, 256, 0, stream>>>(Gq);
    // q~
    qtilde2<<<dim3(24, 16), 256, 0, stream>>>(qbuf_a, a_wkv + (size_t)l * LG_ * 2048, qt_a, 16,
                                              qbuf_b, b_wkv + (size_t)l * SM_ * 2048, qt_b);
    // S = q~ . x^T
    SArgs sa{qt_a, Abf_lg, S_a, LG_, NLG_, 224 / 16, B_ * (224 / 16)};
    SArgs sb{qt_b, Abf_sm, S_b, SM_, NSM_, 416 / 16, B_ * (416 / 16)};
    s_gemm<<<sa.nblk + sb.nblk, 64, 0, stream>>>(sa, sb);
    // softmax -> p (once per (b,h))
    SMArgs ma{S_a, qbuf_a, kvc_a, p_a, pcls_a, NLG_, 224};
    SMArgs mb{S_b, qbuf_b, kvc_b, p_b, pcls_b, NSM_, 416};
    softmax_p2<<<dim3(H_, B_, 2), 256, 0, stream>>>(ma, mb);
    // u = p . x
    UG ua{p_a, xT_lg, u_a, LG_, 224, 224, LG_ / 64};
    UG ub{p_b, xT_sm, u_b, SM_, 416, 416, SM_ / 64};
    ugemm2<<<dim3(LG_ / 64 + SM_ / 64, B_), 256, 0, stream>>>(ua, ub);
    // o = u . Wv + pcls * v_cls
    OArgs oa{u_a, WTkv_al, kvc_a, pcls_a, obufb_a, LG_};
    OArgs ob{u_b, WTkv_bl, kvc_b, pcls_b, obufb_b, SM_};
    ogemm_w<<<128, 256, 0, stream>>>(oa, ob);
    // wo
    SGArgs Gw; Gw.nd = 2;
    Gw.d[0] = {obufb_a, WTwo_al, a_wob + (size_t)l * LG_, nullptr, t1b_a, nullptr, INNER_, LG_};
    Gw.d[1] = {obufb_b, WTwo_bl, b_wob + (size_t)l * SM_, nullptr, t1b_b, nullptr, INNER_, SM_};
    Gw.cum[0] = 0; Gw.cum[1] = LG_ / 16; Gw.cum[2] = LG_ / 16 + SM_ / 16;
    sg_wide<<<Gw.cum[2], 256, 0, stream>>>(Gw);
    // pout + residual (f32 += , bf16 mirror)
    SGArgs Gr; Gr.nd = 2;
    Gr.d[0] = {t1b_a, WTpout_al, a_pout_b + (size_t)l * SM_, cls_sm, clsb_sm, cls_sm, LG_, SM_};
    Gr.d[1] = {t1b_b, WTpout_bl, b_pout_b + (size_t)l * LG_, cls_lg, clsb_lg, cls_lg, SM_, LG_};
    Gr.cum[0] = 0; Gr.cum[1] = SM_ / 16; Gr.cum[2] = SM_ / 16 + LG_ / 16;
    sg_wide<<<Gr.cum[2], 256, 0, stream>>>(Gr);
  }

  final_copy<<<128, 256, 0, stream>>>(cls_sm, out, NSM_ + 1, SM_,
                                      cls_lg, out + sm_elems, NLG_ + 1, LG_);
}

// Round 10
// 655.199 us; speedup vs baseline: 5.4202x; 1.0207x over previous
//
#include <hip/hip_runtime.h>
#include <hip/hip_bf16.h>
#include <math.h>

#define B_     64
#define NSM_   400
#define NLG_   196
#define SM_    512
#define LG_    1024
#define H_     16
#define DH_    64
#define INNER_ 1024
#define SSTR   424    // S row stride (f32)
#define PSTR   424    // p row stride (bf16)

typedef __attribute__((ext_vector_type(8))) short bf16x8;
typedef __attribute__((ext_vector_type(4))) float f32x4;

__device__ __forceinline__ unsigned short f2b(float f) {
  unsigned u = __float_as_uint(f);
  u = u + 0x7FFFu + ((u >> 16) & 1u);   // RNE
  return (unsigned short)(u >> 16);
}

// ============================ setup kernels ================================

// grid-stride tokens pass: full f32 copy to out, patches->bf16, cls -> f32+bf16
struct CC2 { const float* tok; float* out; unsigned short* abf; float* cls;
             unsigned short* clsb; int Np1, nf4, shift, tot4; };
__global__ __launch_bounds__(256) void copy_cvt2(CC2 a, CC2 b) {
  const int total = a.tot4 + b.tot4;
  for (int i = blockIdx.x * 256 + threadIdx.x; i < total; i += gridDim.x * 256) {
    CC2 g; int idx;
    if (i < a.tot4) { g = a; idx = i; } else { g = b; idx = i - a.tot4; }
    int rowg = idx >> g.shift, t = idx & ((1 << g.shift) - 1);
    int bb = rowg / g.Np1, row = rowg - bb * g.Np1;
    const float4 v = ((const float4*)g.tok)[idx];
    ((float4*)g.out)[idx] = v;
    ushort4 w2; w2.x = f2b(v.x); w2.y = f2b(v.y); w2.z = f2b(v.z); w2.w = f2b(v.w);
    if (row > 0) {
      ((ushort4*)g.abf)[(size_t)(bb * (g.Np1 - 1) + row - 1) * g.nf4 + t] = w2;
    } else {
      ((float4*)g.cls)[(size_t)bb * g.nf4 + t] = v;
      ((ushort4*)g.clsb)[(size_t)bb * g.nf4 + t] = w2;
    }
  }
}

// merged: x^T transposes (both branches) + all 10 weight transposes
struct TXArgs { const unsigned short* xbf; unsigned short* xT; int Nctx, dout, xstride, nx, ny, nblk; };
struct WTDesc { const float* src; unsigned short* dst; int K, N; };
struct WTArgs { WTDesc d[10]; int cum[11]; };
__global__ __launch_bounds__(256) void prep_all(TXArgs ta, TXArgs tb, WTArgs W, int ntx) {
  __shared__ unsigned short tile[64][65];
  int bx = blockIdx.x;
  int tx = threadIdx.x & 63, ty = threadIdx.x >> 6;
  if (bx < ntx) {
    // ---- x^T part
    TXArgs g;
    if (bx < ta.nblk) { g = ta; } else { g = tb; bx -= ta.nblk; }
    int cx = bx % g.nx; int rem = bx / g.nx;
    int jy = rem % g.ny; int b = rem / g.ny;
    int jt = jy * 64, ct = cx * 64;
    for (int r = ty; r < 64; r += 4) {
      int j = jt + r;
      tile[r][tx] = (j < g.Nctx) ? g.xbf[((size_t)b * g.Nctx + j) * g.dout + ct + tx]
                                 : (unsigned short)0;
    }
    __syncthreads();
    for (int r = ty; r < 64; r += 4) {
      int col = jt + tx;
      if (col < g.xstride)
        g.xT[((size_t)b * g.dout + ct + r) * g.xstride + col] = tile[tx][r];
    }
  } else {
    // ---- weight transpose part (f32 (L,K,N) -> bf16 (L,N,K))
    bx -= ntx;
    int di = 0;
    while (bx >= W.cum[di + 1]) di++;
    int local = bx - W.cum[di];
    WTDesc g = W.d[di];
    int tn = g.N >> 6;
    int tpl = tn * (g.K >> 6);
    int layer = local / tpl, rem = local % tpl;
    int kt = (rem / tn) * 64, nt = (rem % tn) * 64;
    const float* wp = g.src + (size_t)layer * g.K * g.N;
    unsigned short* op = g.dst + (size_t)layer * g.K * g.N;
    for (int r = ty; r < 64; r += 4)
      tile[r][tx] = f2b(wp[(size_t)(kt + r) * g.N + nt + tx]);
    __syncthreads();
    for (int r = ty; r < 64; r += 4)
      op[(size_t)(nt + r) * g.K + kt + tx] = tile[tx][r];
  }
}

// ========== wide small GEMM: M=64, one 16-col tile per 256-thr block =======
// wave w handles M-rows [w*16, w*16+16): 4 waves/block -> latency hidden
struct SGDesc {
  const unsigned short* A;    // [64][K] bf16
  const unsigned short* WT;   // [N][K] bf16
  const float* bias;          // [N] or null
  float* Cf;                  // f32 out [64][N] or null
  unsigned short* Cbf;        // bf16 out [64][N] or null
  const float* Rf;            // residual f32 in [64][N] or null
  int K, N;
};
struct SGArgs { SGDesc d[4]; int cum[5]; int nd; };
__global__ __launch_bounds__(256) void sg_wide(SGArgs W) {
  int bx = blockIdx.x, di = 0;
  while (di < W.nd - 1 && bx >= W.cum[di + 1]) di++;
  SGDesc g = W.d[di];
  const int n0 = (bx - W.cum[di]) * 16;
  const int tid = threadIdx.x;
  const int lane = tid & 63, mt = tid >> 6;
  const int r16 = lane & 15, kv8 = (lane >> 4) * 8;
  f32x4 acc; acc[0] = 0.f; acc[1] = 0.f; acc[2] = 0.f; acc[3] = 0.f;
  const unsigned short* wp = &g.WT[(size_t)(n0 + r16) * g.K + kv8];
  const unsigned short* ap = &g.A[(size_t)(mt * 16 + r16) * g.K + kv8];
  const int K = g.K;
#pragma unroll 4
  for (int k0 = 0; k0 < K; k0 += 32)
    acc = __builtin_amdgcn_mfma_f32_16x16x32_bf16(*(const bf16x8*)&ap[k0],
                                                  *(const bf16x8*)&wp[k0], acc, 0, 0, 0);
  const int rbase = (lane >> 4) * 4;
#pragma unroll
  for (int rr = 0; rr < 4; rr++) {
    int r = mt * 16 + rbase + rr, c = n0 + r16;
    float v = acc[rr];
    if (g.bias) v += g.bias[c];
    if (g.Rf) v += g.Rf[(size_t)r * g.N + c];
    if (g.Cf)  g.Cf[(size_t)r * g.N + c] = v;
    if (g.Cbf) g.Cbf[(size_t)r * g.N + c] = f2b(v);
  }
}

// =============================== layernorm =================================
struct LNArgs { const float* x; unsigned short* xnb; const float* ng; const float* nb; int dim; };
__global__ __launch_bounds__(256) void ln2(LNArgs la, LNArgs lb) {
  LNArgs g = ((int)blockIdx.x < 64) ? la : lb;
  int b = blockIdx.x & 63, t = threadIdx.x;
  __shared__ float rs[4], rq[4], bc[2];
  const float* xp = g.x + (size_t)b * g.dim;
  float s = 0.f, sq = 0.f;
  for (int c = t; c < g.dim; c += 256) {
    float v = xp[c];
    s += v; sq += v * v;
  }
#pragma unroll
  for (int off = 32; off >= 1; off >>= 1) {
    s += __shfl_down(s, off);
    sq += __shfl_down(sq, off);
  }
  int w = t >> 6;
  if ((t & 63) == 0) { rs[w] = s; rq[w] = sq; }
  __syncthreads();
  if (t == 0) {
    float ts = rs[0] + rs[1] + rs[2] + rs[3];
    float tq = rq[0] + rq[1] + rq[2] + rq[3];
    float mu = ts / g.dim;
    float var = tq / g.dim - mu * mu;
    bc[0] = mu; bc[1] = rsqrtf(var + 1e-5f);
  }
  __syncthreads();
  float mu = bc[0], r = bc[1];
  for (int c = t; c < g.dim; c += 256)
    g.xnb[(size_t)b * g.dim + c] = f2b((xp[c] - mu) * r * g.ng[c] + g.nb[c]);
}

// ============================ q~ (merged) ==================================
// qt[b][h][c] = bf16( sum_d q[b][h*64+d] * wkv[c][h*64+d] )
__global__ __launch_bounds__(256) void qtilde2(const float* qa, const float* wkva,
                                               unsigned short* qta, int nxa,
                                               const float* qb, const float* wkvb,
                                               unsigned short* qtb) {
  const float* qbuf; const float* wkv; unsigned short* qt; int dout, ct;
  if ((int)blockIdx.x < nxa) { qbuf = qa; wkv = wkva; qt = qta; dout = 1024; ct = blockIdx.x; }
  else { qbuf = qb; wkv = wkvb; qt = qtb; dout = 512; ct = blockIdx.x - nxa; }
  const int h = blockIdx.y;
  __shared__ float qs[64][65];    // +1 pad: compute loop reads qs[b=lane][d] -> banks spread
  __shared__ float wsm[64][65];
  int t = threadIdx.x;
  for (int i = t; i < 64 * 64; i += 256) {
    int b = i >> 6, d = i & 63;
    qs[b][d] = qbuf[(size_t)b * INNER_ + h * 64 + d];
  }
  for (int i = t; i < 64 * 64; i += 256) {
    int c = i >> 6, d = i & 63;
    wsm[c][d] = wkv[(size_t)(ct * 64 + c) * 2048 + h * 64 + d];
  }
  __syncthreads();
  int b = t & 63, w = t >> 6;
  for (int c = w; c < 64; c += 4) {
    float s = 0.f;
#pragma unroll
    for (int d = 0; d < 64; d++) s += qs[b][d] * wsm[c][d];
    qt[((size_t)b * 16 + h) * dout + ct * 64 + c] = f2b(s);
  }
}

// ======================== S = q~ . x^T (1 wave / 16x16 tile) ===============
struct SArgs { const unsigned short* qt; const unsigned short* xbf; float* S;
               int dout, Nctx, ntj, nblk; };
__global__ __launch_bounds__(64) void s_gemm(SArgs ga, SArgs gb) {
  SArgs g; int bx;
  if ((int)blockIdx.x < ga.nblk) { g = ga; bx = blockIdx.x; }
  else { g = gb; bx = blockIdx.x - ga.nblk; }
  const int b = bx / g.ntj, jt = bx - b * g.ntj;
  const int lane = threadIdx.x;
  const int r16 = lane & 15, kv8 = (lane >> 4) * 8;
  const unsigned short* ap = g.qt + ((size_t)b * 16 + r16) * g.dout + kv8;
  const unsigned short* bp = g.xbf + ((size_t)b * g.Nctx + jt * 16 + r16) * g.dout + kv8;
  f32x4 acc; acc[0]=0.f; acc[1]=0.f; acc[2]=0.f; acc[3]=0.f;
  const int K = g.dout;
#pragma unroll 4
  for (int k0 = 0; k0 < K; k0 += 32)
    acc = __builtin_amdgcn_mfma_f32_16x16x32_bf16(*(const bf16x8*)&ap[k0],
                                                  *(const bf16x8*)&bp[k0], acc, 0, 0, 0);
  const int rbase = (lane >> 4) * 4;
#pragma unroll
  for (int rr = 0; rr < 4; rr++)
    g.S[((size_t)b * 16 + rbase + rr) * SSTR + jt * 16 + r16] = acc[rr];
}

// ============================ softmax -> p (once) ==========================
struct SMArgs { const float* S; const float* qb; const float* kvc;
                unsigned short* p; float* pcls; int Nctx, Npad; };
__global__ __launch_bounds__(256) void softmax_p2(SMArgs ga, SMArgs gb) {
  SMArgs g = blockIdx.z ? gb : ga;
  const int h = blockIdx.x, b = blockIdx.y;
  const int t = threadIdx.x;
  __shared__ float red[4], bc;
  float sc = 0.f;
  if (t < 64) sc = g.qb[(size_t)b * INNER_ + h * 64 + t] * g.kvc[(size_t)b * 2048 + h * 64 + t];
#pragma unroll
  for (int o = 32; o >= 1; o >>= 1) sc += __shfl_down(sc, o);
  if (t == 0) bc = sc * 0.125f;
  __syncthreads();
  const float scls = bc;
  const float* Sp = g.S + ((size_t)b * 16 + h) * SSTR;

  float sraw[2] = {-1e30f, -1e30f};
#pragma unroll
  for (int u2 = 0; u2 < 2; u2++) {
    int j = t + u2 * 256;
    if (j < g.Nctx) sraw[u2] = Sp[j] * 0.125f;
  }
  float mx = fmaxf(fmaxf(sraw[0], sraw[1]), scls);
#pragma unroll
  for (int o = 32; o >= 1; o >>= 1) mx = fmaxf(mx, __shfl_down(mx, o));
  if ((t & 63) == 0) red[t >> 6] = mx;
  __syncthreads();
  mx = fmaxf(fmaxf(red[0], red[1]), fmaxf(red[2], red[3]));
  __syncthreads();

  float e0 = (t < g.Nctx) ? expf(sraw[0] - mx) : 0.f;
  float e1 = (t + 256 < g.Nctx) ? expf(sraw[1] - mx) : 0.f;
  float ecls = expf(scls - mx);
  float ls = e0 + e1;
#pragma unroll
  for (int o = 32; o >= 1; o >>= 1) ls += __shfl_down(ls, o);
  if ((t & 63) == 0) red[t >> 6] = ls;
  __syncthreads();
  const float denom = red[0] + red[1] + red[2] + red[3] + ecls;
  const float inv = 1.f / denom;

  unsigned short* pp = g.p + ((size_t)b * 16 + h) * PSTR;
  if (t < g.Nctx) pp[t] = f2b(e0 * inv);
  if (t + 256 < g.Nctx) pp[t + 256] = f2b(e1 * inv);
  for (int j = g.Nctx + t; j < g.Npad; j += 256) pp[j] = 0;
  if (t == 0) g.pcls[b * 16 + h] = ecls * inv;
}

// ============================ u = p . x ====================================
struct UG { const unsigned short* p; const unsigned short* xT; unsigned short* u;
            int dout, Npad, xstride, ntx; };
__global__ __launch_bounds__(256) void ugemm2(UG ga, UG gb) {
  UG g; int bx = blockIdx.x;
  if (bx < ga.ntx) g = ga; else { g = gb; bx -= ga.ntx; }
  const int b = blockIdx.y;
  const int tid = threadIdx.x, lane = tid & 63, w = tid >> 6;
  const int c0 = bx * 64 + w * 16;
  const int r16 = lane & 15, kv8 = (lane >> 4) * 8, rbase = (lane >> 4) * 4;
  const unsigned short* ap = g.p + ((size_t)b * 16 + r16) * PSTR + kv8;
  const unsigned short* bp = g.xT + ((size_t)b * g.dout + c0 + r16) * g.xstride + kv8;
  f32x4 acc; acc[0]=0.f; acc[1]=0.f; acc[2]=0.f; acc[3]=0.f;
#pragma unroll 2
  for (int k0 = 0; k0 < g.Npad; k0 += 32)
    acc = __builtin_amdgcn_mfma_f32_16x16x32_bf16(*(const bf16x8*)&ap[k0],
                                                  *(const bf16x8*)&bp[k0], acc, 0, 0, 0);
#pragma unroll
  for (int rr = 0; rr < 4; rr++)
    g.u[((size_t)b * 16 + rbase + rr) * g.dout + c0 + r16] = f2b(acc[rr]);
}

// ==================== o = u.Wv (+ cls term), 4 waves/block =================
struct OArgs {
  const unsigned short* u; const unsigned short* WTkv; const float* kvc; const float* pcls;
  unsigned short* ob; int dout;
};
__global__ __launch_bounds__(256) void ogemm_w(OArgs ga, OArgs gb) {
  OArgs g; int bx = blockIdx.x;
  if (bx < 64) { g = ga; } else { g = gb; bx -= 64; }
  const int h = bx >> 2, dt = bx & 3;
  const int tid = threadIdx.x, lane = tid & 63, mt = tid >> 6;
  const int r16 = lane & 15, kv8 = (lane >> 4) * 8;
  const int dout = g.dout;
  f32x4 acc; acc[0]=0.f; acc[1]=0.f; acc[2]=0.f; acc[3]=0.f;
  const unsigned short* wp = &g.WTkv[(size_t)(1024 + h * 64 + dt * 16 + r16) * dout + kv8];
  const unsigned short* up = &g.u[((size_t)(mt * 16 + r16) * 16 + h) * dout + kv8];
#pragma unroll 4
  for (int k0 = 0; k0 < dout; k0 += 32)
    acc = __builtin_amdgcn_mfma_f32_16x16x32_bf16(*(const bf16x8*)&up[k0],
                                                  *(const bf16x8*)&wp[k0], acc, 0, 0, 0);
  const int rbase = (lane >> 4) * 4;
#pragma unroll
  for (int rr = 0; rr < 4; rr++) {
    int bi = mt * 16 + rbase + rr;
    int d = h * 64 + dt * 16 + r16;
    float v = acc[rr] + g.pcls[bi * 16 + h] * g.kvc[(size_t)bi * 2048 + 1024 + d];
    g.ob[(size_t)bi * INNER_ + d] = f2b(v);
  }
}

// ============================ final cls copy ===============================
__global__ __launch_bounds__(256) void final_copy(const float* clsa, float* outa, int Np1a, int dima,
                                                  const float* clsb2, float* outb, int Np1b, int dimb) {
  int x = blockIdx.x, t = threadIdx.x;
  if (x < 64) {
    for (int c = t; c < dima; c += 256)
      outa[(size_t)x * Np1a * dima + c] = clsa[(size_t)x * dima + c];
  } else {
    int b = x - 64;
    for (int c = t; c < dimb; c += 256)
      outb[(size_t)b * Np1b * dimb + c] = clsb2[(size_t)b * dimb + c];
  }
}

// ================================ host =====================================
extern "C" void kernel_launch(void* const* d_in, const int* in_sizes, int n_in,
                              void* d_out, int out_size, void* d_ws, size_t ws_size,
                              hipStream_t stream) {
  const float* sm_tokens = (const float*)d_in[0];
  const float* lg_tokens = (const float*)d_in[1];
  const float* a_pin_w  = (const float*)d_in[2];  const float* a_pin_b  = (const float*)d_in[3];
  const float* a_ng     = (const float*)d_in[4];  const float* a_nb     = (const float*)d_in[5];
  const float* a_wq     = (const float*)d_in[6];  const float* a_wkv    = (const float*)d_in[7];
  const float* a_wo     = (const float*)d_in[8];  const float* a_wob    = (const float*)d_in[9];
  const float* a_pout_w = (const float*)d_in[10]; const float* a_pout_b = (const float*)d_in[11];
  const float* b_pin_w  = (const float*)d_in[12]; const float* b_pin_b  = (const float*)d_in[13];
  const float* b_ng     = (const float*)d_in[14]; const float* b_nb     = (const float*)d_in[15];
  const float* b_wq     = (const float*)d_in[16]; const float* b_wkv    = (const float*)d_in[17];
  const float* b_wo     = (const float*)d_in[18]; const float* b_wob    = (const float*)d_in[19];
  const float* b_pout_w = (const float*)d_in[20]; const float* b_pout_b = (const float*)d_in[21];

  float* out = (float*)d_out;
  char* ws = (char*)d_ws;
  size_t off = 0;
  auto alloc = [&](size_t bytes) -> void* {
    void* pt = ws + off;
    off += (bytes + 255) & ~(size_t)255;
    return pt;
  };
  unsigned short* Abf_lg = (unsigned short*)alloc(((size_t)B_ * NLG_ + 32) * LG_ * 2);
  unsigned short* Abf_sm = (unsigned short*)alloc(((size_t)B_ * NSM_ + 32) * SM_ * 2);
  unsigned short* xT_lg  = (unsigned short*)alloc((size_t)B_ * LG_ * 224 * 2);
  unsigned short* xT_sm  = (unsigned short*)alloc((size_t)B_ * SM_ * 416 * 2);
  unsigned short* WTkv_a = (unsigned short*)alloc((size_t)4 * 2048 * LG_ * 2);
  unsigned short* WTkv_b = (unsigned short*)alloc((size_t)4 * 2048 * SM_ * 2);
  unsigned short* WTpin_a = (unsigned short*)alloc((size_t)4 * SM_ * LG_ * 2);
  unsigned short* WTpin_b = (unsigned short*)alloc((size_t)4 * LG_ * SM_ * 2);
  unsigned short* WTwq_a  = (unsigned short*)alloc((size_t)4 * LG_ * INNER_ * 2);
  unsigned short* WTwq_b  = (unsigned short*)alloc((size_t)4 * SM_ * INNER_ * 2);
  unsigned short* WTwo_a  = (unsigned short*)alloc((size_t)4 * INNER_ * LG_ * 2);
  unsigned short* WTwo_b  = (unsigned short*)alloc((size_t)4 * INNER_ * SM_ * 2);
  unsigned short* WTpout_a = (unsigned short*)alloc((size_t)4 * LG_ * SM_ * 2);
  unsigned short* WTpout_b = (unsigned short*)alloc((size_t)4 * SM_ * LG_ * 2);
  unsigned short* qt_a = (unsigned short*)alloc((size_t)B_ * 16 * LG_ * 2);
  unsigned short* qt_b = (unsigned short*)alloc((size_t)B_ * 16 * SM_ * 2);
  float* S_a = (float*)alloc((size_t)B_ * 16 * SSTR * 4);
  float* S_b = (float*)alloc((size_t)B_ * 16 * SSTR * 4);
  unsigned short* p_a = (unsigned short*)alloc((size_t)B_ * 16 * PSTR * 2);
  unsigned short* p_b = (unsigned short*)alloc((size_t)B_ * 16 * PSTR * 2);
  unsigned short* u_a  = (unsigned short*)alloc((size_t)B_ * 16 * LG_ * 2);
  unsigned short* u_b  = (unsigned short*)alloc((size_t)B_ * 16 * SM_ * 2);
  float* pcls_a = (float*)alloc((size_t)B_ * 16 * 4);
  float* pcls_b = (float*)alloc((size_t)B_ * 16 * 4);
  float* cls_sm = (float*)alloc((size_t)B_ * SM_ * 4);
  float* cls_lg = (float*)alloc((size_t)B_ * LG_ * 4);
  unsigned short* clsb_sm = (unsigned short*)alloc((size_t)B_ * SM_ * 2);
  unsigned short* clsb_lg = (unsigned short*)alloc((size_t)B_ * LG_ * 2);
  float* xbuf_a = (float*)alloc((size_t)B_ * LG_ * 4);
  float* xbuf_b = (float*)alloc((size_t)B_ * SM_ * 4);
  unsigned short* xnb_a = (unsigned short*)alloc((size_t)B_ * LG_ * 2);
  unsigned short* xnb_b = (unsigned short*)alloc((size_t)B_ * SM_ * 2);
  float* qbuf_a = (float*)alloc((size_t)B_ * INNER_ * 4);
  float* qbuf_b = (float*)alloc((size_t)B_ * INNER_ * 4);
  float* kvc_a  = (float*)alloc((size_t)B_ * 2048 * 4);
  float* kvc_b  = (float*)alloc((size_t)B_ * 2048 * 4);
  unsigned short* obufb_a = (unsigned short*)alloc((size_t)B_ * INNER_ * 2);
  unsigned short* obufb_b = (unsigned short*)alloc((size_t)B_ * INNER_ * 2);
  unsigned short* t1b_a = (unsigned short*)alloc((size_t)B_ * LG_ * 2);
  unsigned short* t1b_b = (unsigned short*)alloc((size_t)B_ * SM_ * 2);
  (void)ws_size; (void)in_sizes; (void)n_in; (void)out_size;

  const size_t sm_elems = (size_t)B_ * (NSM_ + 1) * SM_;

  // ---- setup 1: tokens pass (grid-stride, all lanes active)
  CC2 ca{sm_tokens, out, Abf_sm, cls_sm, clsb_sm, NSM_ + 1, SM_ / 4, 7,
         (int)(sm_elems / 4)};
  CC2 cb{lg_tokens, out + sm_elems, Abf_lg, cls_lg, clsb_lg, NLG_ + 1, LG_ / 4, 8,
         (int)((size_t)B_ * (NLG_ + 1) * LG_ / 4)};
  copy_cvt2<<<2048, 256, 0, stream>>>(ca, cb);
  // ---- setup 2: x^T + all weight transposes in one dispatch
  TXArgs txa{Abf_lg, xT_lg, NLG_, LG_, 224, LG_ / 64, 4, B_ * (LG_ / 64) * 4};
  TXArgs txb{Abf_sm, xT_sm, NSM_, SM_, 416, SM_ / 64, 7, B_ * (SM_ / 64) * 7};
  WTArgs W;
  W.d[0] = {a_wkv,    WTkv_a,   LG_, 2048};
  W.d[1] = {b_wkv,    WTkv_b,   SM_, 2048};
  W.d[2] = {a_pin_w,  WTpin_a,  SM_, LG_};
  W.d[3] = {b_pin_w,  WTpin_b,  LG_, SM_};
  W.d[4] = {a_wq,     WTwq_a,   LG_, INNER_};
  W.d[5] = {b_wq,     WTwq_b,   SM_, INNER_};
  W.d[6] = {a_wo,     WTwo_a,   INNER_, LG_};
  W.d[7] = {b_wo,     WTwo_b,   INNER_, SM_};
  W.d[8] = {a_pout_w, WTpout_a, LG_, SM_};
  W.d[9] = {b_pout_w, WTpout_b, SM_, LG_};
  W.cum[0] = 0;
  for (int i = 0; i < 10; i++)
    W.cum[i + 1] = W.cum[i] + (W.d[i].K / 64) * (W.d[i].N / 64) * 4;
  const int ntx = txa.nblk + txb.nblk;
  prep_all<<<ntx + W.cum[10], 256, 0, stream>>>(txa, txb, W, ntx);

  for (int l = 0; l < 4; l++) {
    const unsigned short* WTpin_al = WTpin_a + (size_t)l * SM_ * LG_;
    const unsigned short* WTpin_bl = WTpin_b + (size_t)l * LG_ * SM_;
    const unsigned short* WTwq_al  = WTwq_a  + (size_t)l * LG_ * INNER_;
    const unsigned short* WTwq_bl  = WTwq_b  + (size_t)l * SM_ * INNER_;
    const unsigned short* WTkv_al  = WTkv_a  + (size_t)l * 2048 * LG_;
    const unsigned short* WTkv_bl  = WTkv_b  + (size_t)l * 2048 * SM_;
    const unsigned short* WTwo_al  = WTwo_a  + (size_t)l * INNER_ * LG_;
    const unsigned short* WTwo_bl  = WTwo_b  + (size_t)l * INNER_ * SM_;
    const unsigned short* WTpout_al = WTpout_a + (size_t)l * LG_ * SM_;
    const unsigned short* WTpout_bl = WTpout_b + (size_t)l * SM_ * LG_;

    // pin
    SGArgs Gp; Gp.nd = 2;
    Gp.d[0] = {clsb_sm, WTpin_al, a_pin_b + (size_t)l * LG_, xbuf_a, nullptr, nullptr, SM_, LG_};
    Gp.d[1] = {clsb_lg, WTpin_bl, b_pin_b + (size_t)l * SM_, xbuf_b, nullptr, nullptr, LG_, SM_};
    Gp.cum[0] = 0; Gp.cum[1] = LG_ / 16; Gp.cum[2] = LG_ / 16 + SM_ / 16;
    sg_wide<<<Gp.cum[2], 256, 0, stream>>>(Gp);
    // ln
    LNArgs la{xbuf_a, xnb_a, a_ng + (size_t)l * LG_, a_nb + (size_t)l * LG_, LG_};
    LNArgs lb{xbuf_b, xnb_b, b_ng + (size_t)l * SM_, b_nb + (size_t)l * SM_, SM_};
    ln2<<<128, 256, 0, stream>>>(la, lb);
    // q + kv (cls)
    SGArgs Gq; Gq.nd = 4;
    Gq.d[0] = {xnb_a, WTwq_al, nullptr, qbuf_a, nullptr, nullptr, LG_, INNER_};
    Gq.d[1] = {xnb_a, WTkv_al, nullptr, kvc_a,  nullptr, nullptr, LG_, 2048};
    Gq.d[2] = {xnb_b, WTwq_bl, nullptr, qbuf_b, nullptr, nullptr, SM_, INNER_};
    Gq.d[3] = {xnb_b, WTkv_bl, nullptr, kvc_b,  nullptr, nullptr, SM_, 2048};
    Gq.cum[0] = 0; Gq.cum[1] = 64; Gq.cum[2] = 192; Gq.cum[3] = 256; Gq.cum[4] = 384;
    sg_wide<<<384, 256, 0, stream>>>(Gq);
    // q~
    qtilde2<<<dim3(24, 16), 256, 0, stream>>>(qbuf_a, a_wkv + (size_t)l * LG_ * 2048, qt_a, 16,
                                              qbuf_b, b_wkv + (size_t)l * SM_ * 2048, qt_b);
    // S = q~ . x^T
    SArgs sa{qt_a, Abf_lg, S_a, LG_, NLG_, 224 / 16, B_ * (224 / 16)};
    SArgs sb{qt_b, Abf_sm, S_b, SM_, NSM_, 416 / 16, B_ * (416 / 16)};
    s_gemm<<<sa.nblk + sb.nblk, 64, 0, stream>>>(sa, sb);
    // softmax -> p (once per (b,h))
    SMArgs ma{S_a, qbuf_a, kvc_a, p_a, pcls_a, NLG_, 224};
    SMArgs mb{S_b, qbuf_b, kvc_b, p_b, pcls_b, NSM_, 416};
    softmax_p2<<<dim3(H_, B_, 2), 256, 0, stream>>>(ma, mb);
    // u = p . x
    UG ua{p_a, xT_lg, u_a, LG_, 224, 224, LG_ / 64};
    UG ub{p_b, xT_sm, u_b, SM_, 416, 416, SM_ / 64};
    ugemm2<<<dim3(LG_ / 64 + SM_ / 64, B_), 256, 0, stream>>>(ua, ub);
    // o = u . Wv + pcls * v_cls
    OArgs oa{u_a, WTkv_al, kvc_a, pcls_a, obufb_a, LG_};
    OArgs ob{u_b, WTkv_bl, kvc_b, pcls_b, obufb_b, SM_};
    ogemm_w<<<128, 256, 0, stream>>>(oa, ob);
    // wo
    SGArgs Gw; Gw.nd = 2;
    Gw.d[0] = {obufb_a, WTwo_al, a_wob + (size_t)l * LG_, nullptr, t1b_a, nullptr, INNER_, LG_};
    Gw.d[1] = {obufb_b, WTwo_bl, b_wob + (size_t)l * SM_, nullptr, t1b_b, nullptr, INNER_, SM_};
    Gw.cum[0] = 0; Gw.cum[1] = LG_ / 16; Gw.cum[2] = LG_ / 16 + SM_ / 16;
    sg_wide<<<Gw.cum[2], 256, 0, stream>>>(Gw);
    // pout + residual (f32 += , bf16 mirror)
    SGArgs Gr; Gr.nd = 2;
    Gr.d[0] = {t1b_a, WTpout_al, a_pout_b + (size_t)l * SM_, cls_sm, clsb_sm, cls_sm, LG_, SM_};
    Gr.d[1] = {t1b_b, WTpout_bl, b_pout_b + (size_t)l * LG_, cls_lg, clsb_lg, cls_lg, SM_, LG_};
    Gr.cum[0] = 0; Gr.cum[1] = SM_ / 16; Gr.cum[2] = SM_ / 16 + LG_ / 16;
    sg_wide<<<Gr.cum[2], 256, 0, stream>>>(Gr);
  }

  final_copy<<<128, 256, 0, stream>>>(cls_sm, out, NSM_ + 1, SM_,
                                      cls_lg, out + sm_elems, NLG_ + 1, LG_);
}

// Round 11
// 610.983 us; speedup vs baseline: 5.8124x; 1.0724x over previous
//
#include <hip/hip_runtime.h>
#include <hip/hip_bf16.h>
#include <math.h>

#define B_     64
#define NSM_   400
#define NLG_   196
#define SM_    512
#define LG_    1024
#define H_     16
#define DH_    64
#define INNER_ 1024
#define SSTR   424    // S row stride (f32)
#define PSTR   424    // p row stride (bf16)

typedef __attribute__((ext_vector_type(8))) short bf16x8;
typedef __attribute__((ext_vector_type(4))) float f32x4;

__device__ __forceinline__ unsigned short f2b(float f) {
  unsigned u = __float_as_uint(f);
  u = u + 0x7FFFu + ((u >> 16) & 1u);   // RNE
  return (unsigned short)(u >> 16);
}

// ============================ setup kernels ================================

// grid-stride tokens pass: full f32 copy to out, patches->bf16, cls -> f32+bf16
struct CC2 { const float* tok; float* out; unsigned short* abf; float* cls;
             unsigned short* clsb; int Np1, nf4, shift, tot4; };
__global__ __launch_bounds__(256) void copy_cvt2(CC2 a, CC2 b) {
  const int total = a.tot4 + b.tot4;
  for (int i = blockIdx.x * 256 + threadIdx.x; i < total; i += gridDim.x * 256) {
    CC2 g; int idx;
    if (i < a.tot4) { g = a; idx = i; } else { g = b; idx = i - a.tot4; }
    int rowg = idx >> g.shift, t = idx & ((1 << g.shift) - 1);
    int bb = rowg / g.Np1, row = rowg - bb * g.Np1;
    const float4 v = ((const float4*)g.tok)[idx];
    ((float4*)g.out)[idx] = v;
    ushort4 w2; w2.x = f2b(v.x); w2.y = f2b(v.y); w2.z = f2b(v.z); w2.w = f2b(v.w);
    if (row > 0) {
      ((ushort4*)g.abf)[(size_t)(bb * (g.Np1 - 1) + row - 1) * g.nf4 + t] = w2;
    } else {
      ((float4*)g.cls)[(size_t)bb * g.nf4 + t] = v;
      ((ushort4*)g.clsb)[(size_t)bb * g.nf4 + t] = w2;
    }
  }
}

// merged: x^T transposes (both branches) + all 10 weight transposes
// wkv descriptors also emit a straight bf16 copy of the K-half (dst2).
struct TXArgs { const unsigned short* xbf; unsigned short* xT; int Nctx, dout, xstride, nx, ny, nblk; };
struct WTDesc { const float* src; unsigned short* dst; unsigned short* dst2; int K, N; };
struct WTArgs { WTDesc d[10]; int cum[11]; };
__global__ __launch_bounds__(256) void prep_all(TXArgs ta, TXArgs tb, WTArgs W, int ntx) {
  __shared__ unsigned short tile[64][65];
  int bx = blockIdx.x;
  int tx = threadIdx.x & 63, ty = threadIdx.x >> 6;
  if (bx < ntx) {
    // ---- x^T part
    TXArgs g;
    if (bx < ta.nblk) { g = ta; } else { g = tb; bx -= ta.nblk; }
    int cx = bx % g.nx; int rem = bx / g.nx;
    int jy = rem % g.ny; int b = rem / g.ny;
    int jt = jy * 64, ct = cx * 64;
    for (int r = ty; r < 64; r += 4) {
      int j = jt + r;
      tile[r][tx] = (j < g.Nctx) ? g.xbf[((size_t)b * g.Nctx + j) * g.dout + ct + tx]
                                 : (unsigned short)0;
    }
    __syncthreads();
    for (int r = ty; r < 64; r += 4) {
      int col = jt + tx;
      if (col < g.xstride)
        g.xT[((size_t)b * g.dout + ct + r) * g.xstride + col] = tile[tx][r];
    }
  } else {
    // ---- weight transpose part (f32 (L,K,N) -> bf16 (L,N,K); wkv also (L,K,1024))
    bx -= ntx;
    int di = 0;
    while (bx >= W.cum[di + 1]) di++;
    int local = bx - W.cum[di];
    WTDesc g = W.d[di];
    int tn = g.N >> 6;
    int tpl = tn * (g.K >> 6);
    int layer = local / tpl, rem = local % tpl;
    int kt = (rem / tn) * 64, nt = (rem % tn) * 64;
    const float* wp = g.src + (size_t)layer * g.K * g.N;
    unsigned short* op = g.dst + (size_t)layer * g.K * g.N;
    for (int r = ty; r < 64; r += 4) {
      unsigned short v = f2b(wp[(size_t)(kt + r) * g.N + nt + tx]);
      tile[r][tx] = v;
      if (g.dst2 && nt < 1024)
        g.dst2[(size_t)layer * g.K * 1024 + (size_t)(kt + r) * 1024 + nt + tx] = v;
    }
    __syncthreads();
    for (int r = ty; r < 64; r += 4)
      op[(size_t)(nt + r) * g.K + kt + tx] = tile[tx][r];
  }
}

// ========== wide small GEMM: M=64, one 16-col tile per 256-thr block =======
// wave w handles M-rows [w*16, w*16+16): 4 waves/block -> latency hidden
struct SGDesc {
  const unsigned short* A;    // [64][K] bf16
  const unsigned short* WT;   // [N][K] bf16
  const float* bias;          // [N] or null
  float* Cf;                  // f32 out [64][N] or null
  unsigned short* Cbf;        // bf16 out [64][N] or null
  const float* Rf;            // residual f32 in [64][N] or null
  int K, N;
};
struct SGArgs { SGDesc d[4]; int cum[5]; int nd; };
__global__ __launch_bounds__(256) void sg_wide(SGArgs W) {
  int bx = blockIdx.x, di = 0;
  while (di < W.nd - 1 && bx >= W.cum[di + 1]) di++;
  SGDesc g = W.d[di];
  const int n0 = (bx - W.cum[di]) * 16;
  const int tid = threadIdx.x;
  const int lane = tid & 63, mt = tid >> 6;
  const int r16 = lane & 15, kv8 = (lane >> 4) * 8;
  f32x4 acc; acc[0] = 0.f; acc[1] = 0.f; acc[2] = 0.f; acc[3] = 0.f;
  const unsigned short* wp = &g.WT[(size_t)(n0 + r16) * g.K + kv8];
  const unsigned short* ap = &g.A[(size_t)(mt * 16 + r16) * g.K + kv8];
  const int K = g.K;
#pragma unroll 4
  for (int k0 = 0; k0 < K; k0 += 32)
    acc = __builtin_amdgcn_mfma_f32_16x16x32_bf16(*(const bf16x8*)&ap[k0],
                                                  *(const bf16x8*)&wp[k0], acc, 0, 0, 0);
  const int rbase = (lane >> 4) * 4;
#pragma unroll
  for (int rr = 0; rr < 4; rr++) {
    int r = mt * 16 + rbase + rr, c = n0 + r16;
    float v = acc[rr];
    if (g.bias) v += g.bias[c];
    if (g.Rf) v += g.Rf[(size_t)r * g.N + c];
    if (g.Cf)  g.Cf[(size_t)r * g.N + c] = v;
    if (g.Cbf) g.Cbf[(size_t)r * g.N + c] = f2b(v);
  }
}

// =============================== layernorm =================================
struct LNArgs { const float* x; unsigned short* xnb; const float* ng; const float* nb; int dim; };
__global__ __launch_bounds__(256) void ln2(LNArgs la, LNArgs lb) {
  LNArgs g = ((int)blockIdx.x < 64) ? la : lb;
  int b = blockIdx.x & 63, t = threadIdx.x;
  __shared__ float rs[4], rq[4], bc[2];
  const float* xp = g.x + (size_t)b * g.dim;
  float s = 0.f, sq = 0.f;
  for (int c = t; c < g.dim; c += 256) {
    float v = xp[c];
    s += v; sq += v * v;
  }
#pragma unroll
  for (int off = 32; off >= 1; off >>= 1) {
    s += __shfl_down(s, off);
    sq += __shfl_down(sq, off);
  }
  int w = t >> 6;
  if ((t & 63) == 0) { rs[w] = s; rq[w] = sq; }
  __syncthreads();
  if (t == 0) {
    float ts = rs[0] + rs[1] + rs[2] + rs[3];
    float tq = rq[0] + rq[1] + rq[2] + rq[3];
    float mu = ts / g.dim;
    float var = tq / g.dim - mu * mu;
    bc[0] = mu; bc[1] = rsqrtf(var + 1e-5f);
  }
  __syncthreads();
  float mu = bc[0], r = bc[1];
  for (int c = t; c < g.dim; c += 256)
    g.xnb[(size_t)b * g.dim + c] = f2b((xp[c] - mu) * r * g.ng[c] + g.nb[c]);
}

// ==================== q~ via MFMA: q̃_bh = q_h(64x64) @ wkv_rows ============
// qt[(b*16+h)*dout + c'] = sum_d qb16[b][h*64+d] * wkvnb[c'][h*64+d]
struct QTArgs { const unsigned short* qb16; const unsigned short* wkvnb;
                unsigned short* qt; int dout, ntiles, nblk; };
__global__ __launch_bounds__(256) void qtilde3(QTArgs ga, QTArgs gb) {
  QTArgs g; int bx = blockIdx.x;
  if (bx < ga.nblk) g = ga; else { g = gb; bx -= ga.nblk; }
  const int h = bx / g.ntiles, nt = bx - h * g.ntiles;
  const int n0 = nt * 16;
  const int tid = threadIdx.x, lane = tid & 63, mt = tid >> 6;
  const int r16 = lane & 15, kv8 = (lane >> 4) * 8;
  const unsigned short* ap = g.qb16 + (size_t)(mt * 16 + r16) * INNER_ + h * 64 + kv8;
  const unsigned short* bp = g.wkvnb + (size_t)(n0 + r16) * 1024 + h * 64 + kv8;
  f32x4 acc; acc[0] = 0.f; acc[1] = 0.f; acc[2] = 0.f; acc[3] = 0.f;
  acc = __builtin_amdgcn_mfma_f32_16x16x32_bf16(*(const bf16x8*)&ap[0],
                                                *(const bf16x8*)&bp[0], acc, 0, 0, 0);
  acc = __builtin_amdgcn_mfma_f32_16x16x32_bf16(*(const bf16x8*)&ap[32],
                                                *(const bf16x8*)&bp[32], acc, 0, 0, 0);
  const int rbase = (lane >> 4) * 4;
#pragma unroll
  for (int rr = 0; rr < 4; rr++) {
    int b = mt * 16 + rbase + rr;
    g.qt[((size_t)b * 16 + h) * g.dout + n0 + r16] = f2b(acc[rr]);
  }
}

// ================= S = q~ . x^T (4 j-tiles per 256-thr block) ==============
struct SArgs { const unsigned short* qt; const unsigned short* xbf; float* S;
               int dout, Nctx, ntj, nbj, nblk; };
__global__ __launch_bounds__(256) void s_gemm(SArgs ga, SArgs gb) {
  SArgs g; int bx;
  if ((int)blockIdx.x < ga.nblk) { g = ga; bx = blockIdx.x; }
  else { g = gb; bx = blockIdx.x - ga.nblk; }
  const int b = bx / g.nbj, jq = bx - b * g.nbj;
  const int tid = threadIdx.x, lane = tid & 63, w = tid >> 6;
  const int jt = jq * 4 + w;
  if (jt >= g.ntj) return;
  const int r16 = lane & 15, kv8 = (lane >> 4) * 8;
  const unsigned short* ap = g.qt + ((size_t)b * 16 + r16) * g.dout + kv8;
  const unsigned short* bp = g.xbf + ((size_t)b * g.Nctx + jt * 16 + r16) * g.dout + kv8;
  f32x4 acc; acc[0]=0.f; acc[1]=0.f; acc[2]=0.f; acc[3]=0.f;
  const int K = g.dout;
#pragma unroll 4
  for (int k0 = 0; k0 < K; k0 += 32)
    acc = __builtin_amdgcn_mfma_f32_16x16x32_bf16(*(const bf16x8*)&ap[k0],
                                                  *(const bf16x8*)&bp[k0], acc, 0, 0, 0);
  const int rbase = (lane >> 4) * 4;
#pragma unroll
  for (int rr = 0; rr < 4; rr++)
    g.S[((size_t)b * 16 + rbase + rr) * SSTR + jt * 16 + r16] = acc[rr];
}

// ============================ softmax -> p (once) ==========================
struct SMArgs { const float* S; const float* qb; const float* kvc;
                unsigned short* p; float* pcls; int Nctx, Npad; };
__global__ __launch_bounds__(256) void softmax_p2(SMArgs ga, SMArgs gb) {
  SMArgs g = blockIdx.z ? gb : ga;
  const int h = blockIdx.x, b = blockIdx.y;
  const int t = threadIdx.x;
  __shared__ float red[4], bc;
  float sc = 0.f;
  if (t < 64) sc = g.qb[(size_t)b * INNER_ + h * 64 + t] * g.kvc[(size_t)b * 2048 + h * 64 + t];
#pragma unroll
  for (int o = 32; o >= 1; o >>= 1) sc += __shfl_down(sc, o);
  if (t == 0) bc = sc * 0.125f;
  __syncthreads();
  const float scls = bc;
  const float* Sp = g.S + ((size_t)b * 16 + h) * SSTR;

  float sraw[2] = {-1e30f, -1e30f};
#pragma unroll
  for (int u2 = 0; u2 < 2; u2++) {
    int j = t + u2 * 256;
    if (j < g.Nctx) sraw[u2] = Sp[j] * 0.125f;
  }
  float mx = fmaxf(fmaxf(sraw[0], sraw[1]), scls);
#pragma unroll
  for (int o = 32; o >= 1; o >>= 1) mx = fmaxf(mx, __shfl_down(mx, o));
  if ((t & 63) == 0) red[t >> 6] = mx;
  __syncthreads();
  mx = fmaxf(fmaxf(red[0], red[1]), fmaxf(red[2], red[3]));
  __syncthreads();

  float e0 = (t < g.Nctx) ? expf(sraw[0] - mx) : 0.f;
  float e1 = (t + 256 < g.Nctx) ? expf(sraw[1] - mx) : 0.f;
  float ecls = expf(scls - mx);
  float ls = e0 + e1;
#pragma unroll
  for (int o = 32; o >= 1; o >>= 1) ls += __shfl_down(ls, o);
  if ((t & 63) == 0) red[t >> 6] = ls;
  __syncthreads();
  const float denom = red[0] + red[1] + red[2] + red[3] + ecls;
  const float inv = 1.f / denom;

  unsigned short* pp = g.p + ((size_t)b * 16 + h) * PSTR;
  if (t < g.Nctx) pp[t] = f2b(e0 * inv);
  if (t + 256 < g.Nctx) pp[t + 256] = f2b(e1 * inv);
  for (int j = g.Nctx + t; j < g.Npad; j += 256) pp[j] = 0;
  if (t == 0) g.pcls[b * 16 + h] = ecls * inv;
}

// ============================ u = p . x ====================================
struct UG { const unsigned short* p; const unsigned short* xT; unsigned short* u;
            int dout, Npad, xstride, ntx; };
__global__ __launch_bounds__(256) void ugemm2(UG ga, UG gb) {
  UG g; int bx = blockIdx.x;
  if (bx < ga.ntx) g = ga; else { g = gb; bx -= ga.ntx; }
  const int b = blockIdx.y;
  const int tid = threadIdx.x, lane = tid & 63, w = tid >> 6;
  const int c0 = bx * 64 + w * 16;
  const int r16 = lane & 15, kv8 = (lane >> 4) * 8, rbase = (lane >> 4) * 4;
  const unsigned short* ap = g.p + ((size_t)b * 16 + r16) * PSTR + kv8;
  const unsigned short* bp = g.xT + ((size_t)b * g.dout + c0 + r16) * g.xstride + kv8;
  f32x4 acc; acc[0]=0.f; acc[1]=0.f; acc[2]=0.f; acc[3]=0.f;
#pragma unroll 2
  for (int k0 = 0; k0 < g.Npad; k0 += 32)
    acc = __builtin_amdgcn_mfma_f32_16x16x32_bf16(*(const bf16x8*)&ap[k0],
                                                  *(const bf16x8*)&bp[k0], acc, 0, 0, 0);
#pragma unroll
  for (int rr = 0; rr < 4; rr++)
    g.u[((size_t)b * 16 + rbase + rr) * g.dout + c0 + r16] = f2b(acc[rr]);
}

// ==================== o = u.Wv (+ cls term), 4 waves/block =================
struct OArgs {
  const unsigned short* u; const unsigned short* WTkv; const float* kvc; const float* pcls;
  unsigned short* ob; int dout;
};
__global__ __launch_bounds__(256) void ogemm_w(OArgs ga, OArgs gb) {
  OArgs g; int bx = blockIdx.x;
  if (bx < 64) { g = ga; } else { g = gb; bx -= 64; }
  const int h = bx >> 2, dt = bx & 3;
  const int tid = threadIdx.x, lane = tid & 63, mt = tid >> 6;
  const int r16 = lane & 15, kv8 = (lane >> 4) * 8;
  const int dout = g.dout;
  f32x4 acc; acc[0]=0.f; acc[1]=0.f; acc[2]=0.f; acc[3]=0.f;
  const unsigned short* wp = &g.WTkv[(size_t)(1024 + h * 64 + dt * 16 + r16) * dout + kv8];
  const unsigned short* up = &g.u[((size_t)(mt * 16 + r16) * 16 + h) * dout + kv8];
#pragma unroll 4
  for (int k0 = 0; k0 < dout; k0 += 32)
    acc = __builtin_amdgcn_mfma_f32_16x16x32_bf16(*(const bf16x8*)&up[k0],
                                                  *(const bf16x8*)&wp[k0], acc, 0, 0, 0);
  const int rbase = (lane >> 4) * 4;
#pragma unroll
  for (int rr = 0; rr < 4; rr++) {
    int bi = mt * 16 + rbase + rr;
    int d = h * 64 + dt * 16 + r16;
    float v = acc[rr] + g.pcls[bi * 16 + h] * g.kvc[(size_t)bi * 2048 + 1024 + d];
    g.ob[(size_t)bi * INNER_ + d] = f2b(v);
  }
}

// ============================ final cls copy ===============================
__global__ __launch_bounds__(256) void final_copy(const float* clsa, float* outa, int Np1a, int dima,
                                                  const float* clsb2, float* outb, int Np1b, int dimb) {
  int x = blockIdx.x, t = threadIdx.x;
  if (x < 64) {
    for (int c = t; c < dima; c += 256)
      outa[(size_t)x * Np1a * dima + c] = clsa[(size_t)x * dima + c];
  } else {
    int b = x - 64;
    for (int c = t; c < dimb; c += 256)
      outb[(size_t)b * Np1b * dimb + c] = clsb2[(size_t)b * dimb + c];
  }
}

// ================================ host =====================================
extern "C" void kernel_launch(void* const* d_in, const int* in_sizes, int n_in,
                              void* d_out, int out_size, void* d_ws, size_t ws_size,
                              hipStream_t stream) {
  const float* sm_tokens = (const float*)d_in[0];
  const float* lg_tokens = (const float*)d_in[1];
  const float* a_pin_w  = (const float*)d_in[2];  const float* a_pin_b  = (const float*)d_in[3];
  const float* a_ng     = (const float*)d_in[4];  const float* a_nb     = (const float*)d_in[5];
  const float* a_wq     = (const float*)d_in[6];  const float* a_wkv    = (const float*)d_in[7];
  const float* a_wo     = (const float*)d_in[8];  const float* a_wob    = (const float*)d_in[9];
  const float* a_pout_w = (const float*)d_in[10]; const float* a_pout_b = (const float*)d_in[11];
  const float* b_pin_w  = (const float*)d_in[12]; const float* b_pin_b  = (const float*)d_in[13];
  const float* b_ng     = (const float*)d_in[14]; const float* b_nb     = (const float*)d_in[15];
  const float* b_wq     = (const float*)d_in[16]; const float* b_wkv    = (const float*)d_in[17];
  const float* b_wo     = (const float*)d_in[18]; const float* b_wob    = (const float*)d_in[19];
  const float* b_pout_w = (const float*)d_in[20]; const float* b_pout_b = (const float*)d_in[21];

  float* out = (float*)d_out;
  char* ws = (char*)d_ws;
  size_t off = 0;
  auto alloc = [&](size_t bytes) -> void* {
    void* pt = ws + off;
    off += (bytes + 255) & ~(size_t)255;
    return pt;
  };
  unsigned short* Abf_lg = (unsigned short*)alloc(((size_t)B_ * NLG_ + 32) * LG_ * 2);
  unsigned short* Abf_sm = (unsigned short*)alloc(((size_t)B_ * NSM_ + 32) * SM_ * 2);
  unsigned short* xT_lg  = (unsigned short*)alloc((size_t)B_ * LG_ * 224 * 2);
  unsigned short* xT_sm  = (unsigned short*)alloc((size_t)B_ * SM_ * 416 * 2);
  unsigned short* WTkv_a = (unsigned short*)alloc((size_t)4 * 2048 * LG_ * 2);
  unsigned short* WTkv_b = (unsigned short*)alloc((size_t)4 * 2048 * SM_ * 2);
  unsigned short* wkvnb_a = (unsigned short*)alloc((size_t)4 * LG_ * 1024 * 2);
  unsigned short* wkvnb_b = (unsigned short*)alloc((size_t)4 * SM_ * 1024 * 2);
  unsigned short* WTpin_a = (unsigned short*)alloc((size_t)4 * SM_ * LG_ * 2);
  unsigned short* WTpin_b = (unsigned short*)alloc((size_t)4 * LG_ * SM_ * 2);
  unsigned short* WTwq_a  = (unsigned short*)alloc((size_t)4 * LG_ * INNER_ * 2);
  unsigned short* WTwq_b  = (unsigned short*)alloc((size_t)4 * SM_ * INNER_ * 2);
  unsigned short* WTwo_a  = (unsigned short*)alloc((size_t)4 * INNER_ * LG_ * 2);
  unsigned short* WTwo_b  = (unsigned short*)alloc((size_t)4 * INNER_ * SM_ * 2);
  unsigned short* WTpout_a = (unsigned short*)alloc((size_t)4 * LG_ * SM_ * 2);
  unsigned short* WTpout_b = (unsigned short*)alloc((size_t)4 * SM_ * LG_ * 2);
  unsigned short* qt_a = (unsigned short*)alloc((size_t)B_ * 16 * LG_ * 2);
  unsigned short* qt_b = (unsigned short*)alloc((size_t)B_ * 16 * SM_ * 2);
  float* S_a = (float*)alloc((size_t)B_ * 16 * SSTR * 4);
  float* S_b = (float*)alloc((size_t)B_ * 16 * SSTR * 4);
  unsigned short* p_a = (unsigned short*)alloc((size_t)B_ * 16 * PSTR * 2);
  unsigned short* p_b = (unsigned short*)alloc((size_t)B_ * 16 * PSTR * 2);
  unsigned short* u_a  = (unsigned short*)alloc((size_t)B_ * 16 * LG_ * 2);
  unsigned short* u_b  = (unsigned short*)alloc((size_t)B_ * 16 * SM_ * 2);
  float* pcls_a = (float*)alloc((size_t)B_ * 16 * 4);
  float* pcls_b = (float*)alloc((size_t)B_ * 16 * 4);
  float* cls_sm = (float*)alloc((size_t)B_ * SM_ * 4);
  float* cls_lg = (float*)alloc((size_t)B_ * LG_ * 4);
  unsigned short* clsb_sm = (unsigned short*)alloc((size_t)B_ * SM_ * 2);
  unsigned short* clsb_lg = (unsigned short*)alloc((size_t)B_ * LG_ * 2);
  float* xbuf_a = (float*)alloc((size_t)B_ * LG_ * 4);
  float* xbuf_b = (float*)alloc((size_t)B_ * SM_ * 4);
  unsigned short* xnb_a = (unsigned short*)alloc((size_t)B_ * LG_ * 2);
  unsigned short* xnb_b = (unsigned short*)alloc((size_t)B_ * SM_ * 2);
  float* qbuf_a = (float*)alloc((size_t)B_ * INNER_ * 4);
  float* qbuf_b = (float*)alloc((size_t)B_ * INNER_ * 4);
  unsigned short* qb16_a = (unsigned short*)alloc((size_t)B_ * INNER_ * 2);
  unsigned short* qb16_b = (unsigned short*)alloc((size_t)B_ * INNER_ * 2);
  float* kvc_a  = (float*)alloc((size_t)B_ * 2048 * 4);
  float* kvc_b  = (float*)alloc((size_t)B_ * 2048 * 4);
  unsigned short* obufb_a = (unsigned short*)alloc((size_t)B_ * INNER_ * 2);
  unsigned short* obufb_b = (unsigned short*)alloc((size_t)B_ * INNER_ * 2);
  unsigned short* t1b_a = (unsigned short*)alloc((size_t)B_ * LG_ * 2);
  unsigned short* t1b_b = (unsigned short*)alloc((size_t)B_ * SM_ * 2);
  (void)ws_size; (void)in_sizes; (void)n_in; (void)out_size;

  const size_t sm_elems = (size_t)B_ * (NSM_ + 1) * SM_;

  // ---- setup 1: tokens pass (grid-stride, all lanes active)
  CC2 ca{sm_tokens, out, Abf_sm, cls_sm, clsb_sm, NSM_ + 1, SM_ / 4, 7,
         (int)(sm_elems / 4)};
  CC2 cb{lg_tokens, out + sm_elems, Abf_lg, cls_lg, clsb_lg, NLG_ + 1, LG_ / 4, 8,
         (int)((size_t)B_ * (NLG_ + 1) * LG_ / 4)};
  copy_cvt2<<<2048, 256, 0, stream>>>(ca, cb);
  // ---- setup 2: x^T + all weight transposes (wkv also straight K-half copy)
  TXArgs txa{Abf_lg, xT_lg, NLG_, LG_, 224, LG_ / 64, 4, B_ * (LG_ / 64) * 4};
  TXArgs txb{Abf_sm, xT_sm, NSM_, SM_, 416, SM_ / 64, 7, B_ * (SM_ / 64) * 7};
  WTArgs W;
  W.d[0] = {a_wkv,    WTkv_a,   wkvnb_a, LG_, 2048};
  W.d[1] = {b_wkv,    WTkv_b,   wkvnb_b, SM_, 2048};
  W.d[2] = {a_pin_w,  WTpin_a,  nullptr, SM_, LG_};
  W.d[3] = {b_pin_w,  WTpin_b,  nullptr, LG_, SM_};
  W.d[4] = {a_wq,     WTwq_a,   nullptr, LG_, INNER_};
  W.d[5] = {b_wq,     WTwq_b,   nullptr, SM_, INNER_};
  W.d[6] = {a_wo,     WTwo_a,   nullptr, INNER_, LG_};
  W.d[7] = {b_wo,     WTwo_b,   nullptr, INNER_, SM_};
  W.d[8] = {a_pout_w, WTpout_a, nullptr, LG_, SM_};
  W.d[9] = {b_pout_w, WTpout_b, nullptr, SM_, LG_};
  W.cum[0] = 0;
  for (int i = 0; i < 10; i++)
    W.cum[i + 1] = W.cum[i] + (W.d[i].K / 64) * (W.d[i].N / 64) * 4;
  const int ntx = txa.nblk + txb.nblk;
  prep_all<<<ntx + W.cum[10], 256, 0, stream>>>(txa, txb, W, ntx);

  for (int l = 0; l < 4; l++) {
    const unsigned short* WTpin_al = WTpin_a + (size_t)l * SM_ * LG_;
    const unsigned short* WTpin_bl = WTpin_b + (size_t)l * LG_ * SM_;
    const unsigned short* WTwq_al  = WTwq_a  + (size_t)l * LG_ * INNER_;
    const unsigned short* WTwq_bl  = WTwq_b  + (size_t)l * SM_ * INNER_;
    const unsigned short* WTkv_al  = WTkv_a  + (size_t)l * 2048 * LG_;
    const unsigned short* WTkv_bl  = WTkv_b  + (size_t)l * 2048 * SM_;
    const unsigned short* wkvnb_al = wkvnb_a + (size_t)l * LG_ * 1024;
    const unsigned short* wkvnb_bl = wkvnb_b + (size_t)l * SM_ * 1024;
    const unsigned short* WTwo_al  = WTwo_a  + (size_t)l * INNER_ * LG_;
    const unsigned short* WTwo_bl  = WTwo_b  + (size_t)l * INNER_ * SM_;
    const unsigned short* WTpout_al = WTpout_a + (size_t)l * LG_ * SM_;
    const unsigned short* WTpout_bl = WTpout_b + (size_t)l * SM_ * LG_;

    // pin
    SGArgs Gp; Gp.nd = 2;
    Gp.d[0] = {clsb_sm, WTpin_al, a_pin_b + (size_t)l * LG_, xbuf_a, nullptr, nullptr, SM_, LG_};
    Gp.d[1] = {clsb_lg, WTpin_bl, b_pin_b + (size_t)l * SM_, xbuf_b, nullptr, nullptr, LG_, SM_};
    Gp.cum[0] = 0; Gp.cum[1] = LG_ / 16; Gp.cum[2] = LG_ / 16 + SM_ / 16;
    sg_wide<<<Gp.cum[2], 256, 0, stream>>>(Gp);
    // ln
    LNArgs la{xbuf_a, xnb_a, a_ng + (size_t)l * LG_, a_nb + (size_t)l * LG_, LG_};
    LNArgs lb{xbuf_b, xnb_b, b_ng + (size_t)l * SM_, b_nb + (size_t)l * SM_, SM_};
    ln2<<<128, 256, 0, stream>>>(la, lb);
    // q (f32 + bf16 mirror) + kv (cls)
    SGArgs Gq; Gq.nd = 4;
    Gq.d[0] = {xnb_a, WTwq_al, nullptr, qbuf_a, qb16_a, nullptr, LG_, INNER_};
    Gq.d[1] = {xnb_a, WTkv_al, nullptr, kvc_a,  nullptr, nullptr, LG_, 2048};
    Gq.d[2] = {xnb_b, WTwq_bl, nullptr, qbuf_b, qb16_b, nullptr, SM_, INNER_};
    Gq.d[3] = {xnb_b, WTkv_bl, nullptr, kvc_b,  nullptr, nullptr, SM_, 2048};
    Gq.cum[0] = 0; Gq.cum[1] = 64; Gq.cum[2] = 192; Gq.cum[3] = 256; Gq.cum[4] = 384;
    sg_wide<<<384, 256, 0, stream>>>(Gq);
    // q~ (MFMA over bf16 straight wkv)
    QTArgs qa{qb16_a, wkvnb_al, qt_a, LG_, LG_ / 16, 16 * (LG_ / 16)};
    QTArgs qb{qb16_b, wkvnb_bl, qt_b, SM_, SM_ / 16, 16 * (SM_ / 16)};
    qtilde3<<<qa.nblk + qb.nblk, 256, 0, stream>>>(qa, qb);
    // S = q~ . x^T
    SArgs sa{qt_a, Abf_lg, S_a, LG_, NLG_, 14, 4, B_ * 4};
    SArgs sb{qt_b, Abf_sm, S_b, SM_, NSM_, 26, 7, B_ * 7};
    s_gemm<<<sa.nblk + sb.nblk, 256, 0, stream>>>(sa, sb);
    // softmax -> p (once per (b,h))
    SMArgs ma{S_a, qbuf_a, kvc_a, p_a, pcls_a, NLG_, 224};
    SMArgs mb{S_b, qbuf_b, kvc_b, p_b, pcls_b, NSM_, 416};
    softmax_p2<<<dim3(H_, B_, 2), 256, 0, stream>>>(ma, mb);
    // u = p . x
    UG ua{p_a, xT_lg, u_a, LG_, 224, 224, LG_ / 64};
    UG ub{p_b, xT_sm, u_b, SM_, 416, 416, SM_ / 64};
    ugemm2<<<dim3(LG_ / 64 + SM_ / 64, B_), 256, 0, stream>>>(ua, ub);
    // o = u . Wv + pcls * v_cls
    OArgs oa{u_a, WTkv_al, kvc_a, pcls_a, obufb_a, LG_};
    OArgs ob{u_b, WTkv_bl, kvc_b, pcls_b, obufb_b, SM_};
    ogemm_w<<<128, 256, 0, stream>>>(oa, ob);
    // wo
    SGArgs Gw; Gw.nd = 2;
    Gw.d[0] = {obufb_a, WTwo_al, a_wob + (size_t)l * LG_, nullptr, t1b_a, nullptr, INNER_, LG_};
    Gw.d[1] = {obufb_b, WTwo_bl, b_wob + (size_t)l * SM_, nullptr, t1b_b, nullptr, INNER_, SM_};
    Gw.cum[0] = 0; Gw.cum[1] = LG_ / 16; Gw.cum[2] = LG_ / 16 + SM_ / 16;
    sg_wide<<<Gw.cum[2], 256, 0, stream>>>(Gw);
    // pout + residual (f32 += , bf16 mirror)
    SGArgs Gr; Gr.nd = 2;
    Gr.d[0] = {t1b_a, WTpout_al, a_pout_b + (size_t)l * SM_, cls_sm, clsb_sm, cls_sm, LG_, SM_};
    Gr.d[1] = {t1b_b, WTpout_bl, b_pout_b + (size_t)l * LG_, cls_lg, clsb_lg, cls_lg, SM_, LG_};
    Gr.cum[0] = 0; Gr.cum[1] = SM_ / 16; Gr.cum[2] = SM_ / 16 + LG_ / 16;
    sg_wide<<<Gr.cum[2], 256, 0, stream>>>(Gr);
  }

  final_copy<<<128, 256, 0, stream>>>(cls_sm, out, NSM_ + 1, SM_,
                                      cls_lg, out + sm_elems, NLG_ + 1, LG_);
}

// Round 12
// 601.210 us; speedup vs baseline: 5.9069x; 1.0163x over previous
//
#include <hip/hip_runtime.h>
#include <hip/hip_bf16.h>
#include <math.h>

#define B_     64
#define NSM_   400
#define NLG_   196
#define SM_    512
#define LG_    1024
#define H_     16
#define DH_    64
#define INNER_ 1024
#define SSTR   424    // S row stride (f32)
#define PSTR   424    // p row stride (bf16)

typedef __attribute__((ext_vector_type(8))) short bf16x8;
typedef __attribute__((ext_vector_type(4))) float f32x4;

__device__ __forceinline__ unsigned short f2b(float f) {
  unsigned u = __float_as_uint(f);
  u = u + 0x7FFFu + ((u >> 16) & 1u);   // RNE
  return (unsigned short)(u >> 16);
}

// ============================ setup kernels ================================

// setup1 = all 10 weight transposes (vectorized) + grid-stride token pass.
// The two halves are independent; weight VALU hides under token BW.
struct CC2 { const float* tok; float* out; unsigned short* abf; float* cls;
             unsigned short* clsb; int Np1, nf4, shift, tot4; };
struct WTDesc { const float* src; unsigned short* dst; unsigned short* dst2; int K, N; };
struct WTArgs { WTDesc d[10]; int cum[11]; };
__global__ __launch_bounds__(256) void setup1(CC2 ca, CC2 cb, WTArgs W, int nw) {
  __shared__ unsigned short tile[64][68];   // 136B row stride: 8B-aligned, 2-way banks
  const int tid = threadIdx.x;
  if ((int)blockIdx.x < nw) {
    // ---- weight transpose: f32 (L,K,N) -> bf16 (L,N,K); wkv also straight (L,K,1024)
    int bx = blockIdx.x, di = 0;
    while (bx >= W.cum[di + 1]) di++;
    int local = bx - W.cum[di];
    WTDesc g = W.d[di];
    int tn = g.N >> 6;
    int tpl = tn * (g.K >> 6);
    int layer = local / tpl, rem = local % tpl;
    int kt = (rem / tn) * 64, nt = (rem % tn) * 64;
    const float* wp = g.src + (size_t)layer * g.K * g.N;
    unsigned short* op = g.dst + (size_t)layer * g.K * g.N;
    unsigned short* d2 = (g.dst2 && nt < 1024)
                             ? g.dst2 + (size_t)layer * g.K * 1024 : nullptr;
#pragma unroll
    for (int p = 0; p < 4; p++) {
      int r = (tid >> 4) + p * 16;
      int c = (tid & 15) * 4;
      const float4 v = *(const float4*)&wp[(size_t)(kt + r) * g.N + nt + c];
      ushort4 w4;
      w4.x = f2b(v.x); w4.y = f2b(v.y); w4.z = f2b(v.z); w4.w = f2b(v.w);
      *(ushort4*)&tile[r][c] = w4;
      if (d2) *(ushort4*)&d2[(size_t)(kt + r) * 1024 + nt + c] = w4;
    }
    __syncthreads();
    int tx = tid & 63, ty = tid >> 6;
    for (int r = ty; r < 64; r += 4)
      op[(size_t)(nt + r) * g.K + kt + tx] = tile[tx][r];
  } else {
    // ---- token pass: full f32 copy to out, patches->bf16, cls -> f32+bf16
    const int nblk = gridDim.x - nw;
    const int total = ca.tot4 + cb.tot4;
    for (int i = ((int)blockIdx.x - nw) * 256 + tid; i < total; i += nblk * 256) {
      CC2 g; int idx;
      if (i < ca.tot4) { g = ca; idx = i; } else { g = cb; idx = i - ca.tot4; }
      int rowg = idx >> g.shift, t = idx & ((1 << g.shift) - 1);
      int bb = rowg / g.Np1, row = rowg - bb * g.Np1;
      const float4 v = ((const float4*)g.tok)[idx];
      ((float4*)g.out)[idx] = v;
      ushort4 w2; w2.x = f2b(v.x); w2.y = f2b(v.y); w2.z = f2b(v.z); w2.w = f2b(v.w);
      if (row > 0) {
        ((ushort4*)g.abf)[(size_t)(bb * (g.Np1 - 1) + row - 1) * g.nf4 + t] = w2;
      } else {
        ((float4*)g.cls)[(size_t)bb * g.nf4 + t] = v;
        ((ushort4*)g.clsb)[(size_t)bb * g.nf4 + t] = w2;
      }
    }
  }
}

// setup2 = x^T transposes (depends on Abf from setup1), vectorized loads
struct TXArgs { const unsigned short* xbf; unsigned short* xT; int Nctx, dout, xstride, nx, ny, nblk; };
__global__ __launch_bounds__(256) void setup2(TXArgs ta, TXArgs tb) {
  __shared__ unsigned short tile[64][68];
  TXArgs g; int bx = blockIdx.x;
  if (bx < ta.nblk) { g = ta; } else { g = tb; bx -= ta.nblk; }
  int cx = bx % g.nx; int rem = bx / g.nx;
  int jy = rem % g.ny; int b = rem / g.ny;
  int jt = jy * 64, ct = cx * 64;
  const int tid = threadIdx.x;
#pragma unroll
  for (int p = 0; p < 4; p++) {
    int row = (tid >> 4) + p * 16;
    int c = (tid & 15) * 4;
    int j = jt + row;
    ushort4 v;
    if (j < g.Nctx) v = *(const ushort4*)&g.xbf[((size_t)b * g.Nctx + j) * g.dout + ct + c];
    else { v.x = 0; v.y = 0; v.z = 0; v.w = 0; }
    *(ushort4*)&tile[row][c] = v;
  }
  __syncthreads();
  int tx = tid & 63, ty = tid >> 6;
  for (int r = ty; r < 64; r += 4) {
    int col = jt + tx;
    if (col < g.xstride)
      g.xT[((size_t)b * g.dout + ct + r) * g.xstride + col] = tile[tx][r];
  }
}

// ========== wide small GEMM: M=64, one 16-col tile per 256-thr block =======
struct SGDesc {
  const unsigned short* A;    // [64][K] bf16
  const unsigned short* WT;   // [N][K] bf16
  const float* bias;          // [N] or null
  float* Cf;                  // f32 out [64][N] or null
  unsigned short* Cbf;        // bf16 out [64][N] or null
  const float* Rf;            // residual f32 in [64][N] or null
  int K, N;
  float* outF;                // extra f32 out with row stride ostride, or null
  int ostride;
};
struct SGArgs { SGDesc d[4]; int cum[5]; int nd; };
__global__ __launch_bounds__(256) void sg_wide(SGArgs W) {
  int bx = blockIdx.x, di = 0;
  while (di < W.nd - 1 && bx >= W.cum[di + 1]) di++;
  SGDesc g = W.d[di];
  const int n0 = (bx - W.cum[di]) * 16;
  const int tid = threadIdx.x;
  const int lane = tid & 63, mt = tid >> 6;
  const int r16 = lane & 15, kv8 = (lane >> 4) * 8;
  f32x4 acc; acc[0] = 0.f; acc[1] = 0.f; acc[2] = 0.f; acc[3] = 0.f;
  const unsigned short* wp = &g.WT[(size_t)(n0 + r16) * g.K + kv8];
  const unsigned short* ap = &g.A[(size_t)(mt * 16 + r16) * g.K + kv8];
  const int K = g.K;
#pragma unroll 4
  for (int k0 = 0; k0 < K; k0 += 32)
    acc = __builtin_amdgcn_mfma_f32_16x16x32_bf16(*(const bf16x8*)&ap[k0],
                                                  *(const bf16x8*)&wp[k0], acc, 0, 0, 0);
  const int rbase = (lane >> 4) * 4;
#pragma unroll
  for (int rr = 0; rr < 4; rr++) {
    int r = mt * 16 + rbase + rr, c = n0 + r16;
    float v = acc[rr];
    if (g.bias) v += g.bias[c];
    if (g.Rf) v += g.Rf[(size_t)r * g.N + c];
    if (g.Cf)  g.Cf[(size_t)r * g.N + c] = v;
    if (g.Cbf) g.Cbf[(size_t)r * g.N + c] = f2b(v);
    if (g.outF) g.outF[(size_t)r * g.ostride + c] = v;
  }
}

// =============================== layernorm =================================
struct LNArgs { const float* x; unsigned short* xnb; const float* ng; const float* nb; int dim; };
__global__ __launch_bounds__(256) void ln2(LNArgs la, LNArgs lb) {
  LNArgs g = ((int)blockIdx.x < 64) ? la : lb;
  int b = blockIdx.x & 63, t = threadIdx.x;
  __shared__ float rs[4], rq[4], bc[2];
  const float* xp = g.x + (size_t)b * g.dim;
  float s = 0.f, sq = 0.f;
  for (int c = t; c < g.dim; c += 256) {
    float v = xp[c];
    s += v; sq += v * v;
  }
#pragma unroll
  for (int off = 32; off >= 1; off >>= 1) {
    s += __shfl_down(s, off);
    sq += __shfl_down(sq, off);
  }
  int w = t >> 6;
  if ((t & 63) == 0) { rs[w] = s; rq[w] = sq; }
  __syncthreads();
  if (t == 0) {
    float ts = rs[0] + rs[1] + rs[2] + rs[3];
    float tq = rq[0] + rq[1] + rq[2] + rq[3];
    float mu = ts / g.dim;
    float var = tq / g.dim - mu * mu;
    bc[0] = mu; bc[1] = rsqrtf(var + 1e-5f);
  }
  __syncthreads();
  float mu = bc[0], r = bc[1];
  for (int c = t; c < g.dim; c += 256)
    g.xnb[(size_t)b * g.dim + c] = f2b((xp[c] - mu) * r * g.ng[c] + g.nb[c]);
}

// ==================== q~ via MFMA: q̃_bh = q_h(64x64) @ wkv_rows ============
struct QTArgs { const unsigned short* qb16; const unsigned short* wkvnb;
                unsigned short* qt; int dout, ntiles, nblk; };
__global__ __launch_bounds__(256) void qtilde3(QTArgs ga, QTArgs gb) {
  QTArgs g; int bx = blockIdx.x;
  if (bx < ga.nblk) g = ga; else { g = gb; bx -= ga.nblk; }
  const int h = bx / g.ntiles, nt = bx - h * g.ntiles;
  const int n0 = nt * 16;
  const int tid = threadIdx.x, lane = tid & 63, mt = tid >> 6;
  const int r16 = lane & 15, kv8 = (lane >> 4) * 8;
  const unsigned short* ap = g.qb16 + (size_t)(mt * 16 + r16) * INNER_ + h * 64 + kv8;
  const unsigned short* bp = g.wkvnb + (size_t)(n0 + r16) * 1024 + h * 64 + kv8;
  f32x4 acc; acc[0] = 0.f; acc[1] = 0.f; acc[2] = 0.f; acc[3] = 0.f;
  acc = __builtin_amdgcn_mfma_f32_16x16x32_bf16(*(const bf16x8*)&ap[0],
                                                *(const bf16x8*)&bp[0], acc, 0, 0, 0);
  acc = __builtin_amdgcn_mfma_f32_16x16x32_bf16(*(const bf16x8*)&ap[32],
                                                *(const bf16x8*)&bp[32], acc, 0, 0, 0);
  const int rbase = (lane >> 4) * 4;
#pragma unroll
  for (int rr = 0; rr < 4; rr++) {
    int b = mt * 16 + rbase + rr;
    g.qt[((size_t)b * 16 + h) * g.dout + n0 + r16] = f2b(acc[rr]);
  }
}

// ================= S = q~ . x^T (4 j-tiles per 256-thr block) ==============
struct SArgs { const unsigned short* qt; const unsigned short* xbf; float* S;
               int dout, Nctx, ntj, nbj, nblk; };
__global__ __launch_bounds__(256) void s_gemm(SArgs ga, SArgs gb) {
  SArgs g; int bx;
  if ((int)blockIdx.x < ga.nblk) { g = ga; bx = blockIdx.x; }
  else { g = gb; bx = blockIdx.x - ga.nblk; }
  const int b = bx / g.nbj, jq = bx - b * g.nbj;
  const int tid = threadIdx.x, lane = tid & 63, w = tid >> 6;
  const int jt = jq * 4 + w;
  if (jt >= g.ntj) return;
  const int r16 = lane & 15, kv8 = (lane >> 4) * 8;
  const unsigned short* ap = g.qt + ((size_t)b * 16 + r16) * g.dout + kv8;
  const unsigned short* bp = g.xbf + ((size_t)b * g.Nctx + jt * 16 + r16) * g.dout + kv8;
  f32x4 acc; acc[0]=0.f; acc[1]=0.f; acc[2]=0.f; acc[3]=0.f;
  const int K = g.dout;
#pragma unroll 4
  for (int k0 = 0; k0 < K; k0 += 32)
    acc = __builtin_amdgcn_mfma_f32_16x16x32_bf16(*(const bf16x8*)&ap[k0],
                                                  *(const bf16x8*)&bp[k0], acc, 0, 0, 0);
  const int rbase = (lane >> 4) * 4;
#pragma unroll
  for (int rr = 0; rr < 4; rr++)
    g.S[((size_t)b * 16 + rbase + rr) * SSTR + jt * 16 + r16] = acc[rr];
}

// ============================ softmax -> p (once) ==========================
struct SMArgs { const float* S; const float* qb; const float* kvc;
                unsigned short* p; float* pcls; int Nctx, Npad; };
__global__ __launch_bounds__(256) void softmax_p2(SMArgs ga, SMArgs gb) {
  SMArgs g = blockIdx.z ? gb : ga;
  const int h = blockIdx.x, b = blockIdx.y;
  const int t = threadIdx.x;
  __shared__ float red[4], bc;
  float sc = 0.f;
  if (t < 64) sc = g.qb[(size_t)b * INNER_ + h * 64 + t] * g.kvc[(size_t)b * 2048 + h * 64 + t];
#pragma unroll
  for (int o = 32; o >= 1; o >>= 1) sc += __shfl_down(sc, o);
  if (t == 0) bc = sc * 0.125f;
  __syncthreads();
  const float scls = bc;
  const float* Sp = g.S + ((size_t)b * 16 + h) * SSTR;

  float sraw[2] = {-1e30f, -1e30f};
#pragma unroll
  for (int u2 = 0; u2 < 2; u2++) {
    int j = t + u2 * 256;
    if (j < g.Nctx) sraw[u2] = Sp[j] * 0.125f;
  }
  float mx = fmaxf(fmaxf(sraw[0], sraw[1]), scls);
#pragma unroll
  for (int o = 32; o >= 1; o >>= 1) mx = fmaxf(mx, __shfl_down(mx, o));
  if ((t & 63) == 0) red[t >> 6] = mx;
  __syncthreads();
  mx = fmaxf(fmaxf(red[0], red[1]), fmaxf(red[2], red[3]));
  __syncthreads();

  float e0 = (t < g.Nctx) ? expf(sraw[0] - mx) : 0.f;
  float e1 = (t + 256 < g.Nctx) ? expf(sraw[1] - mx) : 0.f;
  float ecls = expf(scls - mx);
  float ls = e0 + e1;
#pragma unroll
  for (int o = 32; o >= 1; o >>= 1) ls += __shfl_down(ls, o);
  if ((t & 63) == 0) red[t >> 6] = ls;
  __syncthreads();
  const float denom = red[0] + red[1] + red[2] + red[3] + ecls;
  const float inv = 1.f / denom;

  unsigned short* pp = g.p + ((size_t)b * 16 + h) * PSTR;
  if (t < g.Nctx) pp[t] = f2b(e0 * inv);
  if (t + 256 < g.Nctx) pp[t + 256] = f2b(e1 * inv);
  for (int j = g.Nctx + t; j < g.Npad; j += 256) pp[j] = 0;
  if (t == 0) g.pcls[b * 16 + h] = ecls * inv;
}

// ============================ u = p . x ====================================
struct UG { const unsigned short* p; const unsigned short* xT; unsigned short* u;
            int dout, Npad, xstride, ntx; };
__global__ __launch_bounds__(256) void ugemm2(UG ga, UG gb) {
  UG g; int bx = blockIdx.x;
  if (bx < ga.ntx) g = ga; else { g = gb; bx -= ga.ntx; }
  const int b = blockIdx.y;
  const int tid = threadIdx.x, lane = tid & 63, w = tid >> 6;
  const int c0 = bx * 64 + w * 16;
  const int r16 = lane & 15, kv8 = (lane >> 4) * 8, rbase = (lane >> 4) * 4;
  const unsigned short* ap = g.p + ((size_t)b * 16 + r16) * PSTR + kv8;
  const unsigned short* bp = g.xT + ((size_t)b * g.dout + c0 + r16) * g.xstride + kv8;
  f32x4 acc; acc[0]=0.f; acc[1]=0.f; acc[2]=0.f; acc[3]=0.f;
#pragma unroll 2
  for (int k0 = 0; k0 < g.Npad; k0 += 32)
    acc = __builtin_amdgcn_mfma_f32_16x16x32_bf16(*(const bf16x8*)&ap[k0],
                                                  *(const bf16x8*)&bp[k0], acc, 0, 0, 0);
#pragma unroll
  for (int rr = 0; rr < 4; rr++)
    g.u[((size_t)b * 16 + rbase + rr) * g.dout + c0 + r16] = f2b(acc[rr]);
}

// ==================== o = u.Wv (+ cls term), 4 waves/block =================
struct OArgs {
  const unsigned short* u; const unsigned short* WTkv; const float* kvc; const float* pcls;
  unsigned short* ob; int dout;
};
__global__ __launch_bounds__(256) void ogemm_w(OArgs ga, OArgs gb) {
  OArgs g; int bx = blockIdx.x;
  if (bx < 64) { g = ga; } else { g = gb; bx -= 64; }
  const int h = bx >> 2, dt = bx & 3;
  const int tid = threadIdx.x, lane = tid & 63, mt = tid >> 6;
  const int r16 = lane & 15, kv8 = (lane >> 4) * 8;
  const int dout = g.dout;
  f32x4 acc; acc[0]=0.f; acc[1]=0.f; acc[2]=0.f; acc[3]=0.f;
  const unsigned short* wp = &g.WTkv[(size_t)(1024 + h * 64 + dt * 16 + r16) * dout + kv8];
  const unsigned short* up = &g.u[((size_t)(mt * 16 + r16) * 16 + h) * dout + kv8];
#pragma unroll 4
  for (int k0 = 0; k0 < dout; k0 += 32)
    acc = __builtin_amdgcn_mfma_f32_16x16x32_bf16(*(const bf16x8*)&up[k0],
                                                  *(const bf16x8*)&wp[k0], acc, 0, 0, 0);
  const int rbase = (lane >> 4) * 4;
#pragma unroll
  for (int rr = 0; rr < 4; rr++) {
    int bi = mt * 16 + rbase + rr;
    int d = h * 64 + dt * 16 + r16;
    float v = acc[rr] + g.pcls[bi * 16 + h] * g.kvc[(size_t)bi * 2048 + 1024 + d];
    g.ob[(size_t)bi * INNER_ + d] = f2b(v);
  }
}

// ================================ host =====================================
extern "C" void kernel_launch(void* const* d_in, const int* in_sizes, int n_in,
                              void* d_out, int out_size, void* d_ws, size_t ws_size,
                              hipStream_t stream) {
  const float* sm_tokens = (const float*)d_in[0];
  const float* lg_tokens = (const float*)d_in[1];
  const float* a_pin_w  = (const float*)d_in[2];  const float* a_pin_b  = (const float*)d_in[3];
  const float* a_ng     = (const float*)d_in[4];  const float* a_nb     = (const float*)d_in[5];
  const float* a_wq     = (const float*)d_in[6];  const float* a_wkv    = (const float*)d_in[7];
  const float* a_wo     = (const float*)d_in[8];  const float* a_wob    = (const float*)d_in[9];
  const float* a_pout_w = (const float*)d_in[10]; const float* a_pout_b = (const float*)d_in[11];
  const float* b_pin_w  = (const float*)d_in[12]; const float* b_pin_b  = (const float*)d_in[13];
  const float* b_ng     = (const float*)d_in[14]; const float* b_nb     = (const float*)d_in[15];
  const float* b_wq     = (const float*)d_in[16]; const float* b_wkv    = (const float*)d_in[17];
  const float* b_wo     = (const float*)d_in[18]; const float* b_wob    = (const float*)d_in[19];
  const float* b_pout_w = (const float*)d_in[20]; const float* b_pout_b = (const float*)d_in[21];

  float* out = (float*)d_out;
  char* ws = (char*)d_ws;
  size_t off = 0;
  auto alloc = [&](size_t bytes) -> void* {
    void* pt = ws + off;
    off += (bytes + 255) & ~(size_t)255;
    return pt;
  };
  unsigned short* Abf_lg = (unsigned short*)alloc(((size_t)B_ * NLG_ + 32) * LG_ * 2);
  unsigned short* Abf_sm = (unsigned short*)alloc(((size_t)B_ * NSM_ + 32) * SM_ * 2);
  unsigned short* xT_lg  = (unsigned short*)alloc((size_t)B_ * LG_ * 224 * 2);
  unsigned short* xT_sm  = (unsigned short*)alloc((size_t)B_ * SM_ * 416 * 2);
  unsigned short* WTkv_a = (unsigned short*)alloc((size_t)4 * 2048 * LG_ * 2);
  unsigned short* WTkv_b = (unsigned short*)alloc((size_t)4 * 2048 * SM_ * 2);
  unsigned short* wkvnb_a = (unsigned short*)alloc((size_t)4 * LG_ * 1024 * 2);
  unsigned short* wkvnb_b = (unsigned short*)alloc((size_t)4 * SM_ * 1024 * 2);
  unsigned short* WTpin_a = (unsigned short*)alloc((size_t)4 * SM_ * LG_ * 2);
  unsigned short* WTpin_b = (unsigned short*)alloc((size_t)4 * LG_ * SM_ * 2);
  unsigned short* WTwq_a  = (unsigned short*)alloc((size_t)4 * LG_ * INNER_ * 2);
  unsigned short* WTwq_b  = (unsigned short*)alloc((size_t)4 * SM_ * INNER_ * 2);
  unsigned short* WTwo_a  = (unsigned short*)alloc((size_t)4 * INNER_ * LG_ * 2);
  unsigned short* WTwo_b  = (unsigned short*)alloc((size_t)4 * INNER_ * SM_ * 2);
  unsigned short* WTpout_a = (unsigned short*)alloc((size_t)4 * LG_ * SM_ * 2);
  unsigned short* WTpout_b = (unsigned short*)alloc((size_t)4 * SM_ * LG_ * 2);
  unsigned short* qt_a = (unsigned short*)alloc((size_t)B_ * 16 * LG_ * 2);
  unsigned short* qt_b = (unsigned short*)alloc((size_t)B_ * 16 * SM_ * 2);
  float* S_a = (float*)alloc((size_t)B_ * 16 * SSTR * 4);
  float* S_b = (float*)alloc((size_t)B_ * 16 * SSTR * 4);
  unsigned short* p_a = (unsigned short*)alloc((size_t)B_ * 16 * PSTR * 2);
  unsigned short* p_b = (unsigned short*)alloc((size_t)B_ * 16 * PSTR * 2);
  unsigned short* u_a  = (unsigned short*)alloc((size_t)B_ * 16 * LG_ * 2);
  unsigned short* u_b  = (unsigned short*)alloc((size_t)B_ * 16 * SM_ * 2);
  float* pcls_a = (float*)alloc((size_t)B_ * 16 * 4);
  float* pcls_b = (float*)alloc((size_t)B_ * 16 * 4);
  float* cls_sm = (float*)alloc((size_t)B_ * SM_ * 4);
  float* cls_lg = (float*)alloc((size_t)B_ * LG_ * 4);
  unsigned short* clsb_sm = (unsigned short*)alloc((size_t)B_ * SM_ * 2);
  unsigned short* clsb_lg = (unsigned short*)alloc((size_t)B_ * LG_ * 2);
  float* xbuf_a = (float*)alloc((size_t)B_ * LG_ * 4);
  float* xbuf_b = (float*)alloc((size_t)B_ * SM_ * 4);
  unsigned short* xnb_a = (unsigned short*)alloc((size_t)B_ * LG_ * 2);
  unsigned short* xnb_b = (unsigned short*)alloc((size_t)B_ * SM_ * 2);
  float* qbuf_a = (float*)alloc((size_t)B_ * INNER_ * 4);
  float* qbuf_b = (float*)alloc((size_t)B_ * INNER_ * 4);
  unsigned short* qb16_a = (unsigned short*)alloc((size_t)B_ * INNER_ * 2);
  unsigned short* qb16_b = (unsigned short*)alloc((size_t)B_ * INNER_ * 2);
  float* kvc_a  = (float*)alloc((size_t)B_ * 2048 * 4);
  float* kvc_b  = (float*)alloc((size_t)B_ * 2048 * 4);
  unsigned short* obufb_a = (unsigned short*)alloc((size_t)B_ * INNER_ * 2);
  unsigned short* obufb_b = (unsigned short*)alloc((size_t)B_ * INNER_ * 2);
  unsigned short* t1b_a = (unsigned short*)alloc((size_t)B_ * LG_ * 2);
  unsigned short* t1b_b = (unsigned short*)alloc((size_t)B_ * SM_ * 2);
  (void)ws_size; (void)in_sizes; (void)n_in; (void)out_size;

  const size_t sm_elems = (size_t)B_ * (NSM_ + 1) * SM_;

  // ---- setup1: all weight transposes + token pass (one dispatch)
  CC2 ca{sm_tokens, out, Abf_sm, cls_sm, clsb_sm, NSM_ + 1, SM_ / 4, 7,
         (int)(sm_elems / 4)};
  CC2 cb{lg_tokens, out + sm_elems, Abf_lg, cls_lg, clsb_lg, NLG_ + 1, LG_ / 4, 8,
         (int)((size_t)B_ * (NLG_ + 1) * LG_ / 4)};
  WTArgs W;
  W.d[0] = {a_wkv,    WTkv_a,   wkvnb_a, LG_, 2048};
  W.d[1] = {b_wkv,    WTkv_b,   wkvnb_b, SM_, 2048};
  W.d[2] = {a_pin_w,  WTpin_a,  nullptr, SM_, LG_};
  W.d[3] = {b_pin_w,  WTpin_b,  nullptr, LG_, SM_};
  W.d[4] = {a_wq,     WTwq_a,   nullptr, LG_, INNER_};
  W.d[5] = {b_wq,     WTwq_b,   nullptr, SM_, INNER_};
  W.d[6] = {a_wo,     WTwo_a,   nullptr, INNER_, LG_};
  W.d[7] = {b_wo,     WTwo_b,   nullptr, INNER_, SM_};
  W.d[8] = {a_pout_w, WTpout_a, nullptr, LG_, SM_};
  W.d[9] = {b_pout_w, WTpout_b, nullptr, SM_, LG_};
  W.cum[0] = 0;
  for (int i = 0; i < 10; i++)
    W.cum[i + 1] = W.cum[i] + (W.d[i].K / 64) * (W.d[i].N / 64) * 4;
  setup1<<<W.cum[10] + 2048, 256, 0, stream>>>(ca, cb, W, W.cum[10]);
  // ---- setup2: x^T (needs Abf from setup1)
  TXArgs txa{Abf_lg, xT_lg, NLG_, LG_, 224, LG_ / 64, 4, B_ * (LG_ / 64) * 4};
  TXArgs txb{Abf_sm, xT_sm, NSM_, SM_, 416, SM_ / 64, 7, B_ * (SM_ / 64) * 7};
  setup2<<<txa.nblk + txb.nblk, 256, 0, stream>>>(txa, txb);

  for (int l = 0; l < 4; l++) {
    const unsigned short* WTpin_al = WTpin_a + (size_t)l * SM_ * LG_;
    const unsigned short* WTpin_bl = WTpin_b + (size_t)l * LG_ * SM_;
    const unsigned short* WTwq_al  = WTwq_a  + (size_t)l * LG_ * INNER_;
    const unsigned short* WTwq_bl  = WTwq_b  + (size_t)l * SM_ * INNER_;
    const unsigned short* WTkv_al  = WTkv_a  + (size_t)l * 2048 * LG_;
    const unsigned short* WTkv_bl  = WTkv_b  + (size_t)l * 2048 * SM_;
    const unsigned short* wkvnb_al = wkvnb_a + (size_t)l * LG_ * 1024;
    const unsigned short* wkvnb_bl = wkvnb_b + (size_t)l * SM_ * 1024;
    const unsigned short* WTwo_al  = WTwo_a  + (size_t)l * INNER_ * LG_;
    const unsigned short* WTwo_bl  = WTwo_b  + (size_t)l * INNER_ * SM_;
    const unsigned short* WTpout_al = WTpout_a + (size_t)l * LG_ * SM_;
    const unsigned short* WTpout_bl = WTpout_b + (size_t)l * SM_ * LG_;

    // pin
    SGArgs Gp; Gp.nd = 2;
    Gp.d[0] = {clsb_sm, WTpin_al, a_pin_b + (size_t)l * LG_, xbuf_a, nullptr, nullptr, SM_, LG_, nullptr, 0};
    Gp.d[1] = {clsb_lg, WTpin_bl, b_pin_b + (size_t)l * SM_, xbuf_b, nullptr, nullptr, LG_, SM_, nullptr, 0};
    Gp.cum[0] = 0; Gp.cum[1] = LG_ / 16; Gp.cum[2] = LG_ / 16 + SM_ / 16;
    sg_wide<<<Gp.cum[2], 256, 0, stream>>>(Gp);
    // ln
    LNArgs la{xbuf_a, xnb_a, a_ng + (size_t)l * LG_, a_nb + (size_t)l * LG_, LG_};
    LNArgs lb{xbuf_b, xnb_b, b_ng + (size_t)l * SM_, b_nb + (size_t)l * SM_, SM_};
    ln2<<<128, 256, 0, stream>>>(la, lb);
    // q (f32 + bf16 mirror) + kv (cls)
    SGArgs Gq; Gq.nd = 4;
    Gq.d[0] = {xnb_a, WTwq_al, nullptr, qbuf_a, qb16_a, nullptr, LG_, INNER_, nullptr, 0};
    Gq.d[1] = {xnb_a, WTkv_al, nullptr, kvc_a,  nullptr, nullptr, LG_, 2048, nullptr, 0};
    Gq.d[2] = {xnb_b, WTwq_bl, nullptr, qbuf_b, qb16_b, nullptr, SM_, INNER_, nullptr, 0};
    Gq.d[3] = {xnb_b, WTkv_bl, nullptr, kvc_b,  nullptr, nullptr, SM_, 2048, nullptr, 0};
    Gq.cum[0] = 0; Gq.cum[1] = 64; Gq.cum[2] = 192; Gq.cum[3] = 256; Gq.cum[4] = 384;
    sg_wide<<<384, 256, 0, stream>>>(Gq);
    // q~ (MFMA over bf16 straight wkv)
    QTArgs qa{qb16_a, wkvnb_al, qt_a, LG_, LG_ / 16, 16 * (LG_ / 16)};
    QTArgs qb{qb16_b, wkvnb_bl, qt_b, SM_, SM_ / 16, 16 * (SM_ / 16)};
    qtilde3<<<qa.nblk + qb.nblk, 256, 0, stream>>>(qa, qb);
    // S = q~ . x^T
    SArgs sa{qt_a, Abf_lg, S_a, LG_, NLG_, 14, 4, B_ * 4};
    SArgs sb{qt_b, Abf_sm, S_b, SM_, NSM_, 26, 7, B_ * 7};
    s_gemm<<<sa.nblk + sb.nblk, 256, 0, stream>>>(sa, sb);
    // softmax -> p (once per (b,h))
    SMArgs ma{S_a, qbuf_a, kvc_a, p_a, pcls_a, NLG_, 224};
    SMArgs mb{S_b, qbuf_b, kvc_b, p_b, pcls_b, NSM_, 416};
    softmax_p2<<<dim3(H_, B_, 2), 256, 0, stream>>>(ma, mb);
    // u = p . x
    UG ua{p_a, xT_lg, u_a, LG_, 224, 224, LG_ / 64};
    UG ub{p_b, xT_sm, u_b, SM_, 416, 416, SM_ / 64};
    ugemm2<<<dim3(LG_ / 64 + SM_ / 64, B_), 256, 0, stream>>>(ua, ub);
    // o = u . Wv + pcls * v_cls
    OArgs oa{u_a, WTkv_al, kvc_a, pcls_a, obufb_a, LG_};
    OArgs ob{u_b, WTkv_bl, kvc_b, pcls_b, obufb_b, SM_};
    ogemm_w<<<128, 256, 0, stream>>>(oa, ob);
    // wo
    SGArgs Gw; Gw.nd = 2;
    Gw.d[0] = {obufb_a, WTwo_al, a_wob + (size_t)l * LG_, nullptr, t1b_a, nullptr, INNER_, LG_, nullptr, 0};
    Gw.d[1] = {obufb_b, WTwo_bl, b_wob + (size_t)l * SM_, nullptr, t1b_b, nullptr, INNER_, SM_, nullptr, 0};
    Gw.cum[0] = 0; Gw.cum[1] = LG_ / 16; Gw.cum[2] = LG_ / 16 + SM_ / 16;
    sg_wide<<<Gw.cum[2], 256, 0, stream>>>(Gw);
    // pout + residual; on the last layer also write cls rows straight to out
    float* outF_a = (l == 3) ? out : nullptr;
    float* outF_b = (l == 3) ? out + sm_elems : nullptr;
    SGArgs Gr; Gr.nd = 2;
    Gr.d[0] = {t1b_a, WTpout_al, a_pout_b + (size_t)l * SM_, cls_sm, clsb_sm, cls_sm, LG_, SM_,
               outF_a, (NSM_ + 1) * SM_};
    Gr.d[1] = {t1b_b, WTpout_bl, b_pout_b + (size_t)l * LG_, cls_lg, clsb_lg, cls_lg, SM_, LG_,
               outF_b, (NLG_ + 1) * LG_};
    Gr.cum[0] = 0; Gr.cum[1] = SM_ / 16; Gr.cum[2] = SM_ / 16 + LG_ / 16;
    sg_wide<<<Gr.cum[2], 256, 0, stream>>>(Gr);
  }
}

// Round 14
// 587.576 us; speedup vs baseline: 6.0440x; 1.0232x over previous
//
#include <hip/hip_runtime.h>
#include <hip/hip_bf16.h>
#include <math.h>

#define B_     64
#define NSM_   400
#define NLG_   196
#define SM_    512
#define LG_    1024
#define H_     16
#define DH_    64
#define INNER_ 1024
#define SSTR   424    // S row stride (f32)
#define PSTR   424    // p LDS row stride (bf16)
#define NJMAX  7

typedef __attribute__((ext_vector_type(8))) short bf16x8;
typedef __attribute__((ext_vector_type(8))) unsigned short u16x8;
typedef __attribute__((ext_vector_type(4))) float f32x4;

__device__ __forceinline__ unsigned short f2b(float f) {
  unsigned u = __float_as_uint(f);
  u = u + 0x7FFFu + ((u >> 16) & 1u);   // RNE
  return (unsigned short)(u >> 16);
}

// ============================ setup kernels ================================

// setup1 = all 10 weight transposes (vectorized both ways) + token pass (nt copy)
struct CC2 { const float* tok; float* out; unsigned short* abf; float* cls;
             unsigned short* clsb; int Np1, nf4, shift, tot4; };
struct WTDesc { const float* src; unsigned short* dst; unsigned short* dst2; int K, N; };
struct WTArgs { WTDesc d[10]; int cum[11]; };
__global__ __launch_bounds__(256) void setup1(CC2 ca, CC2 cb, WTArgs W, int nw) {
  __shared__ unsigned short tile[64][68];   // 136B rows: 8B-aligned, 2-way banks (free)
  const int tid = threadIdx.x;
  if ((int)blockIdx.x < nw) {
    // ---- weight transpose: f32 (L,K,N) -> bf16 (L,N,K); wkv also straight (L,K,1024)
    int bx = blockIdx.x, di = 0;
    while (bx >= W.cum[di + 1]) di++;
    int local = bx - W.cum[di];
    WTDesc g = W.d[di];
    int tn = g.N >> 6;
    int tpl = tn * (g.K >> 6);
    int layer = local / tpl, rem = local % tpl;
    int kt = (rem / tn) * 64, nt = (rem % tn) * 64;
    const float* wp = g.src + (size_t)layer * g.K * g.N;
    unsigned short* op = g.dst + (size_t)layer * g.K * g.N;
    unsigned short* d2 = (g.dst2 && nt < 1024)
                             ? g.dst2 + (size_t)layer * g.K * 1024 : nullptr;
#pragma unroll
    for (int p = 0; p < 4; p++) {
      int r = (tid >> 4) + p * 16;
      int c = (tid & 15) * 4;
      const f32x4 v = *(const f32x4*)&wp[(size_t)(kt + r) * g.N + nt + c];
      ushort4 w4;
      w4.x = f2b(v.x); w4.y = f2b(v.y); w4.z = f2b(v.z); w4.w = f2b(v.w);
      *(ushort4*)&tile[r][c] = w4;
      if (d2) *(ushort4*)&d2[(size_t)(kt + r) * 1024 + nt + c] = w4;
    }
    __syncthreads();
    // vectorized transpose-out: thread (r2, cseg) writes 16 K-elems of row nt+r2
    const int r2 = tid & 63, cseg = tid >> 6;
    u16x8 v0, v1;
#pragma unroll
    for (int i = 0; i < 8; i++) v0[i] = tile[cseg * 16 + i][r2];
#pragma unroll
    for (int i = 0; i < 8; i++) v1[i] = tile[cseg * 16 + 8 + i][r2];
    unsigned short* orow = &op[(size_t)(nt + r2) * g.K + kt + cseg * 16];
    *(u16x8*)&orow[0] = v0;
    *(u16x8*)&orow[8] = v1;
  } else {
    // ---- token pass: f32 copy to out (non-temporal), patches->bf16, cls -> f32+bf16
    const int nblk = gridDim.x - nw;
    const int total = ca.tot4 + cb.tot4;
    for (int i = ((int)blockIdx.x - nw) * 256 + tid; i < total; i += nblk * 256) {
      CC2 g; int idx;
      if (i < ca.tot4) { g = ca; idx = i; } else { g = cb; idx = i - ca.tot4; }
      int rowg = idx >> g.shift, t = idx & ((1 << g.shift) - 1);
      int bb = rowg / g.Np1, row = rowg - bb * g.Np1;
      const f32x4 v = __builtin_nontemporal_load(&((const f32x4*)g.tok)[idx]);
      __builtin_nontemporal_store(v, &((f32x4*)g.out)[idx]);
      ushort4 w2; w2.x = f2b(v.x); w2.y = f2b(v.y); w2.z = f2b(v.z); w2.w = f2b(v.w);
      if (row > 0) {
        ((ushort4*)g.abf)[(size_t)(bb * (g.Np1 - 1) + row - 1) * g.nf4 + t] = w2;
      } else {
        ((f32x4*)g.cls)[(size_t)bb * g.nf4 + t] = v;
        ((ushort4*)g.clsb)[(size_t)bb * g.nf4 + t] = w2;
      }
    }
  }
}

// setup2 = x^T transposes (depends on Abf), vectorized loads + stores
struct TXArgs { const unsigned short* xbf; unsigned short* xT; int Nctx, dout, xstride, nx, ny, nblk; };
__global__ __launch_bounds__(256) void setup2(TXArgs ta, TXArgs tb) {
  __shared__ unsigned short tile[64][68];
  TXArgs g; int bx = blockIdx.x;
  if (bx < ta.nblk) { g = ta; } else { g = tb; bx -= ta.nblk; }
  int cx = bx % g.nx; int rem = bx / g.nx;
  int jy = rem % g.ny; int b = rem / g.ny;
  int jt = jy * 64, ct = cx * 64;
  const int tid = threadIdx.x;
#pragma unroll
  for (int p = 0; p < 4; p++) {
    int row = (tid >> 4) + p * 16;   // j-local
    int c = (tid & 15) * 4;          // dout-local
    int j = jt + row;
    ushort4 v;
    if (j < g.Nctx) v = *(const ushort4*)&g.xbf[((size_t)b * g.Nctx + j) * g.dout + ct + c];
    else { v.x = 0; v.y = 0; v.z = 0; v.w = 0; }
    *(ushort4*)&tile[row][c] = v;
  }
  __syncthreads();
  // thread (r2 = dout-local row, jseg) writes 16 j-elems (xstride%16==0 -> seg all-or-none)
  const int r2 = tid & 63, jseg = tid >> 6;
  if (jt + jseg * 16 < g.xstride) {
    u16x8 v0, v1;
#pragma unroll
    for (int i = 0; i < 8; i++) v0[i] = tile[jseg * 16 + i][r2];
#pragma unroll
    for (int i = 0; i < 8; i++) v1[i] = tile[jseg * 16 + 8 + i][r2];
    unsigned short* orow = &g.xT[((size_t)b * g.dout + ct + r2) * g.xstride + jt + jseg * 16];
    *(u16x8*)&orow[0] = v0;
    *(u16x8*)&orow[8] = v1;
  }
}

// ========== wide small GEMM: M=64, one 16-col tile per 256-thr block =======
struct SGDesc {
  const unsigned short* A; const unsigned short* WT; const float* bias;
  float* Cf; unsigned short* Cbf; const float* Rf;
  int K, N;
  float* outF; int ostride;
};
struct SGArgs { SGDesc d[4]; int cum[5]; int nd; };
__global__ __launch_bounds__(256) void sg_wide(SGArgs W) {
  int bx = blockIdx.x, di = 0;
  while (di < W.nd - 1 && bx >= W.cum[di + 1]) di++;
  SGDesc g = W.d[di];
  const int n0 = (bx - W.cum[di]) * 16;
  const int tid = threadIdx.x;
  const int lane = tid & 63, mt = tid >> 6;
  const int r16 = lane & 15, kv8 = (lane >> 4) * 8;
  f32x4 acc; acc[0] = 0.f; acc[1] = 0.f; acc[2] = 0.f; acc[3] = 0.f;
  const unsigned short* wp = &g.WT[(size_t)(n0 + r16) * g.K + kv8];
  const unsigned short* ap = &g.A[(size_t)(mt * 16 + r16) * g.K + kv8];
  const int K = g.K;
#pragma unroll 4
  for (int k0 = 0; k0 < K; k0 += 32)
    acc = __builtin_amdgcn_mfma_f32_16x16x32_bf16(*(const bf16x8*)&ap[k0],
                                                  *(const bf16x8*)&wp[k0], acc, 0, 0, 0);
  const int rbase = (lane >> 4) * 4;
#pragma unroll
  for (int rr = 0; rr < 4; rr++) {
    int r = mt * 16 + rbase + rr, c = n0 + r16;
    float v = acc[rr];
    if (g.bias) v += g.bias[c];
    if (g.Rf) v += g.Rf[(size_t)r * g.N + c];
    if (g.Cf)  g.Cf[(size_t)r * g.N + c] = v;
    if (g.Cbf) g.Cbf[(size_t)r * g.N + c] = f2b(v);
    if (g.outF) g.outF[(size_t)r * g.ostride + c] = v;
  }
}

// =============================== layernorm =================================
struct LNArgs { const float* x; unsigned short* xnb; const float* ng; const float* nb; int dim; };
__global__ __launch_bounds__(256) void ln2(LNArgs la, LNArgs lb) {
  LNArgs g = ((int)blockIdx.x < 64) ? la : lb;
  int b = blockIdx.x & 63, t = threadIdx.x;
  __shared__ float rs[4], rq[4], bc[2];
  const float* xp = g.x + (size_t)b * g.dim;
  float s = 0.f, sq = 0.f;
  for (int c = t; c < g.dim; c += 256) {
    float v = xp[c];
    s += v; sq += v * v;
  }
#pragma unroll
  for (int off = 32; off >= 1; off >>= 1) {
    s += __shfl_down(s, off);
    sq += __shfl_down(sq, off);
  }
  int w = t >> 6;
  if ((t & 63) == 0) { rs[w] = s; rq[w] = sq; }
  __syncthreads();
  if (t == 0) {
    float ts = rs[0] + rs[1] + rs[2] + rs[3];
    float tq = rq[0] + rq[1] + rq[2] + rq[3];
    float mu = ts / g.dim;
    float var = tq / g.dim - mu * mu;
    bc[0] = mu; bc[1] = rsqrtf(var + 1e-5f);
  }
  __syncthreads();
  float mu = bc[0], r = bc[1];
  for (int c = t; c < g.dim; c += 256)
    g.xnb[(size_t)b * g.dim + c] = f2b((xp[c] - mu) * r * g.ng[c] + g.nb[c]);
}

// ==================== q~ via MFMA: q̃_bh = q_h(64x64) @ wkv_rows ============
struct QTArgs { const unsigned short* qb16; const unsigned short* wkvnb;
                unsigned short* qt; int dout, ntiles, nblk; };
__global__ __launch_bounds__(256) void qtilde3(QTArgs ga, QTArgs gb) {
  QTArgs g; int bx = blockIdx.x;
  if (bx < ga.nblk) g = ga; else { g = gb; bx -= ga.nblk; }
  const int h = bx / g.ntiles, nt = bx - h * g.ntiles;
  const int n0 = nt * 16;
  const int tid = threadIdx.x, lane = tid & 63, mt = tid >> 6;
  const int r16 = lane & 15, kv8 = (lane >> 4) * 8;
  const unsigned short* ap = g.qb16 + (size_t)(mt * 16 + r16) * INNER_ + h * 64 + kv8;
  const unsigned short* bp = g.wkvnb + (size_t)(n0 + r16) * 1024 + h * 64 + kv8;
  f32x4 acc; acc[0] = 0.f; acc[1] = 0.f; acc[2] = 0.f; acc[3] = 0.f;
  acc = __builtin_amdgcn_mfma_f32_16x16x32_bf16(*(const bf16x8*)&ap[0],
                                                *(const bf16x8*)&bp[0], acc, 0, 0, 0);
  acc = __builtin_amdgcn_mfma_f32_16x16x32_bf16(*(const bf16x8*)&ap[32],
                                                *(const bf16x8*)&bp[32], acc, 0, 0, 0);
  const int rbase = (lane >> 4) * 4;
#pragma unroll
  for (int rr = 0; rr < 4; rr++) {
    int b = mt * 16 + rbase + rr;
    g.qt[((size_t)b * 16 + h) * g.dout + n0 + r16] = f2b(acc[rr]);
  }
}

// ================= S = q~ . x^T (4 j-tiles per 256-thr block) ==============
struct SArgs { const unsigned short* qt; const unsigned short* xbf; float* S;
               int dout, Nctx, ntj, nbj, nblk; };
__global__ __launch_bounds__(256) void s_gemm(SArgs ga, SArgs gb) {
  SArgs g; int bx;
  if ((int)blockIdx.x < ga.nblk) { g = ga; bx = blockIdx.x; }
  else { g = gb; bx = blockIdx.x - ga.nblk; }
  const int b = bx / g.nbj, jq = bx - b * g.nbj;
  const int tid = threadIdx.x, lane = tid & 63, w = tid >> 6;
  const int jt = jq * 4 + w;
  if (jt >= g.ntj) return;
  const int r16 = lane & 15, kv8 = (lane >> 4) * 8;
  const unsigned short* ap = g.qt + ((size_t)b * 16 + r16) * g.dout + kv8;
  const unsigned short* bp = g.xbf + ((size_t)b * g.Nctx + jt * 16 + r16) * g.dout + kv8;
  f32x4 acc; acc[0]=0.f; acc[1]=0.f; acc[2]=0.f; acc[3]=0.f;
  const int K = g.dout;
#pragma unroll 4
  for (int k0 = 0; k0 < K; k0 += 32)
    acc = __builtin_amdgcn_mfma_f32_16x16x32_bf16(*(const bf16x8*)&ap[k0],
                                                  *(const bf16x8*)&bp[k0], acc, 0, 0, 0);
  const int rbase = (lane >> 4) * 4;
#pragma unroll
  for (int rr = 0; rr < 4; rr++)
    g.S[((size_t)b * 16 + rbase + rr) * SSTR + jt * 16 + r16] = acc[rr];
}

// ================= softmax (redundant per block) + u = p . x ===============
struct UArgs {
  const float* S; const float* qb; const float* kvc; const unsigned short* xT;
  unsigned short* u; float* pcls; int dout, Nctx, Npad, xstride, ntc, nblk;
};
__global__ __launch_bounds__(256) void usoftmax(UArgs ga, UArgs gb) {
  __shared__ unsigned short p_s[16 * PSTR];
  UArgs g; int bx;
  if ((int)blockIdx.x < ga.nblk) { g = ga; bx = blockIdx.x; }
  else { g = gb; bx = blockIdx.x - ga.nblk; }
  const int b = bx / g.ntc, ct = bx - b * g.ntc;
  const int t = threadIdx.x, lane = t & 63, w = t >> 6;
  // ---- softmax: wave w handles heads w*4 .. w*4+3 (redundant across ct-blocks)
  for (int hh = 0; hh < 4; hh++) {
    const int h = w * 4 + hh;
    const float* Sp = g.S + ((size_t)b * 16 + h) * SSTR;
    float sc = g.qb[(size_t)b * 1024 + h * 64 + lane] * g.kvc[(size_t)b * 2048 + h * 64 + lane];
#pragma unroll
    for (int o = 32; o >= 1; o >>= 1) sc += __shfl_down(sc, o);
    sc = __shfl(sc, 0) * 0.125f;
    float sv[NJMAX];
    float mr = -1e30f;
#pragma unroll
    for (int ji = 0; ji < NJMAX; ji++) {
      int j = ji * 64 + lane;
      sv[ji] = (j < g.Nctx) ? Sp[j] * 0.125f : -1e30f;
      mr = fmaxf(mr, sv[ji]);
    }
#pragma unroll
    for (int o = 32; o >= 1; o >>= 1) mr = fmaxf(mr, __shfl_down(mr, o));
    mr = __shfl(mr, 0);
    const float m = fmaxf(mr, sc);
    float es = 0.f;
#pragma unroll
    for (int ji = 0; ji < NJMAX; ji++) {
      int j = ji * 64 + lane;
      float e = (j < g.Nctx) ? expf(sv[ji] - m) : 0.f;
      sv[ji] = e; es += e;
    }
#pragma unroll
    for (int o = 32; o >= 1; o >>= 1) es += __shfl_down(es, o);
    es = __shfl(es, 0);
    const float ecls = expf(sc - m);
    const float inv = 1.f / (es + ecls);
#pragma unroll
    for (int ji = 0; ji < NJMAX; ji++) {
      int j = ji * 64 + lane;
      if (j < g.Npad) p_s[h * PSTR + j] = (j < g.Nctx) ? f2b(sv[ji] * inv) : (unsigned short)0;
    }
    if (ct == 0 && lane == 0) g.pcls[b * 16 + h] = ecls * inv;
  }
  __syncthreads();
  // ---- u-phase: wave w computes 16-col subtile at ct*64 + w*16
  const int r16 = lane & 15, kv8 = (lane >> 4) * 8, rbase = (lane >> 4) * 4;
  const int c0 = ct * 64 + w * 16;
  f32x4 acc; acc[0]=0.f; acc[1]=0.f; acc[2]=0.f; acc[3]=0.f;
  const unsigned short* bp = g.xT + ((size_t)b * g.dout + c0 + r16) * g.xstride + kv8;
  const unsigned short* apl = &p_s[r16 * PSTR + kv8];
  const int Kp = g.Npad;
#pragma unroll 4
  for (int k0 = 0; k0 < Kp; k0 += 32)
    acc = __builtin_amdgcn_mfma_f32_16x16x32_bf16(*(const bf16x8*)&apl[k0],
                                                  *(const bf16x8*)&bp[k0], acc, 0, 0, 0);
#pragma unroll
  for (int rr = 0; rr < 4; rr++)
    g.u[((size_t)b * 16 + rbase + rr) * g.dout + c0 + r16] = f2b(acc[rr]);
}

// ==================== o = u.Wv (+ cls term), 4 waves/block =================
struct OArgs {
  const unsigned short* u; const unsigned short* WTkv; const float* kvc; const float* pcls;
  unsigned short* ob; int dout;
};
__global__ __launch_bounds__(256) void ogemm_w(OArgs ga, OArgs gb) {
  OArgs g; int bx = blockIdx.x;
  if (bx < 64) { g = ga; } else { g = gb; bx -= 64; }
  const int h = bx >> 2, dt = bx & 3;
  const int tid = threadIdx.x, lane = tid & 63, mt = tid >> 6;
  const int r16 = lane & 15, kv8 = (lane >> 4) * 8;
  const int dout = g.dout;
  f32x4 acc; acc[0]=0.f; acc[1]=0.f; acc[2]=0.f; acc[3]=0.f;
  const unsigned short* wp = &g.WTkv[(size_t)(1024 + h * 64 + dt * 16 + r16) * dout + kv8];
  const unsigned short* up = &g.u[((size_t)(mt * 16 + r16) * 16 + h) * dout + kv8];
#pragma unroll 4
  for (int k0 = 0; k0 < dout; k0 += 32)
    acc = __builtin_amdgcn_mfma_f32_16x16x32_bf16(*(const bf16x8*)&up[k0],
                                                  *(const bf16x8*)&wp[k0], acc, 0, 0, 0);
  const int rbase = (lane >> 4) * 4;
#pragma unroll
  for (int rr = 0; rr < 4; rr++) {
    int bi = mt * 16 + rbase + rr;
    int d = h * 64 + dt * 16 + r16;
    float v = acc[rr] + g.pcls[bi * 16 + h] * g.kvc[(size_t)bi * 2048 + 1024 + d];
    g.ob[(size_t)bi * INNER_ + d] = f2b(v);
  }
}

// ================================ host =====================================
extern "C" void kernel_launch(void* const* d_in, const int* in_sizes, int n_in,
                              void* d_out, int out_size, void* d_ws, size_t ws_size,
                              hipStream_t stream) {
  const float* sm_tokens = (const float*)d_in[0];
  const float* lg_tokens = (const float*)d_in[1];
  const float* a_pin_w  = (const float*)d_in[2];  const float* a_pin_b  = (const float*)d_in[3];
  const float* a_ng     = (const float*)d_in[4];  const float* a_nb     = (const float*)d_in[5];
  const float* a_wq     = (const float*)d_in[6];  const float* a_wkv    = (const float*)d_in[7];
  const float* a_wo     = (const float*)d_in[8];  const float* a_wob    = (const float*)d_in[9];
  const float* a_pout_w = (const float*)d_in[10]; const float* a_pout_b = (const float*)d_in[11];
  const float* b_pin_w  = (const float*)d_in[12]; const float* b_pin_b  = (const float*)d_in[13];
  const float* b_ng     = (const float*)d_in[14]; const float* b_nb     = (const float*)d_in[15];
  const float* b_wq     = (const float*)d_in[16]; const float* b_wkv    = (const float*)d_in[17];
  const float* b_wo     = (const float*)d_in[18]; const float* b_wob    = (const float*)d_in[19];
  const float* b_pout_w = (const float*)d_in[20]; const float* b_pout_b = (const float*)d_in[21];

  float* out = (float*)d_out;
  char* ws = (char*)d_ws;
  size_t off = 0;
  auto alloc = [&](size_t bytes) -> void* {
    void* pt = ws + off;
    off += (bytes + 255) & ~(size_t)255;
    return pt;
  };
  unsigned short* Abf_lg = (unsigned short*)alloc(((size_t)B_ * NLG_ + 32) * LG_ * 2);
  unsigned short* Abf_sm = (unsigned short*)alloc(((size_t)B_ * NSM_ + 32) * SM_ * 2);
  unsigned short* xT_lg  = (unsigned short*)alloc((size_t)B_ * LG_ * 224 * 2);
  unsigned short* xT_sm  = (unsigned short*)alloc((size_t)B_ * SM_ * 416 * 2);
  unsigned short* WTkv_a = (unsigned short*)alloc((size_t)4 * 2048 * LG_ * 2);
  unsigned short* WTkv_b = (unsigned short*)alloc((size_t)4 * 2048 * SM_ * 2);
  unsigned short* wkvnb_a = (unsigned short*)alloc((size_t)4 * LG_ * 1024 * 2);
  unsigned short* wkvnb_b = (unsigned short*)alloc((size_t)4 * SM_ * 1024 * 2);
  unsigned short* WTpin_a = (unsigned short*)alloc((size_t)4 * SM_ * LG_ * 2);
  unsigned short* WTpin_b = (unsigned short*)alloc((size_t)4 * LG_ * SM_ * 2);
  unsigned short* WTwq_a  = (unsigned short*)alloc((size_t)4 * LG_ * INNER_ * 2);
  unsigned short* WTwq_b  = (unsigned short*)alloc((size_t)4 * SM_ * INNER_ * 2);
  unsigned short* WTwo_a  = (unsigned short*)alloc((size_t)4 * INNER_ * LG_ * 2);
  unsigned short* WTwo_b  = (unsigned short*)alloc((size_t)4 * INNER_ * SM_ * 2);
  unsigned short* WTpout_a = (unsigned short*)alloc((size_t)4 * LG_ * SM_ * 2);
  unsigned short* WTpout_b = (unsigned short*)alloc((size_t)4 * SM_ * LG_ * 2);
  unsigned short* qt_a = (unsigned short*)alloc((size_t)B_ * 16 * LG_ * 2);
  unsigned short* qt_b = (unsigned short*)alloc((size_t)B_ * 16 * SM_ * 2);
  float* S_a = (float*)alloc((size_t)B_ * 16 * SSTR * 4);
  float* S_b = (float*)alloc((size_t)B_ * 16 * SSTR * 4);
  unsigned short* u_a  = (unsigned short*)alloc((size_t)B_ * 16 * LG_ * 2);
  unsigned short* u_b  = (unsigned short*)alloc((size_t)B_ * 16 * SM_ * 2);
  float* pcls_a = (float*)alloc((size_t)B_ * 16 * 4);
  float* pcls_b = (float*)alloc((size_t)B_ * 16 * 4);
  float* cls_sm = (float*)alloc((size_t)B_ * SM_ * 4);
  float* cls_lg = (float*)alloc((size_t)B_ * LG_ * 4);
  unsigned short* clsb_sm = (unsigned short*)alloc((size_t)B_ * SM_ * 2);
  unsigned short* clsb_lg = (unsigned short*)alloc((size_t)B_ * LG_ * 2);
  float* xbuf_a = (float*)alloc((size_t)B_ * LG_ * 4);
  float* xbuf_b = (float*)alloc((size_t)B_ * SM_ * 4);
  unsigned short* xnb_a = (unsigned short*)alloc((size_t)B_ * LG_ * 2);
  unsigned short* xnb_b = (unsigned short*)alloc((size_t)B_ * SM_ * 2);
  float* qbuf_a = (float*)alloc((size_t)B_ * INNER_ * 4);
  float* qbuf_b = (float*)alloc((size_t)B_ * INNER_ * 4);
  unsigned short* qb16_a = (unsigned short*)alloc((size_t)B_ * INNER_ * 2);
  unsigned short* qb16_b = (unsigned short*)alloc((size_t)B_ * INNER_ * 2);
  float* kvc_a  = (float*)alloc((size_t)B_ * 2048 * 4);
  float* kvc_b  = (float*)alloc((size_t)B_ * 2048 * 4);
  unsigned short* obufb_a = (unsigned short*)alloc((size_t)B_ * INNER_ * 2);
  unsigned short* obufb_b = (unsigned short*)alloc((size_t)B_ * INNER_ * 2);
  unsigned short* t1b_a = (unsigned short*)alloc((size_t)B_ * LG_ * 2);
  unsigned short* t1b_b = (unsigned short*)alloc((size_t)B_ * SM_ * 2);
  (void)ws_size; (void)in_sizes; (void)n_in; (void)out_size;

  const size_t sm_elems = (size_t)B_ * (NSM_ + 1) * SM_;

  // ---- setup1: all weight transposes + token pass (one dispatch)
  CC2 ca{sm_tokens, out, Abf_sm, cls_sm, clsb_sm, NSM_ + 1, SM_ / 4, 7,
         (int)(sm_elems / 4)};
  CC2 cb{lg_tokens, out + sm_elems, Abf_lg, cls_lg, clsb_lg, NLG_ + 1, LG_ / 4, 8,
         (int)((size_t)B_ * (NLG_ + 1) * LG_ / 4)};
  WTArgs W;
  W.d[0] = {a_wkv,    WTkv_a,   wkvnb_a, LG_, 2048};
  W.d[1] = {b_wkv,    WTkv_b,   wkvnb_b, SM_, 2048};
  W.d[2] = {a_pin_w,  WTpin_a,  nullptr, SM_, LG_};
  W.d[3] = {b_pin_w,  WTpin_b,  nullptr, LG_, SM_};
  W.d[4] = {a_wq,     WTwq_a,   nullptr, LG_, INNER_};
  W.d[5] = {b_wq,     WTwq_b,   nullptr, SM_, INNER_};
  W.d[6] = {a_wo,     WTwo_a,   nullptr, INNER_, LG_};
  W.d[7] = {b_wo,     WTwo_b,   nullptr, INNER_, SM_};
  W.d[8] = {a_pout_w, WTpout_a, nullptr, LG_, SM_};
  W.d[9] = {b_pout_w, WTpout_b, nullptr, SM_, LG_};
  W.cum[0] = 0;
  for (int i = 0; i < 10; i++)
    W.cum[i + 1] = W.cum[i] + (W.d[i].K / 64) * (W.d[i].N / 64) * 4;
  setup1<<<W.cum[10] + 2048, 256, 0, stream>>>(ca, cb, W, W.cum[10]);
  // ---- setup2: x^T (needs Abf from setup1)
  TXArgs txa{Abf_lg, xT_lg, NLG_, LG_, 224, LG_ / 64, 4, B_ * (LG_ / 64) * 4};
  TXArgs txb{Abf_sm, xT_sm, NSM_, SM_, 416, SM_ / 64, 7, B_ * (SM_ / 64) * 7};
  setup2<<<txa.nblk + txb.nblk, 256, 0, stream>>>(txa, txb);

  for (int l = 0; l < 4; l++) {
    const unsigned short* WTpin_al = WTpin_a + (size_t)l * SM_ * LG_;
    const unsigned short* WTpin_bl = WTpin_b + (size_t)l * LG_ * SM_;
    const unsigned short* WTwq_al  = WTwq_a  + (size_t)l * LG_ * INNER_;
    const unsigned short* WTwq_bl  = WTwq_b  + (size_t)l * SM_ * INNER_;
    const unsigned short* WTkv_al  = WTkv_a  + (size_t)l * 2048 * LG_;
    const unsigned short* WTkv_bl  = WTkv_b  + (size_t)l * 2048 * SM_;
    const unsigned short* wkvnb_al = wkvnb_a + (size_t)l * LG_ * 1024;
    const unsigned short* wkvnb_bl = wkvnb_b + (size_t)l * SM_ * 1024;
    const unsigned short* WTwo_al  = WTwo_a  + (size_t)l * INNER_ * LG_;
    const unsigned short* WTwo_bl  = WTwo_b  + (size_t)l * INNER_ * SM_;
    const unsigned short* WTpout_al = WTpout_a + (size_t)l * LG_ * SM_;
    const unsigned short* WTpout_bl = WTpout_b + (size_t)l * SM_ * LG_;

    // pin
    SGArgs Gp; Gp.nd = 2;
    Gp.d[0] = {clsb_sm, WTpin_al, a_pin_b + (size_t)l * LG_, xbuf_a, nullptr, nullptr, SM_, LG_, nullptr, 0};
    Gp.d[1] = {clsb_lg, WTpin_bl, b_pin_b + (size_t)l * SM_, xbuf_b, nullptr, nullptr, LG_, SM_, nullptr, 0};
    Gp.cum[0] = 0; Gp.cum[1] = LG_ / 16; Gp.cum[2] = LG_ / 16 + SM_ / 16;
    sg_wide<<<Gp.cum[2], 256, 0, stream>>>(Gp);
    // ln
    LNArgs la{xbuf_a, xnb_a, a_ng + (size_t)l * LG_, a_nb + (size_t)l * LG_, LG_};
    LNArgs lb{xbuf_b, xnb_b, b_ng + (size_t)l * SM_, b_nb + (size_t)l * SM_, SM_};
    ln2<<<128, 256, 0, stream>>>(la, lb);
    // q (f32 + bf16 mirror) + kv (cls)
    SGArgs Gq; Gq.nd = 4;
    Gq.d[0] = {xnb_a, WTwq_al, nullptr, qbuf_a, qb16_a, nullptr, LG_, INNER_, nullptr, 0};
    Gq.d[1] = {xnb_a, WTkv_al, nullptr, kvc_a,  nullptr, nullptr, LG_, 2048, nullptr, 0};
    Gq.d[2] = {xnb_b, WTwq_bl, nullptr, qbuf_b, qb16_b, nullptr, SM_, INNER_, nullptr, 0};
    Gq.d[3] = {xnb_b, WTkv_bl, nullptr, kvc_b,  nullptr, nullptr, SM_, 2048, nullptr, 0};
    Gq.cum[0] = 0; Gq.cum[1] = 64; Gq.cum[2] = 192; Gq.cum[3] = 256; Gq.cum[4] = 384;
    sg_wide<<<384, 256, 0, stream>>>(Gq);
    // q~ (MFMA over bf16 straight wkv)
    QTArgs qa{qb16_a, wkvnb_al, qt_a, LG_, LG_ / 16, 16 * (LG_ / 16)};
    QTArgs qb{qb16_b, wkvnb_bl, qt_b, SM_, SM_ / 16, 16 * (SM_ / 16)};
    qtilde3<<<qa.nblk + qb.nblk, 256, 0, stream>>>(qa, qb);
    // S = q~ . x^T
    SArgs sa{qt_a, Abf_lg, S_a, LG_, NLG_, 14, 4, B_ * 4};
    SArgs sb{qt_b, Abf_sm, S_b, SM_, NSM_, 26, 7, B_ * 7};
    s_gemm<<<sa.nblk + sb.nblk, 256, 0, stream>>>(sa, sb);
    // softmax (in-LDS, redundant per block) + u = p . x
    UArgs ua{S_a, qbuf_a, kvc_a, xT_lg, u_a, pcls_a, LG_, NLG_, 224, 224, LG_ / 64, B_ * (LG_ / 64)};
    UArgs ub{S_b, qbuf_b, kvc_b, xT_sm, u_b, pcls_b, SM_, NSM_, 416, 416, SM_ / 64, B_ * (SM_ / 64)};
    usoftmax<<<ua.nblk + ub.nblk, 256, 0, stream>>>(ua, ub);
    // o = u . Wv + pcls * v_cls
    OArgs oa{u_a, WTkv_al, kvc_a, pcls_a, obufb_a, LG_};
    OArgs ob{u_b, WTkv_bl, kvc_b, pcls_b, obufb_b, SM_};
    ogemm_w<<<128, 256, 0, stream>>>(oa, ob);
    // wo
    SGArgs Gw; Gw.nd = 2;
    Gw.d[0] = {obufb_a, WTwo_al, a_wob + (size_t)l * LG_, nullptr, t1b_a, nullptr, INNER_, LG_, nullptr, 0};
    Gw.d[1] = {obufb_b, WTwo_bl, b_wob + (size_t)l * SM_, nullptr, t1b_b, nullptr, INNER_, SM_, nullptr, 0};
    Gw.cum[0] = 0; Gw.cum[1] = LG_ / 16; Gw.cum[2] = LG_ / 16 + SM_ / 16;
    sg_wide<<<Gw.cum[2], 256, 0, stream>>>(Gw);
    // pout + residual; on the last layer also write cls rows straight to out
    float* outF_a = (l == 3) ? out : nullptr;
    float* outF_b = (l == 3) ? out + sm_elems : nullptr;
    SGArgs Gr; Gr.nd = 2;
    Gr.d[0] = {t1b_a, WTpout_al, a_pout_b + (size_t)l * SM_, cls_sm, clsb_sm, cls_sm, LG_, SM_,
               outF_a, (NSM_ + 1) * SM_};
    Gr.d[1] = {t1b_b, WTpout_bl, b_pout_b + (size_t)l * LG_, cls_lg, clsb_lg, cls_lg, SM_, LG_,
               outF_b, (NLG_ + 1) * LG_};
    Gr.cum[0] = 0; Gr.cum[1] = SM_ / 16; Gr.cum[2] = SM_ / 16 + LG_ / 16;
    sg_wide<<<Gr.cum[2], 256, 0, stream>>>(Gr);
  }
}

// Round 15
// 559.359 us; speedup vs baseline: 6.3489x; 1.0504x over previous
//
#include <hip/hip_runtime.h>
#include <hip/hip_bf16.h>
#include <math.h>

#define B_     64
#define NSM_   400
#define NLG_   196
#define SM_    512
#define LG_    1024
#define H_     16
#define DH_    64
#define INNER_ 1024
#define SSTR   424    // S row stride (f32)
#define PSTR   424    // p LDS row stride (bf16)
#define NJMAX  7

typedef __attribute__((ext_vector_type(8))) short bf16x8;
typedef __attribute__((ext_vector_type(8))) unsigned short u16x8;
typedef __attribute__((ext_vector_type(4))) float f32x4;

__device__ __forceinline__ unsigned short f2b(float f) {
  unsigned u = __float_as_uint(f);
  u = u + 0x7FFFu + ((u >> 16) & 1u);   // RNE
  return (unsigned short)(u >> 16);
}

// ============================ setup kernels ================================

// setup1 = all 10 weight transposes + token pass (nt copy)
struct CC2 { const float* tok; float* out; unsigned short* abf; float* cls;
             unsigned short* clsb; int Np1, nf4, shift, tot4; };
struct WTDesc { const float* src; unsigned short* dst; unsigned short* dst2; int K, N; };
struct WTArgs { WTDesc d[10]; int cum[11]; };
__global__ __launch_bounds__(256) void setup1(CC2 ca, CC2 cb, WTArgs W, int nw) {
  __shared__ unsigned short tile[64][68];   // 136B rows: 8B-aligned
  const int tid = threadIdx.x;
  if ((int)blockIdx.x < nw) {
    // ---- weight transpose: f32 (L,K,N) -> bf16 (L,N,K); wkv also straight (L,K,1024)
    int bx = blockIdx.x, di = 0;
    while (bx >= W.cum[di + 1]) di++;
    int local = bx - W.cum[di];
    WTDesc g = W.d[di];
    int tn = g.N >> 6;
    int tpl = tn * (g.K >> 6);
    int layer = local / tpl, rem = local % tpl;
    int kt = (rem / tn) * 64, nt = (rem % tn) * 64;
    const float* wp = g.src + (size_t)layer * g.K * g.N;
    unsigned short* op = g.dst + (size_t)layer * g.K * g.N;
    unsigned short* d2 = (g.dst2 && nt < 1024)
                             ? g.dst2 + (size_t)layer * g.K * 1024 : nullptr;
#pragma unroll
    for (int p = 0; p < 4; p++) {
      int r = (tid >> 4) + p * 16;
      int c = (tid & 15) * 4;
      const f32x4 v = __builtin_nontemporal_load(
          (const f32x4*)&wp[(size_t)(kt + r) * g.N + nt + c]);
      ushort4 w4;
      w4.x = f2b(v.x); w4.y = f2b(v.y); w4.z = f2b(v.z); w4.w = f2b(v.w);
      *(ushort4*)&tile[r][c] = w4;
      if (d2) *(ushort4*)&d2[(size_t)(kt + r) * 1024 + nt + c] = w4;
    }
    __syncthreads();
    // coalesced transpose-out: 4-lane cluster writes one contiguous 128B row chunk
    const int r2 = tid >> 2, cseg = tid & 3;
    u16x8 v0, v1;
#pragma unroll
    for (int i = 0; i < 8; i++) v0[i] = tile[cseg * 16 + i][r2];
#pragma unroll
    for (int i = 0; i < 8; i++) v1[i] = tile[cseg * 16 + 8 + i][r2];
    unsigned short* orow = &op[(size_t)(nt + r2) * g.K + kt + cseg * 16];
    *(u16x8*)&orow[0] = v0;
    *(u16x8*)&orow[8] = v1;
  } else {
    // ---- token pass: f32 copy to out (non-temporal), patches->bf16, cls -> f32+bf16
    const int nblk = gridDim.x - nw;
    const int total = ca.tot4 + cb.tot4;
    for (int i = ((int)blockIdx.x - nw) * 256 + tid; i < total; i += nblk * 256) {
      CC2 g; int idx;
      if (i < ca.tot4) { g = ca; idx = i; } else { g = cb; idx = i - ca.tot4; }
      int rowg = idx >> g.shift, t = idx & ((1 << g.shift) - 1);
      int bb = rowg / g.Np1, row = rowg - bb * g.Np1;
      const f32x4 v = __builtin_nontemporal_load(&((const f32x4*)g.tok)[idx]);
      __builtin_nontemporal_store(v, &((f32x4*)g.out)[idx]);
      ushort4 w2; w2.x = f2b(v.x); w2.y = f2b(v.y); w2.z = f2b(v.z); w2.w = f2b(v.w);
      if (row > 0) {
        ((ushort4*)g.abf)[(size_t)(bb * (g.Np1 - 1) + row - 1) * g.nf4 + t] = w2;
      } else {
        ((f32x4*)g.cls)[(size_t)bb * g.nf4 + t] = v;
        ((ushort4*)g.clsb)[(size_t)bb * g.nf4 + t] = w2;
      }
    }
  }
}

// setup2 = x^T transposes (depends on Abf), coalesced writes
struct TXArgs { const unsigned short* xbf; unsigned short* xT; int Nctx, dout, xstride, nx, ny, nblk; };
__global__ __launch_bounds__(256) void setup2(TXArgs ta, TXArgs tb) {
  __shared__ unsigned short tile[64][68];
  TXArgs g; int bx = blockIdx.x;
  if (bx < ta.nblk) { g = ta; } else { g = tb; bx -= ta.nblk; }
  int cx = bx % g.nx; int rem = bx / g.nx;
  int jy = rem % g.ny; int b = rem / g.ny;
  int jt = jy * 64, ct = cx * 64;
  const int tid = threadIdx.x;
#pragma unroll
  for (int p = 0; p < 4; p++) {
    int row = (tid >> 4) + p * 16;   // j-local
    int c = (tid & 15) * 4;          // dout-local
    int j = jt + row;
    ushort4 v;
    if (j < g.Nctx) v = *(const ushort4*)&g.xbf[((size_t)b * g.Nctx + j) * g.dout + ct + c];
    else { v.x = 0; v.y = 0; v.z = 0; v.w = 0; }
    *(ushort4*)&tile[row][c] = v;
  }
  __syncthreads();
  // 4-lane cluster writes contiguous 128B chunk of output row ct+r2
  const int r2 = tid >> 2, jseg = tid & 3;
  if (jt + jseg * 16 < g.xstride) {
    u16x8 v0, v1;
#pragma unroll
    for (int i = 0; i < 8; i++) v0[i] = tile[jseg * 16 + i][r2];
#pragma unroll
    for (int i = 0; i < 8; i++) v1[i] = tile[jseg * 16 + 8 + i][r2];
    unsigned short* orow = &g.xT[((size_t)b * g.dout + ct + r2) * g.xstride + jt + jseg * 16];
    *(u16x8*)&orow[0] = v0;
    *(u16x8*)&orow[8] = v1;
  }
}

// ========== wide small GEMM: M=64, one 16-col tile per 256-thr block =======
struct SGDesc {
  const unsigned short* A; const unsigned short* WT; const float* bias;
  float* Cf; unsigned short* Cbf; const float* Rf;
  int K, N;
  float* outF; int ostride;
};
struct SGArgs { SGDesc d[4]; int cum[5]; int nd; };
__global__ __launch_bounds__(256) void sg_wide(SGArgs W) {
  int bx = blockIdx.x, di = 0;
  while (di < W.nd - 1 && bx >= W.cum[di + 1]) di++;
  SGDesc g = W.d[di];
  const int n0 = (bx - W.cum[di]) * 16;
  const int tid = threadIdx.x;
  const int lane = tid & 63, mt = tid >> 6;
  const int r16 = lane & 15, kv8 = (lane >> 4) * 8;
  f32x4 acc; acc[0] = 0.f; acc[1] = 0.f; acc[2] = 0.f; acc[3] = 0.f;
  const unsigned short* wp = &g.WT[(size_t)(n0 + r16) * g.K + kv8];
  const unsigned short* ap = &g.A[(size_t)(mt * 16 + r16) * g.K + kv8];
  const int K = g.K;
#pragma unroll 4
  for (int k0 = 0; k0 < K; k0 += 32)
    acc = __builtin_amdgcn_mfma_f32_16x16x32_bf16(*(const bf16x8*)&ap[k0],
                                                  *(const bf16x8*)&wp[k0], acc, 0, 0, 0);
  const int rbase = (lane >> 4) * 4;
#pragma unroll
  for (int rr = 0; rr < 4; rr++) {
    int r = mt * 16 + rbase + rr, c = n0 + r16;
    float v = acc[rr];
    if (g.bias) v += g.bias[c];
    if (g.Rf) v += g.Rf[(size_t)r * g.N + c];
    if (g.Cf)  g.Cf[(size_t)r * g.N + c] = v;
    if (g.Cbf) g.Cbf[(size_t)r * g.N + c] = f2b(v);
    if (g.outF) g.outF[(size_t)r * g.ostride + c] = v;
  }
}

// =============================== layernorm =================================
struct LNArgs { const float* x; unsigned short* xnb; const float* ng; const float* nb; int dim; };
__global__ __launch_bounds__(256) void ln2(LNArgs la, LNArgs lb) {
  LNArgs g = ((int)blockIdx.x < 64) ? la : lb;
  int b = blockIdx.x & 63, t = threadIdx.x;
  __shared__ float rs[4], rq[4], bc[2];
  const float* xp = g.x + (size_t)b * g.dim;
  float s = 0.f, sq = 0.f;
  for (int c = t; c < g.dim; c += 256) {
    float v = xp[c];
    s += v; sq += v * v;
  }
#pragma unroll
  for (int off = 32; off >= 1; off >>= 1) {
    s += __shfl_down(s, off);
    sq += __shfl_down(sq, off);
  }
  int w = t >> 6;
  if ((t & 63) == 0) { rs[w] = s; rq[w] = sq; }
  __syncthreads();
  if (t == 0) {
    float ts = rs[0] + rs[1] + rs[2] + rs[3];
    float tq = rq[0] + rq[1] + rq[2] + rq[3];
    float mu = ts / g.dim;
    float var = tq / g.dim - mu * mu;
    bc[0] = mu; bc[1] = rsqrtf(var + 1e-5f);
  }
  __syncthreads();
  float mu = bc[0], r = bc[1];
  for (int c = t; c < g.dim; c += 256)
    g.xnb[(size_t)b * g.dim + c] = f2b((xp[c] - mu) * r * g.ng[c] + g.nb[c]);
}

// ==================== q~ via MFMA: q̃_bh = q_h(64x64) @ wkv_rows ============
struct QTArgs { const unsigned short* qb16; const unsigned short* wkvnb;
                unsigned short* qt; int dout, ntiles, nblk; };
__global__ __launch_bounds__(256) void qtilde3(QTArgs ga, QTArgs gb) {
  QTArgs g; int bx = blockIdx.x;
  if (bx < ga.nblk) g = ga; else { g = gb; bx -= ga.nblk; }
  const int h = bx / g.ntiles, nt = bx - h * g.ntiles;
  const int n0 = nt * 16;
  const int tid = threadIdx.x, lane = tid & 63, mt = tid >> 6;
  const int r16 = lane & 15, kv8 = (lane >> 4) * 8;
  const unsigned short* ap = g.qb16 + (size_t)(mt * 16 + r16) * INNER_ + h * 64 + kv8;
  const unsigned short* bp = g.wkvnb + (size_t)(n0 + r16) * 1024 + h * 64 + kv8;
  f32x4 acc; acc[0] = 0.f; acc[1] = 0.f; acc[2] = 0.f; acc[3] = 0.f;
  acc = __builtin_amdgcn_mfma_f32_16x16x32_bf16(*(const bf16x8*)&ap[0],
                                                *(const bf16x8*)&bp[0], acc, 0, 0, 0);
  acc = __builtin_amdgcn_mfma_f32_16x16x32_bf16(*(const bf16x8*)&ap[32],
                                                *(const bf16x8*)&bp[32], acc, 0, 0, 0);
  const int rbase = (lane >> 4) * 4;
#pragma unroll
  for (int rr = 0; rr < 4; rr++) {
    int b = mt * 16 + rbase + rr;
    g.qt[((size_t)b * 16 + h) * g.dout + n0 + r16] = f2b(acc[rr]);
  }
}

// ================= S = q~ . x^T (4 j-tiles per 256-thr block) ==============
struct SArgs { const unsigned short* qt; const unsigned short* xbf; float* S;
               int dout, Nctx, ntj, nbj, nblk; };
__global__ __launch_bounds__(256) void s_gemm(SArgs ga, SArgs gb) {
  SArgs g; int bx;
  if ((int)blockIdx.x < ga.nblk) { g = ga; bx = blockIdx.x; }
  else { g = gb; bx = blockIdx.x - ga.nblk; }
  const int b = bx / g.nbj, jq = bx - b * g.nbj;
  const int tid = threadIdx.x, lane = tid & 63, w = tid >> 6;
  const int jt = jq * 4 + w;
  if (jt >= g.ntj) return;
  const int r16 = lane & 15, kv8 = (lane >> 4) * 8;
  const unsigned short* ap = g.qt + ((size_t)b * 16 + r16) * g.dout + kv8;
  const unsigned short* bp = g.xbf + ((size_t)b * g.Nctx + jt * 16 + r16) * g.dout + kv8;
  f32x4 acc; acc[0]=0.f; acc[1]=0.f; acc[2]=0.f; acc[3]=0.f;
  const int K = g.dout;
#pragma unroll 4
  for (int k0 = 0; k0 < K; k0 += 32)
    acc = __builtin_amdgcn_mfma_f32_16x16x32_bf16(*(const bf16x8*)&ap[k0],
                                                  *(const bf16x8*)&bp[k0], acc, 0, 0, 0);
  const int rbase = (lane >> 4) * 4;
#pragma unroll
  for (int rr = 0; rr < 4; rr++)
    g.S[((size_t)b * 16 + rbase + rr) * SSTR + jt * 16 + r16] = acc[rr];
}

// ================= softmax (redundant per block) + u = p . x ===============
struct UArgs {
  const float* S; const float* qb; const float* kvc; const unsigned short* xT;
  unsigned short* u; float* pcls; int dout, Nctx, Npad, xstride, ntc, nblk;
};
__global__ __launch_bounds__(256) void usoftmax(UArgs ga, UArgs gb) {
  __shared__ unsigned short p_s[16 * PSTR];
  UArgs g; int bx;
  if ((int)blockIdx.x < ga.nblk) { g = ga; bx = blockIdx.x; }
  else { g = gb; bx = blockIdx.x - ga.nblk; }
  const int b = bx / g.ntc, ct = bx - b * g.ntc;
  const int t = threadIdx.x, lane = t & 63, w = t >> 6;
  for (int hh = 0; hh < 4; hh++) {
    const int h = w * 4 + hh;
    const float* Sp = g.S + ((size_t)b * 16 + h) * SSTR;
    float sc = g.qb[(size_t)b * 1024 + h * 64 + lane] * g.kvc[(size_t)b * 2048 + h * 64 + lane];
#pragma unroll
    for (int o = 32; o >= 1; o >>= 1) sc += __shfl_down(sc, o);
    sc = __shfl(sc, 0) * 0.125f;
    float sv[NJMAX];
    float mr = -1e30f;
#pragma unroll
    for (int ji = 0; ji < NJMAX; ji++) {
      int j = ji * 64 + lane;
      sv[ji] = (j < g.Nctx) ? Sp[j] * 0.125f : -1e30f;
      mr = fmaxf(mr, sv[ji]);
    }
#pragma unroll
    for (int o = 32; o >= 1; o >>= 1) mr = fmaxf(mr, __shfl_down(mr, o));
    mr = __shfl(mr, 0);
    const float m = fmaxf(mr, sc);
    float es = 0.f;
#pragma unroll
    for (int ji = 0; ji < NJMAX; ji++) {
      int j = ji * 64 + lane;
      float e = (j < g.Nctx) ? expf(sv[ji] - m) : 0.f;
      sv[ji] = e; es += e;
    }
#pragma unroll
    for (int o = 32; o >= 1; o >>= 1) es += __shfl_down(es, o);
    es = __shfl(es, 0);
    const float ecls = expf(sc - m);
    const float inv = 1.f / (es + ecls);
#pragma unroll
    for (int ji = 0; ji < NJMAX; ji++) {
      int j = ji * 64 + lane;
      if (j < g.Npad) p_s[h * PSTR + j] = (j < g.Nctx) ? f2b(sv[ji] * inv) : (unsigned short)0;
    }
    if (ct == 0 && lane == 0) g.pcls[b * 16 + h] = ecls * inv;
  }
  __syncthreads();
  const int r16 = lane & 15, kv8 = (lane >> 4) * 8, rbase = (lane >> 4) * 4;
  const int c0 = ct * 64 + w * 16;
  f32x4 acc; acc[0]=0.f; acc[1]=0.f; acc[2]=0.f; acc[3]=0.f;
  const unsigned short* bp = g.xT + ((size_t)b * g.dout + c0 + r16) * g.xstride + kv8;
  const unsigned short* apl = &p_s[r16 * PSTR + kv8];
  const int Kp = g.Npad;
#pragma unroll 4
  for (int k0 = 0; k0 < Kp; k0 += 32)
    acc = __builtin_amdgcn_mfma_f32_16x16x32_bf16(*(const bf16x8*)&apl[k0],
                                                  *(const bf16x8*)&bp[k0], acc, 0, 0, 0);
#pragma unroll
  for (int rr = 0; rr < 4; rr++)
    g.u[((size_t)b * 16 + rbase + rr) * g.dout + c0 + r16] = f2b(acc[rr]);
}

// ==================== o = u.Wv (+ cls term), 4 waves/block =================
struct OArgs {
  const unsigned short* u; const unsigned short* WTkv; const float* kvc; const float* pcls;
  unsigned short* ob; int dout;
};
__global__ __launch_bounds__(256) void ogemm_w(OArgs ga, OArgs gb) {
  OArgs g; int bx = blockIdx.x;
  if (bx < 64) { g = ga; } else { g = gb; bx -= 64; }
  const int h = bx >> 2, dt = bx & 3;
  const int tid = threadIdx.x, lane = tid & 63, mt = tid >> 6;
  const int r16 = lane & 15, kv8 = (lane >> 4) * 8;
  const int dout = g.dout;
  f32x4 acc; acc[0]=0.f; acc[1]=0.f; acc[2]=0.f; acc[3]=0.f;
  const unsigned short* wp = &g.WTkv[(size_t)(1024 + h * 64 + dt * 16 + r16) * dout + kv8];
  const unsigned short* up = &g.u[((size_t)(mt * 16 + r16) * 16 + h) * dout + kv8];
#pragma unroll 4
  for (int k0 = 0; k0 < dout; k0 += 32)
    acc = __builtin_amdgcn_mfma_f32_16x16x32_bf16(*(const bf16x8*)&up[k0],
                                                  *(const bf16x8*)&wp[k0], acc, 0, 0, 0);
  const int rbase = (lane >> 4) * 4;
#pragma unroll
  for (int rr = 0; rr < 4; rr++) {
    int bi = mt * 16 + rbase + rr;
    int d = h * 64 + dt * 16 + r16;
    float v = acc[rr] + g.pcls[bi * 16 + h] * g.kvc[(size_t)bi * 2048 + 1024 + d];
    g.ob[(size_t)bi * INNER_ + d] = f2b(v);
  }
}

// ================================ host =====================================
extern "C" void kernel_launch(void* const* d_in, const int* in_sizes, int n_in,
                              void* d_out, int out_size, void* d_ws, size_t ws_size,
                              hipStream_t stream) {
  const float* sm_tokens = (const float*)d_in[0];
  const float* lg_tokens = (const float*)d_in[1];
  const float* a_pin_w  = (const float*)d_in[2];  const float* a_pin_b  = (const float*)d_in[3];
  const float* a_ng     = (const float*)d_in[4];  const float* a_nb     = (const float*)d_in[5];
  const float* a_wq     = (const float*)d_in[6];  const float* a_wkv    = (const float*)d_in[7];
  const float* a_wo     = (const float*)d_in[8];  const float* a_wob    = (const float*)d_in[9];
  const float* a_pout_w = (const float*)d_in[10]; const float* a_pout_b = (const float*)d_in[11];
  const float* b_pin_w  = (const float*)d_in[12]; const float* b_pin_b  = (const float*)d_in[13];
  const float* b_ng     = (const float*)d_in[14]; const float* b_nb     = (const float*)d_in[15];
  const float* b_wq     = (const float*)d_in[16]; const float* b_wkv    = (const float*)d_in[17];
  const float* b_wo     = (const float*)d_in[18]; const float* b_wob    = (const float*)d_in[19];
  const float* b_pout_w = (const float*)d_in[20]; const float* b_pout_b = (const float*)d_in[21];

  float* out = (float*)d_out;
  char* ws = (char*)d_ws;
  size_t off = 0;
  auto alloc = [&](size_t bytes) -> void* {
    void* pt = ws + off;
    off += (bytes + 255) & ~(size_t)255;
    return pt;
  };
  unsigned short* Abf_lg = (unsigned short*)alloc(((size_t)B_ * NLG_ + 32) * LG_ * 2);
  unsigned short* Abf_sm = (unsigned short*)alloc(((size_t)B_ * NSM_ + 32) * SM_ * 2);
  unsigned short* xT_lg  = (unsigned short*)alloc((size_t)B_ * LG_ * 224 * 2);
  unsigned short* xT_sm  = (unsigned short*)alloc((size_t)B_ * SM_ * 416 * 2);
  unsigned short* WTkv_a = (unsigned short*)alloc((size_t)4 * 2048 * LG_ * 2);
  unsigned short* WTkv_b = (unsigned short*)alloc((size_t)4 * 2048 * SM_ * 2);
  unsigned short* wkvnb_a = (unsigned short*)alloc((size_t)4 * LG_ * 1024 * 2);
  unsigned short* wkvnb_b = (unsigned short*)alloc((size_t)4 * SM_ * 1024 * 2);
  unsigned short* WTpin_a = (unsigned short*)alloc((size_t)4 * SM_ * LG_ * 2);
  unsigned short* WTpin_b = (unsigned short*)alloc((size_t)4 * LG_ * SM_ * 2);
  unsigned short* WTwq_a  = (unsigned short*)alloc((size_t)4 * LG_ * INNER_ * 2);
  unsigned short* WTwq_b  = (unsigned short*)alloc((size_t)4 * SM_ * INNER_ * 2);
  unsigned short* WTwo_a  = (unsigned short*)alloc((size_t)4 * INNER_ * LG_ * 2);
  unsigned short* WTwo_b  = (unsigned short*)alloc((size_t)4 * INNER_ * SM_ * 2);
  unsigned short* WTpout_a = (unsigned short*)alloc((size_t)4 * LG_ * SM_ * 2);
  unsigned short* WTpout_b = (unsigned short*)alloc((size_t)4 * SM_ * LG_ * 2);
  unsigned short* qt_a = (unsigned short*)alloc((size_t)B_ * 16 * LG_ * 2);
  unsigned short* qt_b = (unsigned short*)alloc((size_t)B_ * 16 * SM_ * 2);
  float* S_a = (float*)alloc((size_t)B_ * 16 * SSTR * 4);
  float* S_b = (float*)alloc((size_t)B_ * 16 * SSTR * 4);
  unsigned short* u_a  = (unsigned short*)alloc((size_t)B_ * 16 * LG_ * 2);
  unsigned short* u_b  = (unsigned short*)alloc((size_t)B_ * 16 * SM_ * 2);
  float* pcls_a = (float*)alloc((size_t)B_ * 16 * 4);
  float* pcls_b = (float*)alloc((size_t)B_ * 16 * 4);
  float* cls_sm = (float*)alloc((size_t)B_ * SM_ * 4);
  float* cls_lg = (float*)alloc((size_t)B_ * LG_ * 4);
  unsigned short* clsb_sm = (unsigned short*)alloc((size_t)B_ * SM_ * 2);
  unsigned short* clsb_lg = (unsigned short*)alloc((size_t)B_ * LG_ * 2);
  float* xbuf_a = (float*)alloc((size_t)B_ * LG_ * 4);
  float* xbuf_b = (float*)alloc((size_t)B_ * SM_ * 4);
  unsigned short* xnb_a = (unsigned short*)alloc((size_t)B_ * LG_ * 2);
  unsigned short* xnb_b = (unsigned short*)alloc((size_t)B_ * SM_ * 2);
  float* qbuf_a = (float*)alloc((size_t)B_ * INNER_ * 4);
  float* qbuf_b = (float*)alloc((size_t)B_ * INNER_ * 4);
  unsigned short* qb16_a = (unsigned short*)alloc((size_t)B_ * INNER_ * 2);
  unsigned short* qb16_b = (unsigned short*)alloc((size_t)B_ * INNER_ * 2);
  float* kvc_a  = (float*)alloc((size_t)B_ * 2048 * 4);
  float* kvc_b  = (float*)alloc((size_t)B_ * 2048 * 4);
  unsigned short* obufb_a = (unsigned short*)alloc((size_t)B_ * INNER_ * 2);
  unsigned short* obufb_b = (unsigned short*)alloc((size_t)B_ * INNER_ * 2);
  unsigned short* t1b_a = (unsigned short*)alloc((size_t)B_ * LG_ * 2);
  unsigned short* t1b_b = (unsigned short*)alloc((size_t)B_ * SM_ * 2);
  (void)ws_size; (void)in_sizes; (void)n_in; (void)out_size;

  const size_t sm_elems = (size_t)B_ * (NSM_ + 1) * SM_;

  // ---- setup1: all weight transposes + token pass (one dispatch)
  CC2 ca{sm_tokens, out, Abf_sm, cls_sm, clsb_sm, NSM_ + 1, SM_ / 4, 7,
         (int)(sm_elems / 4)};
  CC2 cb{lg_tokens, out + sm_elems, Abf_lg, cls_lg, clsb_lg, NLG_ + 1, LG_ / 4, 8,
         (int)((size_t)B_ * (NLG_ + 1) * LG_ / 4)};
  WTArgs W;
  W.d[0] = {a_wkv,    WTkv_a,   wkvnb_a, LG_, 2048};
  W.d[1] = {b_wkv,    WTkv_b,   wkvnb_b, SM_, 2048};
  W.d[2] = {a_pin_w,  WTpin_a,  nullptr, SM_, LG_};
  W.d[3] = {b_pin_w,  WTpin_b,  nullptr, LG_, SM_};
  W.d[4] = {a_wq,     WTwq_a,   nullptr, LG_, INNER_};
  W.d[5] = {b_wq,     WTwq_b,   nullptr, SM_, INNER_};
  W.d[6] = {a_wo,     WTwo_a,   nullptr, INNER_, LG_};
  W.d[7] = {b_wo,     WTwo_b,   nullptr, INNER_, SM_};
  W.d[8] = {a_pout_w, WTpout_a, nullptr, LG_, SM_};
  W.d[9] = {b_pout_w, WTpout_b, nullptr, SM_, LG_};
  W.cum[0] = 0;
  for (int i = 0; i < 10; i++)
    W.cum[i + 1] = W.cum[i] + (W.d[i].K / 64) * (W.d[i].N / 64) * 4;
  setup1<<<W.cum[10] + 2048, 256, 0, stream>>>(ca, cb, W, W.cum[10]);
  // ---- setup2: x^T (needs Abf from setup1)
  TXArgs txa{Abf_lg, xT_lg, NLG_, LG_, 224, LG_ / 64, 4, B_ * (LG_ / 64) * 4};
  TXArgs txb{Abf_sm, xT_sm, NSM_, SM_, 416, SM_ / 64, 7, B_ * (SM_ / 64) * 7};
  setup2<<<txa.nblk + txb.nblk, 256, 0, stream>>>(txa, txb);

  for (int l = 0; l < 4; l++) {
    const unsigned short* WTpin_al = WTpin_a + (size_t)l * SM_ * LG_;
    const unsigned short* WTpin_bl = WTpin_b + (size_t)l * LG_ * SM_;
    const unsigned short* WTwq_al  = WTwq_a  + (size_t)l * LG_ * INNER_;
    const unsigned short* WTwq_bl  = WTwq_b  + (size_t)l * SM_ * INNER_;
    const unsigned short* WTkv_al  = WTkv_a  + (size_t)l * 2048 * LG_;
    const unsigned short* WTkv_bl  = WTkv_b  + (size_t)l * 2048 * SM_;
    const unsigned short* wkvnb_al = wkvnb_a + (size_t)l * LG_ * 1024;
    const unsigned short* wkvnb_bl = wkvnb_b + (size_t)l * SM_ * 1024;
    const unsigned short* WTwo_al  = WTwo_a  + (size_t)l * INNER_ * LG_;
    const unsigned short* WTwo_bl  = WTwo_b  + (size_t)l * INNER_ * SM_;
    const unsigned short* WTpout_al = WTpout_a + (size_t)l * LG_ * SM_;
    const unsigned short* WTpout_bl = WTpout_b + (size_t)l * SM_ * LG_;

    // pin
    SGArgs Gp; Gp.nd = 2;
    Gp.d[0] = {clsb_sm, WTpin_al, a_pin_b + (size_t)l * LG_, xbuf_a, nullptr, nullptr, SM_, LG_, nullptr, 0};
    Gp.d[1] = {clsb_lg, WTpin_bl, b_pin_b + (size_t)l * SM_, xbuf_b, nullptr, nullptr, LG_, SM_, nullptr, 0};
    Gp.cum[0] = 0; Gp.cum[1] = LG_ / 16; Gp.cum[2] = LG_ / 16 + SM_ / 16;
    sg_wide<<<Gp.cum[2], 256, 0, stream>>>(Gp);
    // ln
    LNArgs la{xbuf_a, xnb_a, a_ng + (size_t)l * LG_, a_nb + (size_t)l * LG_, LG_};
    LNArgs lb{xbuf_b, xnb_b, b_ng + (size_t)l * SM_, b_nb + (size_t)l * SM_, SM_};
    ln2<<<128, 256, 0, stream>>>(la, lb);
    // q (f32 + bf16 mirror) + kv (cls)
    SGArgs Gq; Gq.nd = 4;
    Gq.d[0] = {xnb_a, WTwq_al, nullptr, qbuf_a, qb16_a, nullptr, LG_, INNER_, nullptr, 0};
    Gq.d[1] = {xnb_a, WTkv_al, nullptr, kvc_a,  nullptr, nullptr, LG_, 2048, nullptr, 0};
    Gq.d[2] = {xnb_b, WTwq_bl, nullptr, qbuf_b, qb16_b, nullptr, SM_, INNER_, nullptr, 0};
    Gq.d[3] = {xnb_b, WTkv_bl, nullptr, kvc_b,  nullptr, nullptr, SM_, 2048, nullptr, 0};
    Gq.cum[0] = 0; Gq.cum[1] = 64; Gq.cum[2] = 192; Gq.cum[3] = 256; Gq.cum[4] = 384;
    sg_wide<<<384, 256, 0, stream>>>(Gq);
    // q~ (MFMA over bf16 straight wkv)
    QTArgs qa{qb16_a, wkvnb_al, qt_a, LG_, LG_ / 16, 16 * (LG_ / 16)};
    QTArgs qb{qb16_b, wkvnb_bl, qt_b, SM_, SM_ / 16, 16 * (SM_ / 16)};
    qtilde3<<<qa.nblk + qb.nblk, 256, 0, stream>>>(qa, qb);
    // S = q~ . x^T
    SArgs sa{qt_a, Abf_lg, S_a, LG_, NLG_, 14, 4, B_ * 4};
    SArgs sb{qt_b, Abf_sm, S_b, SM_, NSM_, 26, 7, B_ * 7};
    s_gemm<<<sa.nblk + sb.nblk, 256, 0, stream>>>(sa, sb);
    // softmax (in-LDS, redundant per block) + u = p . x
    UArgs ua{S_a, qbuf_a, kvc_a, xT_lg, u_a, pcls_a, LG_, NLG_, 224, 224, LG_ / 64, B_ * (LG_ / 64)};
    UArgs ub{S_b, qbuf_b, kvc_b, xT_sm, u_b, pcls_b, SM_, NSM_, 416, 416, SM_ / 64, B_ * (SM_ / 64)};
    usoftmax<<<ua.nblk + ub.nblk, 256, 0, stream>>>(ua, ub);
    // o = u . Wv + pcls * v_cls
    OArgs oa{u_a, WTkv_al, kvc_a, pcls_a, obufb_a, LG_};
    OArgs ob{u_b, WTkv_bl, kvc_b, pcls_b, obufb_b, SM_};
    ogemm_w<<<128, 256, 0, stream>>>(oa, ob);
    // wo
    SGArgs Gw; Gw.nd = 2;
    Gw.d[0] = {obufb_a, WTwo_al, a_wob + (size_t)l * LG_, nullptr, t1b_a, nullptr, INNER_, LG_, nullptr, 0};
    Gw.d[1] = {obufb_b, WTwo_bl, b_wob + (size_t)l * SM_, nullptr, t1b_b, nullptr, INNER_, SM_, nullptr, 0};
    Gw.cum[0] = 0; Gw.cum[1] = LG_ / 16; Gw.cum[2] = LG_ / 16 + SM_ / 16;
    sg_wide<<<Gw.cum[2], 256, 0, stream>>>(Gw);
    // pout + residual; on the last layer also write cls rows straight to out
    float* outF_a = (l == 3) ? out : nullptr;
    float* outF_b = (l == 3) ? out + sm_elems : nullptr;
    SGArgs Gr; Gr.nd = 2;
    Gr.d[0] = {t1b_a, WTpout_al, a_pout_b + (size_t)l * SM_, cls_sm, clsb_sm, cls_sm, LG_, SM_,
               outF_a, (NSM_ + 1) * SM_};
    Gr.d[1] = {t1b_b, WTpout_bl, b_pout_b + (size_t)l * LG_, cls_lg, clsb_lg, cls_lg, SM_, LG_,
               outF_b, (NLG_ + 1) * LG_};
    Gr.cum[0] = 0; Gr.cum[1] = SM_ / 16; Gr.cum[2] = SM_ / 16 + LG_ / 16;
    sg_wide<<<Gr.cum[2], 256, 0, stream>>>(Gr);
  }
}

// Round 16
// 531.465 us; speedup vs baseline: 6.6821x; 1.0525x over previous
//
#include <hip/hip_runtime.h>
#include <hip/hip_bf16.h>
#include <math.h>

#define B_     64
#define NSM_   400
#define NLG_   196
#define SM_    512
#define LG_    1024
#define H_     16
#define DH_    64
#define INNER_ 1024
#define SSTR   424    // S row stride (f32)
#define PSTR   424    // p LDS row stride (bf16)
#define NJMAX  7

typedef __attribute__((ext_vector_type(8))) short bf16x8;
typedef __attribute__((ext_vector_type(8))) unsigned short u16x8;
typedef __attribute__((ext_vector_type(4))) float f32x4;

__device__ __forceinline__ unsigned short f2b(float f) {
  unsigned u = __float_as_uint(f);
  u = u + 0x7FFFu + ((u >> 16) & 1u);   // RNE
  return (unsigned short)(u >> 16);
}
__device__ __forceinline__ f32x4 zero4() {
  f32x4 a; a[0] = 0.f; a[1] = 0.f; a[2] = 0.f; a[3] = 0.f; return a;
}
__device__ __forceinline__ bf16x8 ntl8(const unsigned short* p) {
  return __builtin_nontemporal_load((const bf16x8*)p);
}

// ============================ setup kernels ================================

// setup1 = all 10 weight transposes + token pass (nt copy)
struct CC2 { const float* tok; float* out; unsigned short* abf; float* cls;
             unsigned short* clsb; int Np1, nf4, shift, tot4; };
struct WTDesc { const float* src; unsigned short* dst; unsigned short* dst2; int K, N; };
struct WTArgs { WTDesc d[10]; int cum[11]; };
__global__ __launch_bounds__(256) void setup1(CC2 ca, CC2 cb, WTArgs W, int nw) {
  __shared__ unsigned short tile[64][68];   // 136B rows: 8B-aligned
  const int tid = threadIdx.x;
  if ((int)blockIdx.x < nw) {
    // ---- weight transpose: f32 (L,K,N) -> bf16 (L,N,K); wkv also straight (L,K,1024)
    int bx = blockIdx.x, di = 0;
    while (bx >= W.cum[di + 1]) di++;
    int local = bx - W.cum[di];
    WTDesc g = W.d[di];
    int tn = g.N >> 6;
    int tpl = tn * (g.K >> 6);
    int layer = local / tpl, rem = local % tpl;
    int kt = (rem / tn) * 64, nt = (rem % tn) * 64;
    const float* wp = g.src + (size_t)layer * g.K * g.N;
    unsigned short* op = g.dst + (size_t)layer * g.K * g.N;
    unsigned short* d2 = (g.dst2 && nt < 1024)
                             ? g.dst2 + (size_t)layer * g.K * 1024 : nullptr;
#pragma unroll
    for (int p = 0; p < 4; p++) {
      int r = (tid >> 4) + p * 16;
      int c = (tid & 15) * 4;
      const f32x4 v = __builtin_nontemporal_load(
          (const f32x4*)&wp[(size_t)(kt + r) * g.N + nt + c]);
      ushort4 w4;
      w4.x = f2b(v.x); w4.y = f2b(v.y); w4.z = f2b(v.z); w4.w = f2b(v.w);
      *(ushort4*)&tile[r][c] = w4;
      if (d2) *(ushort4*)&d2[(size_t)(kt + r) * 1024 + nt + c] = w4;
    }
    __syncthreads();
    // coalesced transpose-out: 4-lane cluster writes one contiguous 128B row chunk
    const int r2 = tid >> 2, cseg = tid & 3;
    u16x8 v0, v1;
#pragma unroll
    for (int i = 0; i < 8; i++) v0[i] = tile[cseg * 16 + i][r2];
#pragma unroll
    for (int i = 0; i < 8; i++) v1[i] = tile[cseg * 16 + 8 + i][r2];
    unsigned short* orow = &op[(size_t)(nt + r2) * g.K + kt + cseg * 16];
    *(u16x8*)&orow[0] = v0;
    *(u16x8*)&orow[8] = v1;
  } else {
    // ---- token pass: f32 copy to out (non-temporal), patches->bf16, cls -> f32+bf16
    const int nblk = gridDim.x - nw;
    const int total = ca.tot4 + cb.tot4;
    for (int i = ((int)blockIdx.x - nw) * 256 + tid; i < total; i += nblk * 256) {
      CC2 g; int idx;
      if (i < ca.tot4) { g = ca; idx = i; } else { g = cb; idx = i - ca.tot4; }
      int rowg = idx >> g.shift, t = idx & ((1 << g.shift) - 1);
      int bb = rowg / g.Np1, row = rowg - bb * g.Np1;
      const f32x4 v = __builtin_nontemporal_load(&((const f32x4*)g.tok)[idx]);
      __builtin_nontemporal_store(v, &((f32x4*)g.out)[idx]);
      ushort4 w2; w2.x = f2b(v.x); w2.y = f2b(v.y); w2.z = f2b(v.z); w2.w = f2b(v.w);
      if (row > 0) {
        ((ushort4*)g.abf)[(size_t)(bb * (g.Np1 - 1) + row - 1) * g.nf4 + t] = w2;
      } else {
        ((f32x4*)g.cls)[(size_t)bb * g.nf4 + t] = v;
        ((ushort4*)g.clsb)[(size_t)bb * g.nf4 + t] = w2;
      }
    }
  }
}

// setup2 = x^T transposes (depends on Abf), coalesced writes
struct TXArgs { const unsigned short* xbf; unsigned short* xT; int Nctx, dout, xstride, nx, ny, nblk; };
__global__ __launch_bounds__(256) void setup2(TXArgs ta, TXArgs tb) {
  __shared__ unsigned short tile[64][68];
  TXArgs g; int bx = blockIdx.x;
  if (bx < ta.nblk) { g = ta; } else { g = tb; bx -= ta.nblk; }
  int cx = bx % g.nx; int rem = bx / g.nx;
  int jy = rem % g.ny; int b = rem / g.ny;
  int jt = jy * 64, ct = cx * 64;
  const int tid = threadIdx.x;
#pragma unroll
  for (int p = 0; p < 4; p++) {
    int row = (tid >> 4) + p * 16;   // j-local
    int c = (tid & 15) * 4;          // dout-local
    int j = jt + row;
    ushort4 v;
    if (j < g.Nctx) v = *(const ushort4*)&g.xbf[((size_t)b * g.Nctx + j) * g.dout + ct + c];
    else { v.x = 0; v.y = 0; v.z = 0; v.w = 0; }
    *(ushort4*)&tile[row][c] = v;
  }
  __syncthreads();
  const int r2 = tid >> 2, jseg = tid & 3;
  if (jt + jseg * 16 < g.xstride) {
    u16x8 v0, v1;
#pragma unroll
    for (int i = 0; i < 8; i++) v0[i] = tile[jseg * 16 + i][r2];
#pragma unroll
    for (int i = 0; i < 8; i++) v1[i] = tile[jseg * 16 + 8 + i][r2];
    unsigned short* orow = &g.xT[((size_t)b * g.dout + ct + r2) * g.xstride + jt + jseg * 16];
    *(u16x8*)&orow[0] = v0;
    *(u16x8*)&orow[8] = v1;
  }
}

// ========== wide small GEMM: M=64, one 16-col tile per 256-thr block =======
// dual accumulators: even/odd K-subtiles independent -> half the dependent chain
struct SGDesc {
  const unsigned short* A; const unsigned short* WT; const float* bias;
  float* Cf; unsigned short* Cbf; const float* Rf;
  int K, N;
  float* outF; int ostride;
};
struct SGArgs { SGDesc d[4]; int cum[5]; int nd; };
__global__ __launch_bounds__(256) void sg_wide(SGArgs W) {
  int bx = blockIdx.x, di = 0;
  while (di < W.nd - 1 && bx >= W.cum[di + 1]) di++;
  SGDesc g = W.d[di];
  const int n0 = (bx - W.cum[di]) * 16;
  const int tid = threadIdx.x;
  const int lane = tid & 63, mt = tid >> 6;
  const int r16 = lane & 15, kv8 = (lane >> 4) * 8;
  f32x4 acc0 = zero4(), acc1 = zero4();
  const unsigned short* wp = &g.WT[(size_t)(n0 + r16) * g.K + kv8];
  const unsigned short* ap = &g.A[(size_t)(mt * 16 + r16) * g.K + kv8];
  const int K = g.K;
#pragma unroll 2
  for (int k0 = 0; k0 < K; k0 += 64) {
    acc0 = __builtin_amdgcn_mfma_f32_16x16x32_bf16(*(const bf16x8*)&ap[k0],
                                                   ntl8(&wp[k0]), acc0, 0, 0, 0);
    acc1 = __builtin_amdgcn_mfma_f32_16x16x32_bf16(*(const bf16x8*)&ap[k0 + 32],
                                                   ntl8(&wp[k0 + 32]), acc1, 0, 0, 0);
  }
  const int rbase = (lane >> 4) * 4;
#pragma unroll
  for (int rr = 0; rr < 4; rr++) {
    int r = mt * 16 + rbase + rr, c = n0 + r16;
    float v = acc0[rr] + acc1[rr];
    if (g.bias) v += g.bias[c];
    if (g.Rf) v += g.Rf[(size_t)r * g.N + c];
    if (g.Cf)  g.Cf[(size_t)r * g.N + c] = v;
    if (g.Cbf) g.Cbf[(size_t)r * g.N + c] = f2b(v);
    if (g.outF) g.outF[(size_t)r * g.ostride + c] = v;
  }
}

// =============================== layernorm =================================
struct LNArgs { const float* x; unsigned short* xnb; const float* ng; const float* nb; int dim; };
__global__ __launch_bounds__(256) void ln2(LNArgs la, LNArgs lb) {
  LNArgs g = ((int)blockIdx.x < 64) ? la : lb;
  int b = blockIdx.x & 63, t = threadIdx.x;
  __shared__ float rs[4], rq[4], bc[2];
  const float* xp = g.x + (size_t)b * g.dim;
  float s = 0.f, sq = 0.f;
  for (int c = t; c < g.dim; c += 256) {
    float v = xp[c];
    s += v; sq += v * v;
  }
#pragma unroll
  for (int off = 32; off >= 1; off >>= 1) {
    s += __shfl_down(s, off);
    sq += __shfl_down(sq, off);
  }
  int w = t >> 6;
  if ((t & 63) == 0) { rs[w] = s; rq[w] = sq; }
  __syncthreads();
  if (t == 0) {
    float ts = rs[0] + rs[1] + rs[2] + rs[3];
    float tq = rq[0] + rq[1] + rq[2] + rq[3];
    float mu = ts / g.dim;
    float var = tq / g.dim - mu * mu;
    bc[0] = mu; bc[1] = rsqrtf(var + 1e-5f);
  }
  __syncthreads();
  float mu = bc[0], r = bc[1];
  for (int c = t; c < g.dim; c += 256)
    g.xnb[(size_t)b * g.dim + c] = f2b((xp[c] - mu) * r * g.ng[c] + g.nb[c]);
}

// ==================== q~ via MFMA: q̃_bh = q_h(64x64) @ wkv_rows ============
struct QTArgs { const unsigned short* qb16; const unsigned short* wkvnb;
                unsigned short* qt; int dout, ntiles, nblk; };
__global__ __launch_bounds__(256) void qtilde3(QTArgs ga, QTArgs gb) {
  QTArgs g; int bx = blockIdx.x;
  if (bx < ga.nblk) g = ga; else { g = gb; bx -= ga.nblk; }
  const int h = bx / g.ntiles, nt = bx - h * g.ntiles;
  const int n0 = nt * 16;
  const int tid = threadIdx.x, lane = tid & 63, mt = tid >> 6;
  const int r16 = lane & 15, kv8 = (lane >> 4) * 8;
  const unsigned short* ap = g.qb16 + (size_t)(mt * 16 + r16) * INNER_ + h * 64 + kv8;
  const unsigned short* bp = g.wkvnb + (size_t)(n0 + r16) * 1024 + h * 64 + kv8;
  f32x4 acc0 = zero4(), acc1 = zero4();
  acc0 = __builtin_amdgcn_mfma_f32_16x16x32_bf16(*(const bf16x8*)&ap[0],
                                                 *(const bf16x8*)&bp[0], acc0, 0, 0, 0);
  acc1 = __builtin_amdgcn_mfma_f32_16x16x32_bf16(*(const bf16x8*)&ap[32],
                                                 *(const bf16x8*)&bp[32], acc1, 0, 0, 0);
  const int rbase = (lane >> 4) * 4;
#pragma unroll
  for (int rr = 0; rr < 4; rr++) {
    int b = mt * 16 + rbase + rr;
    g.qt[((size_t)b * 16 + h) * g.dout + n0 + r16] = f2b(acc0[rr] + acc1[rr]);
  }
}

// ================= S = q~ . x^T (4 j-tiles per 256-thr block) ==============
struct SArgs { const unsigned short* qt; const unsigned short* xbf; float* S;
               int dout, Nctx, ntj, nbj, nblk; };
__global__ __launch_bounds__(256) void s_gemm(SArgs ga, SArgs gb) {
  SArgs g; int bx;
  if ((int)blockIdx.x < ga.nblk) { g = ga; bx = blockIdx.x; }
  else { g = gb; bx = blockIdx.x - ga.nblk; }
  const int b = bx / g.nbj, jq = bx - b * g.nbj;
  const int tid = threadIdx.x, lane = tid & 63, w = tid >> 6;
  const int jt = jq * 4 + w;
  if (jt >= g.ntj) return;
  const int r16 = lane & 15, kv8 = (lane >> 4) * 8;
  const unsigned short* ap = g.qt + ((size_t)b * 16 + r16) * g.dout + kv8;
  const unsigned short* bp = g.xbf + ((size_t)b * g.Nctx + jt * 16 + r16) * g.dout + kv8;
  f32x4 acc0 = zero4(), acc1 = zero4();
  const int K = g.dout;
#pragma unroll 2
  for (int k0 = 0; k0 < K; k0 += 64) {
    acc0 = __builtin_amdgcn_mfma_f32_16x16x32_bf16(*(const bf16x8*)&ap[k0],
                                                   *(const bf16x8*)&bp[k0], acc0, 0, 0, 0);
    acc1 = __builtin_amdgcn_mfma_f32_16x16x32_bf16(*(const bf16x8*)&ap[k0 + 32],
                                                   *(const bf16x8*)&bp[k0 + 32], acc1, 0, 0, 0);
  }
  const int rbase = (lane >> 4) * 4;
#pragma unroll
  for (int rr = 0; rr < 4; rr++)
    g.S[((size_t)b * 16 + rbase + rr) * SSTR + jt * 16 + r16] = acc0[rr] + acc1[rr];
}

// ================= softmax (redundant per block) + u = p . x ===============
struct UArgs {
  const float* S; const float* qb; const float* kvc; const unsigned short* xT;
  unsigned short* u; float* pcls; int dout, Nctx, Npad, xstride, ntc, nblk;
};
__global__ __launch_bounds__(256) void usoftmax(UArgs ga, UArgs gb) {
  __shared__ unsigned short p_s[16 * PSTR];
  UArgs g; int bx;
  if ((int)blockIdx.x < ga.nblk) { g = ga; bx = blockIdx.x; }
  else { g = gb; bx = blockIdx.x - ga.nblk; }
  const int b = bx / g.ntc, ct = bx - b * g.ntc;
  const int t = threadIdx.x, lane = t & 63, w = t >> 6;
  for (int hh = 0; hh < 4; hh++) {
    const int h = w * 4 + hh;
    const float* Sp = g.S + ((size_t)b * 16 + h) * SSTR;
    float sc = g.qb[(size_t)b * 1024 + h * 64 + lane] * g.kvc[(size_t)b * 2048 + h * 64 + lane];
#pragma unroll
    for (int o = 32; o >= 1; o >>= 1) sc += __shfl_down(sc, o);
    sc = __shfl(sc, 0) * 0.125f;
    float sv[NJMAX];
    float mr = -1e30f;
#pragma unroll
    for (int ji = 0; ji < NJMAX; ji++) {
      int j = ji * 64 + lane;
      sv[ji] = (j < g.Nctx) ? Sp[j] * 0.125f : -1e30f;
      mr = fmaxf(mr, sv[ji]);
    }
#pragma unroll
    for (int o = 32; o >= 1; o >>= 1) mr = fmaxf(mr, __shfl_down(mr, o));
    mr = __shfl(mr, 0);
    const float m = fmaxf(mr, sc);
    float es = 0.f;
#pragma unroll
    for (int ji = 0; ji < NJMAX; ji++) {
      int j = ji * 64 + lane;
      float e = (j < g.Nctx) ? expf(sv[ji] - m) : 0.f;
      sv[ji] = e; es += e;
    }
#pragma unroll
    for (int o = 32; o >= 1; o >>= 1) es += __shfl_down(es, o);
    es = __shfl(es, 0);
    const float ecls = expf(sc - m);
    const float inv = 1.f / (es + ecls);
#pragma unroll
    for (int ji = 0; ji < NJMAX; ji++) {
      int j = ji * 64 + lane;
      if (j < g.Npad) p_s[h * PSTR + j] = (j < g.Nctx) ? f2b(sv[ji] * inv) : (unsigned short)0;
    }
    if (ct == 0 && lane == 0) g.pcls[b * 16 + h] = ecls * inv;
  }
  __syncthreads();
  const int r16 = lane & 15, kv8 = (lane >> 4) * 8, rbase = (lane >> 4) * 4;
  const int c0 = ct * 64 + w * 16;
  f32x4 acc0 = zero4(), acc1 = zero4();
  const unsigned short* bp = g.xT + ((size_t)b * g.dout + c0 + r16) * g.xstride + kv8;
  const unsigned short* apl = &p_s[r16 * PSTR + kv8];
  const int Kp = g.Npad;
  int k0 = 0;
  for (; k0 + 64 <= Kp; k0 += 64) {
    acc0 = __builtin_amdgcn_mfma_f32_16x16x32_bf16(*(const bf16x8*)&apl[k0],
                                                   *(const bf16x8*)&bp[k0], acc0, 0, 0, 0);
    acc1 = __builtin_amdgcn_mfma_f32_16x16x32_bf16(*(const bf16x8*)&apl[k0 + 32],
                                                   *(const bf16x8*)&bp[k0 + 32], acc1, 0, 0, 0);
  }
  if (k0 < Kp)
    acc0 = __builtin_amdgcn_mfma_f32_16x16x32_bf16(*(const bf16x8*)&apl[k0],
                                                   *(const bf16x8*)&bp[k0], acc0, 0, 0, 0);
#pragma unroll
  for (int rr = 0; rr < 4; rr++)
    g.u[((size_t)b * 16 + rbase + rr) * g.dout + c0 + r16] = f2b(acc0[rr] + acc1[rr]);
}

// ==================== o = u.Wv (+ cls term), 4 waves/block =================
struct OArgs {
  const unsigned short* u; const unsigned short* WTkv; const float* kvc; const float* pcls;
  unsigned short* ob; int dout;
};
__global__ __launch_bounds__(256) void ogemm_w(OArgs ga, OArgs gb) {
  OArgs g; int bx = blockIdx.x;
  if (bx < 64) { g = ga; } else { g = gb; bx -= 64; }
  const int h = bx >> 2, dt = bx & 3;
  const int tid = threadIdx.x, lane = tid & 63, mt = tid >> 6;
  const int r16 = lane & 15, kv8 = (lane >> 4) * 8;
  const int dout = g.dout;
  f32x4 acc0 = zero4(), acc1 = zero4();
  const unsigned short* wp = &g.WTkv[(size_t)(1024 + h * 64 + dt * 16 + r16) * dout + kv8];
  const unsigned short* up = &g.u[((size_t)(mt * 16 + r16) * 16 + h) * dout + kv8];
#pragma unroll 2
  for (int k0 = 0; k0 < dout; k0 += 64) {
    acc0 = __builtin_amdgcn_mfma_f32_16x16x32_bf16(*(const bf16x8*)&up[k0],
                                                   ntl8(&wp[k0]), acc0, 0, 0, 0);
    acc1 = __builtin_amdgcn_mfma_f32_16x16x32_bf16(*(const bf16x8*)&up[k0 + 32],
                                                   ntl8(&wp[k0 + 32]), acc1, 0, 0, 0);
  }
  const int rbase = (lane >> 4) * 4;
#pragma unroll
  for (int rr = 0; rr < 4; rr++) {
    int bi = mt * 16 + rbase + rr;
    int d = h * 64 + dt * 16 + r16;
    float v = acc0[rr] + acc1[rr] + g.pcls[bi * 16 + h] * g.kvc[(size_t)bi * 2048 + 1024 + d];
    g.ob[(size_t)bi * INNER_ + d] = f2b(v);
  }
}

// ================================ host =====================================
extern "C" void kernel_launch(void* const* d_in, const int* in_sizes, int n_in,
                              void* d_out, int out_size, void* d_ws, size_t ws_size,
                              hipStream_t stream) {
  const float* sm_tokens = (const float*)d_in[0];
  const float* lg_tokens = (const float*)d_in[1];
  const float* a_pin_w  = (const float*)d_in[2];  const float* a_pin_b  = (const float*)d_in[3];
  const float* a_ng     = (const float*)d_in[4];  const float* a_nb     = (const float*)d_in[5];
  const float* a_wq     = (const float*)d_in[6];  const float* a_wkv    = (const float*)d_in[7];
  const float* a_wo     = (const float*)d_in[8];  const float* a_wob    = (const float*)d_in[9];
  const float* a_pout_w = (const float*)d_in[10]; const float* a_pout_b = (const float*)d_in[11];
  const float* b_pin_w  = (const float*)d_in[12]; const float* b_pin_b  = (const float*)d_in[13];
  const float* b_ng     = (const float*)d_in[14]; const float* b_nb     = (const float*)d_in[15];
  const float* b_wq     = (const float*)d_in[16]; const float* b_wkv    = (const float*)d_in[17];
  const float* b_wo     = (const float*)d_in[18]; const float* b_wob    = (const float*)d_in[19];
  const float* b_pout_w = (const float*)d_in[20]; const float* b_pout_b = (const float*)d_in[21];

  float* out = (float*)d_out;
  char* ws = (char*)d_ws;
  size_t off = 0;
  auto alloc = [&](size_t bytes) -> void* {
    void* pt = ws + off;
    off += (bytes + 255) & ~(size_t)255;
    return pt;
  };
  unsigned short* Abf_lg = (unsigned short*)alloc(((size_t)B_ * NLG_ + 32) * LG_ * 2);
  unsigned short* Abf_sm = (unsigned short*)alloc(((size_t)B_ * NSM_ + 32) * SM_ * 2);
  unsigned short* xT_lg  = (unsigned short*)alloc((size_t)B_ * LG_ * 224 * 2);
  unsigned short* xT_sm  = (unsigned short*)alloc((size_t)B_ * SM_ * 416 * 2);
  unsigned short* WTkv_a = (unsigned short*)alloc((size_t)4 * 2048 * LG_ * 2);
  unsigned short* WTkv_b = (unsigned short*)alloc((size_t)4 * 2048 * SM_ * 2);
  unsigned short* wkvnb_a = (unsigned short*)alloc((size_t)4 * LG_ * 1024 * 2);
  unsigned short* wkvnb_b = (unsigned short*)alloc((size_t)4 * SM_ * 1024 * 2);
  unsigned short* WTpin_a = (unsigned short*)alloc((size_t)4 * SM_ * LG_ * 2);
  unsigned short* WTpin_b = (unsigned short*)alloc((size_t)4 * LG_ * SM_ * 2);
  unsigned short* WTwq_a  = (unsigned short*)alloc((size_t)4 * LG_ * INNER_ * 2);
  unsigned short* WTwq_b  = (unsigned short*)alloc((size_t)4 * SM_ * INNER_ * 2);
  unsigned short* WTwo_a  = (unsigned short*)alloc((size_t)4 * INNER_ * LG_ * 2);
  unsigned short* WTwo_b  = (unsigned short*)alloc((size_t)4 * INNER_ * SM_ * 2);
  unsigned short* WTpout_a = (unsigned short*)alloc((size_t)4 * LG_ * SM_ * 2);
  unsigned short* WTpout_b = (unsigned short*)alloc((size_t)4 * SM_ * LG_ * 2);
  unsigned short* qt_a = (unsigned short*)alloc((size_t)B_ * 16 * LG_ * 2);
  unsigned short* qt_b = (unsigned short*)alloc((size_t)B_ * 16 * SM_ * 2);
  float* S_a = (float*)alloc((size_t)B_ * 16 * SSTR * 4);
  float* S_b = (float*)alloc((size_t)B_ * 16 * SSTR * 4);
  unsigned short* u_a  = (unsigned short*)alloc((size_t)B_ * 16 * LG_ * 2);
  unsigned short* u_b  = (unsigned short*)alloc((size_t)B_ * 16 * SM_ * 2);
  float* pcls_a = (float*)alloc((size_t)B_ * 16 * 4);
  float* pcls_b = (float*)alloc((size_t)B_ * 16 * 4);
  float* cls_sm = (float*)alloc((size_t)B_ * SM_ * 4);
  float* cls_lg = (float*)alloc((size_t)B_ * LG_ * 4);
  unsigned short* clsb_sm = (unsigned short*)alloc((size_t)B_ * SM_ * 2);
  unsigned short* clsb_lg = (unsigned short*)alloc((size_t)B_ * LG_ * 2);
  float* xbuf_a = (float*)alloc((size_t)B_ * LG_ * 4);
  float* xbuf_b = (float*)alloc((size_t)B_ * SM_ * 4);
  unsigned short* xnb_a = (unsigned short*)alloc((size_t)B_ * LG_ * 2);
  unsigned short* xnb_b = (unsigned short*)alloc((size_t)B_ * SM_ * 2);
  float* qbuf_a = (float*)alloc((size_t)B_ * INNER_ * 4);
  float* qbuf_b = (float*)alloc((size_t)B_ * INNER_ * 4);
  unsigned short* qb16_a = (unsigned short*)alloc((size_t)B_ * INNER_ * 2);
  unsigned short* qb16_b = (unsigned short*)alloc((size_t)B_ * INNER_ * 2);
  float* kvc_a  = (float*)alloc((size_t)B_ * 2048 * 4);
  float* kvc_b  = (float*)alloc((size_t)B_ * 2048 * 4);
  unsigned short* obufb_a = (unsigned short*)alloc((size_t)B_ * INNER_ * 2);
  unsigned short* obufb_b = (unsigned short*)alloc((size_t)B_ * INNER_ * 2);
  unsigned short* t1b_a = (unsigned short*)alloc((size_t)B_ * LG_ * 2);
  unsigned short* t1b_b = (unsigned short*)alloc((size_t)B_ * SM_ * 2);
  (void)ws_size; (void)in_sizes; (void)n_in; (void)out_size;

  const size_t sm_elems = (size_t)B_ * (NSM_ + 1) * SM_;

  // ---- setup1: all weight transposes + token pass (one dispatch)
  CC2 ca{sm_tokens, out, Abf_sm, cls_sm, clsb_sm, NSM_ + 1, SM_ / 4, 7,
         (int)(sm_elems / 4)};
  CC2 cb{lg_tokens, out + sm_elems, Abf_lg, cls_lg, clsb_lg, NLG_ + 1, LG_ / 4, 8,
         (int)((size_t)B_ * (NLG_ + 1) * LG_ / 4)};
  WTArgs W;
  W.d[0] = {a_wkv,    WTkv_a,   wkvnb_a, LG_, 2048};
  W.d[1] = {b_wkv,    WTkv_b,   wkvnb_b, SM_, 2048};
  W.d[2] = {a_pin_w,  WTpin_a,  nullptr, SM_, LG_};
  W.d[3] = {b_pin_w,  WTpin_b,  nullptr, LG_, SM_};
  W.d[4] = {a_wq,     WTwq_a,   nullptr, LG_, INNER_};
  W.d[5] = {b_wq,     WTwq_b,   nullptr, SM_, INNER_};
  W.d[6] = {a_wo,     WTwo_a,   nullptr, INNER_, LG_};
  W.d[7] = {b_wo,     WTwo_b,   nullptr, INNER_, SM_};
  W.d[8] = {a_pout_w, WTpout_a, nullptr, LG_, SM_};
  W.d[9] = {b_pout_w, WTpout_b, nullptr, SM_, LG_};
  W.cum[0] = 0;
  for (int i = 0; i < 10; i++)
    W.cum[i + 1] = W.cum[i] + (W.d[i].K / 64) * (W.d[i].N / 64) * 4;
  setup1<<<W.cum[10] + 2048, 256, 0, stream>>>(ca, cb, W, W.cum[10]);
  // ---- setup2: x^T (needs Abf from setup1)
  TXArgs txa{Abf_lg, xT_lg, NLG_, LG_, 224, LG_ / 64, 4, B_ * (LG_ / 64) * 4};
  TXArgs txb{Abf_sm, xT_sm, NSM_, SM_, 416, SM_ / 64, 7, B_ * (SM_ / 64) * 7};
  setup2<<<txa.nblk + txb.nblk, 256, 0, stream>>>(txa, txb);

  for (int l = 0; l < 4; l++) {
    const unsigned short* WTpin_al = WTpin_a + (size_t)l * SM_ * LG_;
    const unsigned short* WTpin_bl = WTpin_b + (size_t)l * LG_ * SM_;
    const unsigned short* WTwq_al  = WTwq_a  + (size_t)l * LG_ * INNER_;
    const unsigned short* WTwq_bl  = WTwq_b  + (size_t)l * SM_ * INNER_;
    const unsigned short* WTkv_al  = WTkv_a  + (size_t)l * 2048 * LG_;
    const unsigned short* WTkv_bl  = WTkv_b  + (size_t)l * 2048 * SM_;
    const unsigned short* wkvnb_al = wkvnb_a + (size_t)l * LG_ * 1024;
    const unsigned short* wkvnb_bl = wkvnb_b + (size_t)l * SM_ * 1024;
    const unsigned short* WTwo_al  = WTwo_a  + (size_t)l * INNER_ * LG_;
    const unsigned short* WTwo_bl  = WTwo_b  + (size_t)l * INNER_ * SM_;
    const unsigned short* WTpout_al = WTpout_a + (size_t)l * LG_ * SM_;
    const unsigned short* WTpout_bl = WTpout_b + (size_t)l * SM_ * LG_;

    // pin
    SGArgs Gp; Gp.nd = 2;
    Gp.d[0] = {clsb_sm, WTpin_al, a_pin_b + (size_t)l * LG_, xbuf_a, nullptr, nullptr, SM_, LG_, nullptr, 0};
    Gp.d[1] = {clsb_lg, WTpin_bl, b_pin_b + (size_t)l * SM_, xbuf_b, nullptr, nullptr, LG_, SM_, nullptr, 0};
    Gp.cum[0] = 0; Gp.cum[1] = LG_ / 16; Gp.cum[2] = LG_ / 16 + SM_ / 16;
    sg_wide<<<Gp.cum[2], 256, 0, stream>>>(Gp);
    // ln
    LNArgs la{xbuf_a, xnb_a, a_ng + (size_t)l * LG_, a_nb + (size_t)l * LG_, LG_};
    LNArgs lb{xbuf_b, xnb_b, b_ng + (size_t)l * SM_, b_nb + (size_t)l * SM_, SM_};
    ln2<<<128, 256, 0, stream>>>(la, lb);
    // q (f32 + bf16 mirror) + kv (cls)
    SGArgs Gq; Gq.nd = 4;
    Gq.d[0] = {xnb_a, WTwq_al, nullptr, qbuf_a, qb16_a, nullptr, LG_, INNER_, nullptr, 0};
    Gq.d[1] = {xnb_a, WTkv_al, nullptr, kvc_a,  nullptr, nullptr, LG_, 2048, nullptr, 0};
    Gq.d[2] = {xnb_b, WTwq_bl, nullptr, qbuf_b, qb16_b, nullptr, SM_, INNER_, nullptr, 0};
    Gq.d[3] = {xnb_b, WTkv_bl, nullptr, kvc_b,  nullptr, nullptr, SM_, 2048, nullptr, 0};
    Gq.cum[0] = 0; Gq.cum[1] = 64; Gq.cum[2] = 192; Gq.cum[3] = 256; Gq.cum[4] = 384;
    sg_wide<<<384, 256, 0, stream>>>(Gq);
    // q~ (MFMA over bf16 straight wkv)
    QTArgs qa{qb16_a, wkvnb_al, qt_a, LG_, LG_ / 16, 16 * (LG_ / 16)};
    QTArgs qb{qb16_b, wkvnb_bl, qt_b, SM_, SM_ / 16, 16 * (SM_ / 16)};
    qtilde3<<<qa.nblk + qb.nblk, 256, 0, stream>>>(qa, qb);
    // S = q~ . x^T
    SArgs sa{qt_a, Abf_lg, S_a, LG_, NLG_, 14, 4, B_ * 4};
    SArgs sb{qt_b, Abf_sm, S_b, SM_, NSM_, 26, 7, B_ * 7};
    s_gemm<<<sa.nblk + sb.nblk, 256, 0, stream>>>(sa, sb);
    // softmax (in-LDS, redundant per block) + u = p . x
    UArgs ua{S_a, qbuf_a, kvc_a, xT_lg, u_a, pcls_a, LG_, NLG_, 224, 224, LG_ / 64, B_ * (LG_ / 64)};
    UArgs ub{S_b, qbuf_b, kvc_b, xT_sm, u_b, pcls_b, SM_, NSM_, 416, 416, SM_ / 64, B_ * (SM_ / 64)};
    usoftmax<<<ua.nblk + ub.nblk, 256, 0, stream>>>(ua, ub);
    // o = u . Wv + pcls * v_cls
    OArgs oa{u_a, WTkv_al, kvc_a, pcls_a, obufb_a, LG_};
    OArgs ob{u_b, WTkv_bl, kvc_b, pcls_b, obufb_b, SM_};
    ogemm_w<<<128, 256, 0, stream>>>(oa, ob);
    // wo
    SGArgs Gw; Gw.nd = 2;
    Gw.d[0] = {obufb_a, WTwo_al, a_wob + (size_t)l * LG_, nullptr, t1b_a, nullptr, INNER_, LG_, nullptr, 0};
    Gw.d[1] = {obufb_b, WTwo_bl, b_wob + (size_t)l * SM_, nullptr, t1b_b, nullptr, INNER_, SM_, nullptr, 0};
    Gw.cum[0] = 0; Gw.cum[1] = LG_ / 16; Gw.cum[2] = LG_ / 16 + SM_ / 16;
    sg_wide<<<Gw.cum[2], 256, 0, stream>>>(Gw);
    // pout + residual; on the last layer also write cls rows straight to out
    float* outF_a = (l == 3) ? out : nullptr;
    float* outF_b = (l == 3) ? out + sm_elems : nullptr;
    SGArgs Gr; Gr.nd = 2;
    Gr.d[0] = {t1b_a, WTpout_al, a_pout_b + (size_t)l * SM_, cls_sm, clsb_sm, cls_sm, LG_, SM_,
               outF_a, (NSM_ + 1) * SM_};
    Gr.d[1] = {t1b_b, WTpout_bl, b_pout_b + (size_t)l * LG_, cls_lg, clsb_lg, cls_lg, SM_, LG_,
               outF_b, (NLG_ + 1) * LG_};
    Gr.cum[0] = 0; Gr.cum[1] = SM_ / 16; Gr.cum[2] = SM_ / 16 + LG_ / 16;
    sg_wide<<<Gr.cum[2], 256, 0, stream>>>(Gr);
  }
}

// Round 17
// 494.701 us; speedup vs baseline: 7.1787x; 1.0743x over previous
//
#include <hip/hip_runtime.h>
#include <hip/hip_bf16.h>
#include <math.h>

#define B_     64
#define NSM_   400
#define NLG_   196
#define SM_    512
#define LG_    1024
#define H_     16
#define DH_    64
#define INNER_ 1024
#define SSTR   424    // S row stride (f32)
#define PSTR   424    // p row stride (bf16, global)

typedef __attribute__((ext_vector_type(8))) short bf16x8;
typedef __attribute__((ext_vector_type(8))) unsigned short u16x8;
typedef __attribute__((ext_vector_type(4))) float f32x4;

__device__ __forceinline__ unsigned short f2b(float f) {
  unsigned u = __float_as_uint(f);
  u = u + 0x7FFFu + ((u >> 16) & 1u);   // RNE
  return (unsigned short)(u >> 16);
}
__device__ __forceinline__ f32x4 zero4() {
  f32x4 a; a[0] = 0.f; a[1] = 0.f; a[2] = 0.f; a[3] = 0.f; return a;
}

// ============================ setup kernels ================================

// setup1 = all 10 weight transposes + token pass (nt copy)
struct CC2 { const float* tok; float* out; unsigned short* abf; float* cls;
             unsigned short* clsb; int Np1, nf4, shift, tot4; };
struct WTDesc { const float* src; unsigned short* dst; unsigned short* dst2; int K, N; };
struct WTArgs { WTDesc d[10]; int cum[11]; };
__global__ __launch_bounds__(256) void setup1(CC2 ca, CC2 cb, WTArgs W, int nw) {
  __shared__ unsigned short tile[64][68];   // 136B rows: 8B-aligned
  const int tid = threadIdx.x;
  if ((int)blockIdx.x < nw) {
    // ---- weight transpose: f32 (L,K,N) -> bf16 (L,N,K); wkv also straight (L,K,1024)
    int bx = blockIdx.x, di = 0;
    while (bx >= W.cum[di + 1]) di++;
    int local = bx - W.cum[di];
    WTDesc g = W.d[di];
    int tn = g.N >> 6;
    int tpl = tn * (g.K >> 6);
    int layer = local / tpl, rem = local % tpl;
    int kt = (rem / tn) * 64, nt = (rem % tn) * 64;
    const float* wp = g.src + (size_t)layer * g.K * g.N;
    unsigned short* op = g.dst + (size_t)layer * g.K * g.N;
    unsigned short* d2 = (g.dst2 && nt < 1024)
                             ? g.dst2 + (size_t)layer * g.K * 1024 : nullptr;
#pragma unroll
    for (int p = 0; p < 4; p++) {
      int r = (tid >> 4) + p * 16;
      int c = (tid & 15) * 4;
      const f32x4 v = __builtin_nontemporal_load(
          (const f32x4*)&wp[(size_t)(kt + r) * g.N + nt + c]);
      ushort4 w4;
      w4.x = f2b(v.x); w4.y = f2b(v.y); w4.z = f2b(v.z); w4.w = f2b(v.w);
      *(ushort4*)&tile[r][c] = w4;
      if (d2) *(ushort4*)&d2[(size_t)(kt + r) * 1024 + nt + c] = w4;
    }
    __syncthreads();
    // coalesced transpose-out: 4-lane cluster writes one contiguous 128B row chunk
    const int r2 = tid >> 2, cseg = tid & 3;
    u16x8 v0, v1;
#pragma unroll
    for (int i = 0; i < 8; i++) v0[i] = tile[cseg * 16 + i][r2];
#pragma unroll
    for (int i = 0; i < 8; i++) v1[i] = tile[cseg * 16 + 8 + i][r2];
    unsigned short* orow = &op[(size_t)(nt + r2) * g.K + kt + cseg * 16];
    *(u16x8*)&orow[0] = v0;
    *(u16x8*)&orow[8] = v1;
  } else {
    // ---- token pass: f32 copy to out (non-temporal), patches->bf16, cls -> f32+bf16
    const int nblk = gridDim.x - nw;
    const int total = ca.tot4 + cb.tot4;
    for (int i = ((int)blockIdx.x - nw) * 256 + tid; i < total; i += nblk * 256) {
      CC2 g; int idx;
      if (i < ca.tot4) { g = ca; idx = i; } else { g = cb; idx = i - ca.tot4; }
      int rowg = idx >> g.shift, t = idx & ((1 << g.shift) - 1);
      int bb = rowg / g.Np1, row = rowg - bb * g.Np1;
      const f32x4 v = __builtin_nontemporal_load(&((const f32x4*)g.tok)[idx]);
      __builtin_nontemporal_store(v, &((f32x4*)g.out)[idx]);
      ushort4 w2; w2.x = f2b(v.x); w2.y = f2b(v.y); w2.z = f2b(v.z); w2.w = f2b(v.w);
      if (row > 0) {
        ((ushort4*)g.abf)[(size_t)(bb * (g.Np1 - 1) + row - 1) * g.nf4 + t] = w2;
      } else {
        ((f32x4*)g.cls)[(size_t)bb * g.nf4 + t] = v;
        ((ushort4*)g.clsb)[(size_t)bb * g.nf4 + t] = w2;
      }
    }
  }
}

// setup2 = x^T transposes (depends on Abf), coalesced writes
struct TXArgs { const unsigned short* xbf; unsigned short* xT; int Nctx, dout, xstride, nx, ny, nblk; };
__global__ __launch_bounds__(256) void setup2(TXArgs ta, TXArgs tb) {
  __shared__ unsigned short tile[64][68];
  TXArgs g; int bx = blockIdx.x;
  if (bx < ta.nblk) { g = ta; } else { g = tb; bx -= ta.nblk; }
  int cx = bx % g.nx; int rem = bx / g.nx;
  int jy = rem % g.ny; int b = rem / g.ny;
  int jt = jy * 64, ct = cx * 64;
  const int tid = threadIdx.x;
#pragma unroll
  for (int p = 0; p < 4; p++) {
    int row = (tid >> 4) + p * 16;   // j-local
    int c = (tid & 15) * 4;          // dout-local
    int j = jt + row;
    ushort4 v;
    if (j < g.Nctx) v = *(const ushort4*)&g.xbf[((size_t)b * g.Nctx + j) * g.dout + ct + c];
    else { v.x = 0; v.y = 0; v.z = 0; v.w = 0; }
    *(ushort4*)&tile[row][c] = v;
  }
  __syncthreads();
  const int r2 = tid >> 2, jseg = tid & 3;
  if (jt + jseg * 16 < g.xstride) {
    u16x8 v0, v1;
#pragma unroll
    for (int i = 0; i < 8; i++) v0[i] = tile[jseg * 16 + i][r2];
#pragma unroll
    for (int i = 0; i < 8; i++) v1[i] = tile[jseg * 16 + 8 + i][r2];
    unsigned short* orow = &g.xT[((size_t)b * g.dout + ct + r2) * g.xstride + jt + jseg * 16];
    *(u16x8*)&orow[0] = v0;
    *(u16x8*)&orow[8] = v1;
  }
}

// ========== wide small GEMM: M=64, one 16-col tile per 256-thr block =======
struct SGDesc {
  const unsigned short* A; const unsigned short* WT; const float* bias;
  float* Cf; unsigned short* Cbf; const float* Rf;
  int K, N;
  float* outF; int ostride;
};
struct SGArgs { SGDesc d[4]; int cum[5]; int nd; };
__global__ __launch_bounds__(256) void sg_wide(SGArgs W) {
  int bx = blockIdx.x, di = 0;
  while (di < W.nd - 1 && bx >= W.cum[di + 1]) di++;
  SGDesc g = W.d[di];
  const int n0 = (bx - W.cum[di]) * 16;
  const int tid = threadIdx.x;
  const int lane = tid & 63, mt = tid >> 6;
  const int r16 = lane & 15, kv8 = (lane >> 4) * 8;
  f32x4 acc0 = zero4(), acc1 = zero4();
  const unsigned short* wp = &g.WT[(size_t)(n0 + r16) * g.K + kv8];
  const unsigned short* ap = &g.A[(size_t)(mt * 16 + r16) * g.K + kv8];
  const int K = g.K;
#pragma unroll 2
  for (int k0 = 0; k0 < K; k0 += 64) {
    acc0 = __builtin_amdgcn_mfma_f32_16x16x32_bf16(*(const bf16x8*)&ap[k0],
                                                   *(const bf16x8*)&wp[k0], acc0, 0, 0, 0);
    acc1 = __builtin_amdgcn_mfma_f32_16x16x32_bf16(*(const bf16x8*)&ap[k0 + 32],
                                                   *(const bf16x8*)&wp[k0 + 32], acc1, 0, 0, 0);
  }
  const int rbase = (lane >> 4) * 4;
#pragma unroll
  for (int rr = 0; rr < 4; rr++) {
    int r = mt * 16 + rbase + rr, c = n0 + r16;
    float v = acc0[rr] + acc1[rr];
    if (g.bias) v += g.bias[c];
    if (g.Rf) v += g.Rf[(size_t)r * g.N + c];
    if (g.Cf)  g.Cf[(size_t)r * g.N + c] = v;
    if (g.Cbf) g.Cbf[(size_t)r * g.N + c] = f2b(v);
    if (g.outF) g.outF[(size_t)r * g.ostride + c] = v;
  }
}

// =============================== layernorm =================================
struct LNArgs { const float* x; unsigned short* xnb; const float* ng; const float* nb; int dim; };
__global__ __launch_bounds__(256) void ln2(LNArgs la, LNArgs lb) {
  LNArgs g = ((int)blockIdx.x < 64) ? la : lb;
  int b = blockIdx.x & 63, t = threadIdx.x;
  __shared__ float rs[4], rq[4], bc[2];
  const float* xp = g.x + (size_t)b * g.dim;
  float s = 0.f, sq = 0.f;
  for (int c = t; c < g.dim; c += 256) {
    float v = xp[c];
    s += v; sq += v * v;
  }
#pragma unroll
  for (int off = 32; off >= 1; off >>= 1) {
    s += __shfl_down(s, off);
    sq += __shfl_down(sq, off);
  }
  int w = t >> 6;
  if ((t & 63) == 0) { rs[w] = s; rq[w] = sq; }
  __syncthreads();
  if (t == 0) {
    float ts = rs[0] + rs[1] + rs[2] + rs[3];
    float tq = rq[0] + rq[1] + rq[2] + rq[3];
    float mu = ts / g.dim;
    float var = tq / g.dim - mu * mu;
    bc[0] = mu; bc[1] = rsqrtf(var + 1e-5f);
  }
  __syncthreads();
  float mu = bc[0], r = bc[1];
  for (int c = t; c < g.dim; c += 256)
    g.xnb[(size_t)b * g.dim + c] = f2b((xp[c] - mu) * r * g.ng[c] + g.nb[c]);
}

// ==================== q~ via MFMA: q̃_bh = q_h(64x64) @ wkv_rows ============
struct QTArgs { const unsigned short* qb16; const unsigned short* wkvnb;
                unsigned short* qt; int dout, ntiles, nblk; };
__global__ __launch_bounds__(256) void qtilde3(QTArgs ga, QTArgs gb) {
  QTArgs g; int bx = blockIdx.x;
  if (bx < ga.nblk) g = ga; else { g = gb; bx -= ga.nblk; }
  const int h = bx / g.ntiles, nt = bx - h * g.ntiles;
  const int n0 = nt * 16;
  const int tid = threadIdx.x, lane = tid & 63, mt = tid >> 6;
  const int r16 = lane & 15, kv8 = (lane >> 4) * 8;
  const unsigned short* ap = g.qb16 + (size_t)(mt * 16 + r16) * INNER_ + h * 64 + kv8;
  const unsigned short* bp = g.wkvnb + (size_t)(n0 + r16) * 1024 + h * 64 + kv8;
  f32x4 acc0 = zero4(), acc1 = zero4();
  acc0 = __builtin_amdgcn_mfma_f32_16x16x32_bf16(*(const bf16x8*)&ap[0],
                                                 *(const bf16x8*)&bp[0], acc0, 0, 0, 0);
  acc1 = __builtin_amdgcn_mfma_f32_16x16x32_bf16(*(const bf16x8*)&ap[32],
                                                 *(const bf16x8*)&bp[32], acc1, 0, 0, 0);
  const int rbase = (lane >> 4) * 4;
#pragma unroll
  for (int rr = 0; rr < 4; rr++) {
    int b = mt * 16 + rbase + rr;
    g.qt[((size_t)b * 16 + h) * g.dout + n0 + r16] = f2b(acc0[rr] + acc1[rr]);
  }
}

// ================= S = q~ . x^T (4 j-tiles per 256-thr block) ==============
struct SArgs { const unsigned short* qt; const unsigned short* xbf; float* S;
               int dout, Nctx, ntj, nbj, nblk; };
__global__ __launch_bounds__(256) void s_gemm(SArgs ga, SArgs gb) {
  SArgs g; int bx;
  if ((int)blockIdx.x < ga.nblk) { g = ga; bx = blockIdx.x; }
  else { g = gb; bx = blockIdx.x - ga.nblk; }
  const int b = bx / g.nbj, jq = bx - b * g.nbj;
  const int tid = threadIdx.x, lane = tid & 63, w = tid >> 6;
  const int jt = jq * 4 + w;
  if (jt >= g.ntj) return;
  const int r16 = lane & 15, kv8 = (lane >> 4) * 8;
  const unsigned short* ap = g.qt + ((size_t)b * 16 + r16) * g.dout + kv8;
  const unsigned short* bp = g.xbf + ((size_t)b * g.Nctx + jt * 16 + r16) * g.dout + kv8;
  f32x4 acc0 = zero4(), acc1 = zero4();
  const int K = g.dout;
#pragma unroll 2
  for (int k0 = 0; k0 < K; k0 += 64) {
    acc0 = __builtin_amdgcn_mfma_f32_16x16x32_bf16(*(const bf16x8*)&ap[k0],
                                                   *(const bf16x8*)&bp[k0], acc0, 0, 0, 0);
    acc1 = __builtin_amdgcn_mfma_f32_16x16x32_bf16(*(const bf16x8*)&ap[k0 + 32],
                                                   *(const bf16x8*)&bp[k0 + 32], acc1, 0, 0, 0);
  }
  const int rbase = (lane >> 4) * 4;
#pragma unroll
  for (int rr = 0; rr < 4; rr++)
    g.S[((size_t)b * 16 + rbase + rr) * SSTR + jt * 16 + r16] = acc0[rr] + acc1[rr];
}

// ============================ softmax -> p (once per (b,h)) ================
struct SMArgs { const float* S; const float* qb; const float* kvc;
                unsigned short* p; float* pcls; int Nctx, Npad; };
__global__ __launch_bounds__(256) void softmax_p2(SMArgs ga, SMArgs gb) {
  SMArgs g = blockIdx.z ? gb : ga;
  const int h = blockIdx.x, b = blockIdx.y;
  const int t = threadIdx.x;
  __shared__ float red[4], bc;
  float sc = 0.f;
  if (t < 64) sc = g.qb[(size_t)b * INNER_ + h * 64 + t] * g.kvc[(size_t)b * 2048 + h * 64 + t];
#pragma unroll
  for (int o = 32; o >= 1; o >>= 1) sc += __shfl_down(sc, o);
  if (t == 0) bc = sc * 0.125f;
  __syncthreads();
  const float scls = bc;
  const float* Sp = g.S + ((size_t)b * 16 + h) * SSTR;

  float sraw[2] = {-1e30f, -1e30f};
#pragma unroll
  for (int u2 = 0; u2 < 2; u2++) {
    int j = t + u2 * 256;
    if (j < g.Nctx) sraw[u2] = Sp[j] * 0.125f;
  }
  float mx = fmaxf(fmaxf(sraw[0], sraw[1]), scls);
#pragma unroll
  for (int o = 32; o >= 1; o >>= 1) mx = fmaxf(mx, __shfl_down(mx, o));
  if ((t & 63) == 0) red[t >> 6] = mx;
  __syncthreads();
  mx = fmaxf(fmaxf(red[0], red[1]), fmaxf(red[2], red[3]));
  __syncthreads();

  float e0 = (t < g.Nctx) ? expf(sraw[0] - mx) : 0.f;
  float e1 = (t + 256 < g.Nctx) ? expf(sraw[1] - mx) : 0.f;
  float ecls = expf(scls - mx);
  float ls = e0 + e1;
#pragma unroll
  for (int o = 32; o >= 1; o >>= 1) ls += __shfl_down(ls, o);
  if ((t & 63) == 0) red[t >> 6] = ls;
  __syncthreads();
  const float denom = red[0] + red[1] + red[2] + red[3] + ecls;
  const float inv = 1.f / denom;

  unsigned short* pp = g.p + ((size_t)b * 16 + h) * PSTR;
  if (t < g.Nctx) pp[t] = f2b(e0 * inv);
  if (t + 256 < g.Nctx) pp[t + 256] = f2b(e1 * inv);
  for (int j = g.Nctx + t; j < g.Npad; j += 256) pp[j] = 0;
  if (t == 0) g.pcls[b * 16 + h] = ecls * inv;
}

// ============================ u = p . x (dual-acc) =========================
struct UG { const unsigned short* p; const unsigned short* xT; unsigned short* u;
            int dout, Npad, xstride, ntx; };
__global__ __launch_bounds__(256) void ugemm2(UG ga, UG gb) {
  UG g; int bx = blockIdx.x;
  if (bx < ga.ntx) g = ga; else { g = gb; bx -= ga.ntx; }
  const int b = blockIdx.y;
  const int tid = threadIdx.x, lane = tid & 63, w = tid >> 6;
  const int c0 = bx * 64 + w * 16;
  const int r16 = lane & 15, kv8 = (lane >> 4) * 8, rbase = (lane >> 4) * 4;
  const unsigned short* ap = g.p + ((size_t)b * 16 + r16) * PSTR + kv8;
  const unsigned short* bp = g.xT + ((size_t)b * g.dout + c0 + r16) * g.xstride + kv8;
  f32x4 acc0 = zero4(), acc1 = zero4();
  const int Kp = g.Npad;
  int k0 = 0;
  for (; k0 + 64 <= Kp; k0 += 64) {
    acc0 = __builtin_amdgcn_mfma_f32_16x16x32_bf16(*(const bf16x8*)&ap[k0],
                                                   *(const bf16x8*)&bp[k0], acc0, 0, 0, 0);
    acc1 = __builtin_amdgcn_mfma_f32_16x16x32_bf16(*(const bf16x8*)&ap[k0 + 32],
                                                   *(const bf16x8*)&bp[k0 + 32], acc1, 0, 0, 0);
  }
  if (k0 < Kp)
    acc0 = __builtin_amdgcn_mfma_f32_16x16x32_bf16(*(const bf16x8*)&ap[k0],
                                                   *(const bf16x8*)&bp[k0], acc0, 0, 0, 0);
#pragma unroll
  for (int rr = 0; rr < 4; rr++)
    g.u[((size_t)b * 16 + rbase + rr) * g.dout + c0 + r16] = f2b(acc0[rr] + acc1[rr]);
}

// ==================== o = u.Wv (+ cls term), 4 waves/block =================
struct OArgs {
  const unsigned short* u; const unsigned short* WTkv; const float* kvc; const float* pcls;
  unsigned short* ob; int dout;
};
__global__ __launch_bounds__(256) void ogemm_w(OArgs ga, OArgs gb) {
  OArgs g; int bx = blockIdx.x;
  if (bx < 64) { g = ga; } else { g = gb; bx -= 64; }
  const int h = bx >> 2, dt = bx & 3;
  const int tid = threadIdx.x, lane = tid & 63, mt = tid >> 6;
  const int r16 = lane & 15, kv8 = (lane >> 4) * 8;
  const int dout = g.dout;
  f32x4 acc0 = zero4(), acc1 = zero4();
  const unsigned short* wp = &g.WTkv[(size_t)(1024 + h * 64 + dt * 16 + r16) * dout + kv8];
  const unsigned short* up = &g.u[((size_t)(mt * 16 + r16) * 16 + h) * dout + kv8];
#pragma unroll 2
  for (int k0 = 0; k0 < dout; k0 += 64) {
    acc0 = __builtin_amdgcn_mfma_f32_16x16x32_bf16(*(const bf16x8*)&up[k0],
                                                   *(const bf16x8*)&wp[k0], acc0, 0, 0, 0);
    acc1 = __builtin_amdgcn_mfma_f32_16x16x32_bf16(*(const bf16x8*)&up[k0 + 32],
                                                   *(const bf16x8*)&wp[k0 + 32], acc1, 0, 0, 0);
  }
  const int rbase = (lane >> 4) * 4;
#pragma unroll
  for (int rr = 0; rr < 4; rr++) {
    int bi = mt * 16 + rbase + rr;
    int d = h * 64 + dt * 16 + r16;
    float v = acc0[rr] + acc1[rr] + g.pcls[bi * 16 + h] * g.kvc[(size_t)bi * 2048 + 1024 + d];
    g.ob[(size_t)bi * INNER_ + d] = f2b(v);
  }
}

// ================================ host =====================================
extern "C" void kernel_launch(void* const* d_in, const int* in_sizes, int n_in,
                              void* d_out, int out_size, void* d_ws, size_t ws_size,
                              hipStream_t stream) {
  const float* sm_tokens = (const float*)d_in[0];
  const float* lg_tokens = (const float*)d_in[1];
  const float* a_pin_w  = (const float*)d_in[2];  const float* a_pin_b  = (const float*)d_in[3];
  const float* a_ng     = (const float*)d_in[4];  const float* a_nb     = (const float*)d_in[5];
  const float* a_wq     = (const float*)d_in[6];  const float* a_wkv    = (const float*)d_in[7];
  const float* a_wo     = (const float*)d_in[8];  const float* a_wob    = (const float*)d_in[9];
  const float* a_pout_w = (const float*)d_in[10]; const float* a_pout_b = (const float*)d_in[11];
  const float* b_pin_w  = (const float*)d_in[12]; const float* b_pin_b  = (const float*)d_in[13];
  const float* b_ng     = (const float*)d_in[14]; const float* b_nb     = (const float*)d_in[15];
  const float* b_wq     = (const float*)d_in[16]; const float* b_wkv    = (const float*)d_in[17];
  const float* b_wo     = (const float*)d_in[18]; const float* b_wob    = (const float*)d_in[19];
  const float* b_pout_w = (const float*)d_in[20]; const float* b_pout_b = (const float*)d_in[21];

  float* out = (float*)d_out;
  char* ws = (char*)d_ws;
  size_t off = 0;
  auto alloc = [&](size_t bytes) -> void* {
    void* pt = ws + off;
    off += (bytes + 255) & ~(size_t)255;
    return pt;
  };
  unsigned short* Abf_lg = (unsigned short*)alloc(((size_t)B_ * NLG_ + 32) * LG_ * 2);
  unsigned short* Abf_sm = (unsigned short*)alloc(((size_t)B_ * NSM_ + 32) * SM_ * 2);
  unsigned short* xT_lg  = (unsigned short*)alloc((size_t)B_ * LG_ * 224 * 2);
  unsigned short* xT_sm  = (unsigned short*)alloc((size_t)B_ * SM_ * 416 * 2);
  unsigned short* WTkv_a = (unsigned short*)alloc((size_t)4 * 2048 * LG_ * 2);
  unsigned short* WTkv_b = (unsigned short*)alloc((size_t)4 * 2048 * SM_ * 2);
  unsigned short* wkvnb_a = (unsigned short*)alloc((size_t)4 * LG_ * 1024 * 2);
  unsigned short* wkvnb_b = (unsigned short*)alloc((size_t)4 * SM_ * 1024 * 2);
  unsigned short* WTpin_a = (unsigned short*)alloc((size_t)4 * SM_ * LG_ * 2);
  unsigned short* WTpin_b = (unsigned short*)alloc((size_t)4 * LG_ * SM_ * 2);
  unsigned short* WTwq_a  = (unsigned short*)alloc((size_t)4 * LG_ * INNER_ * 2);
  unsigned short* WTwq_b  = (unsigned short*)alloc((size_t)4 * SM_ * INNER_ * 2);
  unsigned short* WTwo_a  = (unsigned short*)alloc((size_t)4 * INNER_ * LG_ * 2);
  unsigned short* WTwo_b  = (unsigned short*)alloc((size_t)4 * INNER_ * SM_ * 2);
  unsigned short* WTpout_a = (unsigned short*)alloc((size_t)4 * LG_ * SM_ * 2);
  unsigned short* WTpout_b = (unsigned short*)alloc((size_t)4 * SM_ * LG_ * 2);
  unsigned short* qt_a = (unsigned short*)alloc((size_t)B_ * 16 * LG_ * 2);
  unsigned short* qt_b = (unsigned short*)alloc((size_t)B_ * 16 * SM_ * 2);
  float* S_a = (float*)alloc((size_t)B_ * 16 * SSTR * 4);
  float* S_b = (float*)alloc((size_t)B_ * 16 * SSTR * 4);
  unsigned short* p_a = (unsigned short*)alloc((size_t)B_ * 16 * PSTR * 2);
  unsigned short* p_b = (unsigned short*)alloc((size_t)B_ * 16 * PSTR * 2);
  unsigned short* u_a  = (unsigned short*)alloc((size_t)B_ * 16 * LG_ * 2);
  unsigned short* u_b  = (unsigned short*)alloc((size_t)B_ * 16 * SM_ * 2);
  float* pcls_a = (float*)alloc((size_t)B_ * 16 * 4);
  float* pcls_b = (float*)alloc((size_t)B_ * 16 * 4);
  float* cls_sm = (float*)alloc((size_t)B_ * SM_ * 4);
  float* cls_lg = (float*)alloc((size_t)B_ * LG_ * 4);
  unsigned short* clsb_sm = (unsigned short*)alloc((size_t)B_ * SM_ * 2);
  unsigned short* clsb_lg = (unsigned short*)alloc((size_t)B_ * LG_ * 2);
  float* xbuf_a = (float*)alloc((size_t)B_ * LG_ * 4);
  float* xbuf_b = (float*)alloc((size_t)B_ * SM_ * 4);
  unsigned short* xnb_a = (unsigned short*)alloc((size_t)B_ * LG_ * 2);
  unsigned short* xnb_b = (unsigned short*)alloc((size_t)B_ * SM_ * 2);
  float* qbuf_a = (float*)alloc((size_t)B_ * INNER_ * 4);
  float* qbuf_b = (float*)alloc((size_t)B_ * INNER_ * 4);
  unsigned short* qb16_a = (unsigned short*)alloc((size_t)B_ * INNER_ * 2);
  unsigned short* qb16_b = (unsigned short*)alloc((size_t)B_ * INNER_ * 2);
  float* kvc_a  = (float*)alloc((size_t)B_ * 2048 * 4);
  float* kvc_b  = (float*)alloc((size_t)B_ * 2048 * 4);
  unsigned short* obufb_a = (unsigned short*)alloc((size_t)B_ * INNER_ * 2);
  unsigned short* obufb_b = (unsigned short*)alloc((size_t)B_ * INNER_ * 2);
  unsigned short* t1b_a = (unsigned short*)alloc((size_t)B_ * LG_ * 2);
  unsigned short* t1b_b = (unsigned short*)alloc((size_t)B_ * SM_ * 2);
  (void)ws_size; (void)in_sizes; (void)n_in; (void)out_size;

  const size_t sm_elems = (size_t)B_ * (NSM_ + 1) * SM_;

  // ---- setup1: all weight transposes + token pass (one dispatch)
  CC2 ca{sm_tokens, out, Abf_sm, cls_sm, clsb_sm, NSM_ + 1, SM_ / 4, 7,
         (int)(sm_elems / 4)};
  CC2 cb{lg_tokens, out + sm_elems, Abf_lg, cls_lg, clsb_lg, NLG_ + 1, LG_ / 4, 8,
         (int)((size_t)B_ * (NLG_ + 1) * LG_ / 4)};
  WTArgs W;
  W.d[0] = {a_wkv,    WTkv_a,   wkvnb_a, LG_, 2048};
  W.d[1] = {b_wkv,    WTkv_b,   wkvnb_b, SM_, 2048};
  W.d[2] = {a_pin_w,  WTpin_a,  nullptr, SM_, LG_};
  W.d[3] = {b_pin_w,  WTpin_b,  nullptr, LG_, SM_};
  W.d[4] = {a_wq,     WTwq_a,   nullptr, LG_, INNER_};
  W.d[5] = {b_wq,     WTwq_b,   nullptr, SM_, INNER_};
  W.d[6] = {a_wo,     WTwo_a,   nullptr, INNER_, LG_};
  W.d[7] = {b_wo,     WTwo_b,   nullptr, INNER_, SM_};
  W.d[8] = {a_pout_w, WTpout_a, nullptr, LG_, SM_};
  W.d[9] = {b_pout_w, WTpout_b, nullptr, SM_, LG_};
  W.cum[0] = 0;
  for (int i = 0; i < 10; i++)
    W.cum[i + 1] = W.cum[i] + (W.d[i].K / 64) * (W.d[i].N / 64) * 4;
  setup1<<<W.cum[10] + 2048, 256, 0, stream>>>(ca, cb, W, W.cum[10]);
  // ---- setup2: x^T (needs Abf from setup1)
  TXArgs txa{Abf_lg, xT_lg, NLG_, LG_, 224, LG_ / 64, 4, B_ * (LG_ / 64) * 4};
  TXArgs txb{Abf_sm, xT_sm, NSM_, SM_, 416, SM_ / 64, 7, B_ * (SM_ / 64) * 7};
  setup2<<<txa.nblk + txb.nblk, 256, 0, stream>>>(txa, txb);

  for (int l = 0; l < 4; l++) {
    const unsigned short* WTpin_al = WTpin_a + (size_t)l * SM_ * LG_;
    const unsigned short* WTpin_bl = WTpin_b + (size_t)l * LG_ * SM_;
    const unsigned short* WTwq_al  = WTwq_a  + (size_t)l * LG_ * INNER_;
    const unsigned short* WTwq_bl  = WTwq_b  + (size_t)l * SM_ * INNER_;
    const unsigned short* WTkv_al  = WTkv_a  + (size_t)l * 2048 * LG_;
    const unsigned short* WTkv_bl  = WTkv_b  + (size_t)l * 2048 * SM_;
    const unsigned short* wkvnb_al = wkvnb_a + (size_t)l * LG_ * 1024;
    const unsigned short* wkvnb_bl = wkvnb_b + (size_t)l * SM_ * 1024;
    const unsigned short* WTwo_al  = WTwo_a  + (size_t)l * INNER_ * LG_;
    const unsigned short* WTwo_bl  = WTwo_b  + (size_t)l * INNER_ * SM_;
    const unsigned short* WTpout_al = WTpout_a + (size_t)l * LG_ * SM_;
    const unsigned short* WTpout_bl = WTpout_b + (size_t)l * SM_ * LG_;

    // pin
    SGArgs Gp; Gp.nd = 2;
    Gp.d[0] = {clsb_sm, WTpin_al, a_pin_b + (size_t)l * LG_, xbuf_a, nullptr, nullptr, SM_, LG_, nullptr, 0};
    Gp.d[1] = {clsb_lg, WTpin_bl, b_pin_b + (size_t)l * SM_, xbuf_b, nullptr, nullptr, LG_, SM_, nullptr, 0};
    Gp.cum[0] = 0; Gp.cum[1] = LG_ / 16; Gp.cum[2] = LG_ / 16 + SM_ / 16;
    sg_wide<<<Gp.cum[2], 256, 0, stream>>>(Gp);
    // ln
    LNArgs la{xbuf_a, xnb_a, a_ng + (size_t)l * LG_, a_nb + (size_t)l * LG_, LG_};
    LNArgs lb{xbuf_b, xnb_b, b_ng + (size_t)l * SM_, b_nb + (size_t)l * SM_, SM_};
    ln2<<<128, 256, 0, stream>>>(la, lb);
    // q (f32 + bf16 mirror) + kv (cls)
    SGArgs Gq; Gq.nd = 4;
    Gq.d[0] = {xnb_a, WTwq_al, nullptr, qbuf_a, qb16_a, nullptr, LG_, INNER_, nullptr, 0};
    Gq.d[1] = {xnb_a, WTkv_al, nullptr, kvc_a,  nullptr, nullptr, LG_, 2048, nullptr, 0};
    Gq.d[2] = {xnb_b, WTwq_bl, nullptr, qbuf_b, qb16_b, nullptr, SM_, INNER_, nullptr, 0};
    Gq.d[3] = {xnb_b, WTkv_bl, nullptr, kvc_b,  nullptr, nullptr, SM_, 2048, nullptr, 0};
    Gq.cum[0] = 0; Gq.cum[1] = 64; Gq.cum[2] = 192; Gq.cum[3] = 256; Gq.cum[4] = 384;
    sg_wide<<<384, 256, 0, stream>>>(Gq);
    // q~ (MFMA over bf16 straight wkv)
    QTArgs qa{qb16_a, wkvnb_al, qt_a, LG_, LG_ / 16, 16 * (LG_ / 16)};
    QTArgs qb{qb16_b, wkvnb_bl, qt_b, SM_, SM_ / 16, 16 * (SM_ / 16)};
    qtilde3<<<qa.nblk + qb.nblk, 256, 0, stream>>>(qa, qb);
    // S = q~ . x^T
    SArgs sa{qt_a, Abf_lg, S_a, LG_, NLG_, 14, 4, B_ * 4};
    SArgs sb{qt_b, Abf_sm, S_b, SM_, NSM_, 26, 7, B_ * 7};
    s_gemm<<<sa.nblk + sb.nblk, 256, 0, stream>>>(sa, sb);
    // softmax -> p (once per (b,h))
    SMArgs ma{S_a, qbuf_a, kvc_a, p_a, pcls_a, NLG_, 224};
    SMArgs mb{S_b, qbuf_b, kvc_b, p_b, pcls_b, NSM_, 416};
    softmax_p2<<<dim3(H_, B_, 2), 256, 0, stream>>>(ma, mb);
    // u = p . x
    UG ua{p_a, xT_lg, u_a, LG_, 224, 224, LG_ / 64};
    UG ub{p_b, xT_sm, u_b, SM_, 416, 416, SM_ / 64};
    ugemm2<<<dim3(LG_ / 64 + SM_ / 64, B_), 256, 0, stream>>>(ua, ub);
    // o = u . Wv + pcls * v_cls
    OArgs oa{u_a, WTkv_al, kvc_a, pcls_a, obufb_a, LG_};
    OArgs ob{u_b, WTkv_bl, kvc_b, pcls_b, obufb_b, SM_};
    ogemm_w<<<128, 256, 0, stream>>>(oa, ob);
    // wo
    SGArgs Gw; Gw.nd = 2;
    Gw.d[0] = {obufb_a, WTwo_al, a_wob + (size_t)l * LG_, nullptr, t1b_a, nullptr, INNER_, LG_, nullptr, 0};
    Gw.d[1] = {obufb_b, WTwo_bl, b_wob + (size_t)l * SM_, nullptr, t1b_b, nullptr, INNER_, SM_, nullptr, 0};
    Gw.cum[0] = 0; Gw.cum[1] = LG_ / 16; Gw.cum[2] = LG_ / 16 + SM_ / 16;
    sg_wide<<<Gw.cum[2], 256, 0, stream>>>(Gw);
    // pout + residual; on the last layer also write cls rows straight to out
    float* outF_a = (l == 3) ? out : nullptr;
    float* outF_b = (l == 3) ? out + sm_elems : nullptr;
    SGArgs Gr; Gr.nd = 2;
    Gr.d[0] = {t1b_a, WTpout_al, a_pout_b + (size_t)l * SM_, cls_sm, clsb_sm, cls_sm, LG_, SM_,
               outF_a, (NSM_ + 1) * SM_};
    Gr.d[1] = {t1b_b, WTpout_bl, b_pout_b + (size_t)l * LG_, cls_lg, clsb_lg, cls_lg, SM_, LG_,
               outF_b, (NLG_ + 1) * LG_};
    Gr.cum[0] = 0; Gr.cum[1] = SM_ / 16; Gr.cum[2] = SM_ / 16 + LG_ / 16;
    sg_wide<<<Gr.cum[2], 256, 0, stream>>>(Gr);
  }
}